// Round 2
// baseline (3415.434 us; speedup 1.0000x reference)
//
#include <hip/hip_runtime.h>

#define B_  4
#define C_  512
#define H_  48
#define W_  48
#define N_  2304      // H_*W_
#define CR_ 64        // C_/R
#define C4_ 128       // C_/4
#define TK  16
#define LDSP 68       // 64 + 4 pad, keeps float4 rows 16B-aligned

// ---------------------------------------------------------------- reductions
__device__ __forceinline__ float blockReduceMax(float v, float* red) {
  const int tid = threadIdx.x;
  red[tid] = v; __syncthreads();
  for (int s = 128; s > 0; s >>= 1) {
    if (tid < s) red[tid] = fmaxf(red[tid], red[tid + s]);
    __syncthreads();
  }
  float r = red[0]; __syncthreads();
  return r;
}
__device__ __forceinline__ float blockReduceSum(float v, float* red) {
  const int tid = threadIdx.x;
  red[tid] = v; __syncthreads();
  for (int s = 128; s > 0; s >>= 1) {
    if (tid < s) red[tid] += red[tid + s];
    __syncthreads();
  }
  float r = red[0]; __syncthreads();
  return r;
}

// ---------------------------------------------------------------- micro-kernel
__device__ __forceinline__ void mm16(const float (*As)[LDSP], const float (*Bs)[LDSP],
                                     float acc[4][4], int ty, int tx)
{
#pragma unroll
  for (int kk = 0; kk < TK; ++kk) {
    const float4 a4 = *(const float4*)(&As[kk][ty * 4]);
    const float4 b4 = *(const float4*)(&Bs[kk][tx * 4]);
    const float av[4] = {a4.x, a4.y, a4.z, a4.w};
    const float bv[4] = {b4.x, b4.y, b4.z, b4.w};
#pragma unroll
    for (int i = 0; i < 4; ++i)
#pragma unroll
      for (int j = 0; j < 4; ++j)
        acc[i][j] = fmaf(av[i], bv[j], acc[i][j]);
  }
}

// ---------------------------------------------------------------- GEMM NN
__global__ __launch_bounds__(256)
void gemm_nn(const float* __restrict__ A, long long aStrideB, int lda,
             const float* __restrict__ B, long long bStrideB, int ldb,
             float* __restrict__ Y, long long yStrideB, int ldy,
             int K,
             const float* __restrict__ scale, const float* __restrict__ bias, int relu)
{
  __shared__ float As[TK][LDSP], Bs[TK][LDSP];
  const int b  = blockIdx.z;
  const int m0 = blockIdx.y * 64, n0 = blockIdx.x * 64;
  const int tid = threadIdx.x, tx = tid & 15, ty = tid >> 4;
  const int ia = tid >> 2, ka = (tid & 3) * 4;
  const int jb = tid & 63, kb = (tid >> 6) * 4;
  const float* Ab = A + (size_t)b * aStrideB;
  const float* Bb = B + (size_t)b * bStrideB;
  float acc[4][4] = {};
  for (int k0 = 0; k0 < K; k0 += TK) {
    const float4 a4 = *(const float4*)(Ab + (size_t)(m0 + ia) * lda + k0 + ka);
    As[ka + 0][ia] = a4.x; As[ka + 1][ia] = a4.y;
    As[ka + 2][ia] = a4.z; As[ka + 3][ia] = a4.w;
#pragma unroll
    for (int t = 0; t < 4; ++t)
      Bs[kb + t][jb] = Bb[(size_t)(k0 + kb + t) * ldb + n0 + jb];
    __syncthreads();
    mm16(As, Bs, acc, ty, tx);
    __syncthreads();
  }
  float* Yb = Y + (size_t)b * yStrideB;
#pragma unroll
  for (int i = 0; i < 4; ++i) {
    const int row = m0 + ty * 4 + i;
    const float s = scale ? scale[row] : 1.f;
    const float bb = bias ? bias[row] : 0.f;
    float4 o;
    o.x = acc[i][0] * s + bb; o.y = acc[i][1] * s + bb;
    o.z = acc[i][2] * s + bb; o.w = acc[i][3] * s + bb;
    if (relu) {
      o.x = fmaxf(o.x, 0.f); o.y = fmaxf(o.y, 0.f);
      o.z = fmaxf(o.z, 0.f); o.w = fmaxf(o.w, 0.f);
    }
    *(float4*)(Yb + (size_t)row * ldy + n0 + tx * 4) = o;
  }
}

// ---------------------------------------------------------------- GEMM NT
__global__ __launch_bounds__(256)
void gemm_nt(const float* __restrict__ A, long long aStrideB, int lda,
             const float* __restrict__ B, long long bStrideB, int ldb,
             float* __restrict__ Y, long long yStrideB, int ldy, int K)
{
  __shared__ float As[TK][LDSP], Bs[TK][LDSP];
  const int b  = blockIdx.z;
  const int m0 = blockIdx.y * 64, n0 = blockIdx.x * 64;
  const int tid = threadIdx.x, tx = tid & 15, ty = tid >> 4;
  const int ia = tid >> 2, ka = (tid & 3) * 4;
  const float* Ab = A + (size_t)b * aStrideB;
  const float* Bb = B + (size_t)b * bStrideB;
  float acc[4][4] = {};
  for (int k0 = 0; k0 < K; k0 += TK) {
    const float4 a4 = *(const float4*)(Ab + (size_t)(m0 + ia) * lda + k0 + ka);
    As[ka + 0][ia] = a4.x; As[ka + 1][ia] = a4.y;
    As[ka + 2][ia] = a4.z; As[ka + 3][ia] = a4.w;
    const float4 b4 = *(const float4*)(Bb + (size_t)(n0 + ia) * ldb + k0 + ka);
    Bs[ka + 0][ia] = b4.x; Bs[ka + 1][ia] = b4.y;
    Bs[ka + 2][ia] = b4.z; Bs[ka + 3][ia] = b4.w;
    __syncthreads();
    mm16(As, Bs, acc, ty, tx);
    __syncthreads();
  }
  float* Yb = Y + (size_t)b * yStrideB;
#pragma unroll
  for (int i = 0; i < 4; ++i) {
    const int row = m0 + ty * 4 + i;
    float4 o = {acc[i][0], acc[i][1], acc[i][2], acc[i][3]};
    *(float4*)(Yb + (size_t)row * ldy + n0 + tx * 4) = o;
  }
}

// ---------------------------------------------------------------- GEMM TN (energy)
__global__ __launch_bounds__(256)
void gemm_tn(const float* __restrict__ A, long long aStrideB, int lda,
             const float* __restrict__ B, long long bStrideB, int ldb,
             float* __restrict__ Y, long long yStrideB, int ldy, int K)
{
  __shared__ float As[TK][LDSP], Bs[TK][LDSP];
  const int b  = blockIdx.z;
  const int m0 = blockIdx.y * 64, n0 = blockIdx.x * 64;
  const int tid = threadIdx.x, tx = tid & 15, ty = tid >> 4;
  const int i2 = tid & 63, k2 = (tid >> 6) * 4;
  const float* Ab = A + (size_t)b * aStrideB;
  const float* Bb = B + (size_t)b * bStrideB;
  float acc[4][4] = {};
  for (int k0 = 0; k0 < K; k0 += TK) {
#pragma unroll
    for (int t = 0; t < 4; ++t) {
      As[k2 + t][i2] = Ab[(size_t)(k0 + k2 + t) * lda + m0 + i2];
      Bs[k2 + t][i2] = Bb[(size_t)(k0 + k2 + t) * ldb + n0 + i2];
    }
    __syncthreads();
    mm16(As, Bs, acc, ty, tx);
    __syncthreads();
  }
  float* Yb = Y + (size_t)b * yStrideB;
#pragma unroll
  for (int i = 0; i < 4; ++i) {
    const int row = m0 + ty * 4 + i;
    float4 o = {acc[i][0], acc[i][1], acc[i][2], acc[i][3]};
    *(float4*)(Yb + (size_t)row * ldy + n0 + tx * 4) = o;
  }
}

// ---------------------------------------------------------------- softmax stats (FULL: reads E)
__global__ __launch_bounds__(256)
void softmax_stats(const float* __restrict__ E, const float* __restrict__ M1,
                   const float* __restrict__ M2, float* __restrict__ st)
{
  const int row = blockIdx.x, b = blockIdx.y, tid = threadIdx.x;
  const float* er = E + ((size_t)b * N_ + row) * N_;
  const float* r1 = M1 + (size_t)row * N_;
  const float* r2 = M2 + (size_t)row * N_;
  float mx0 = -3.4e38f, mx1 = -3.4e38f, mx2 = -3.4e38f;
  for (int n = tid; n < N_; n += 256) {
    const float v = er[n];
    mx0 = fmaxf(mx0, v);
    if (r1[n] > 0.f) mx1 = fmaxf(mx1, v);
    if (r2[n] > 0.f) mx2 = fmaxf(mx2, v);
  }
  __shared__ float red[256];
  mx0 = blockReduceMax(mx0, red);
  mx1 = blockReduceMax(mx1, red);
  mx2 = blockReduceMax(mx2, red);
  float s0 = 0.f, s1 = 0.f, s2 = 0.f;
  for (int n = tid; n < N_; n += 256) {
    const float v = er[n];
    s0 += __expf(v - mx0);
    if (r1[n] > 0.f) s1 += __expf(v - mx1);
    if (r2[n] > 0.f) s2 += __expf(v - mx2);
  }
  s0 = blockReduceSum(s0, red);
  s1 = blockReduceSum(s1, red);
  s2 = blockReduceSum(s2, red);
  if (tid == 0) {
    float* o = st + ((size_t)b * N_ + row) * 6;
    o[0] = mx0; o[1] = s0; o[2] = mx1; o[3] = s1; o[4] = mx2; o[5] = s2;
  }
}

// ---------------------------------------------------------------- softmax stats (LITE: recompute E)
__global__ __launch_bounds__(256)
void softmax_stats_rq(const float* __restrict__ q, const float* __restrict__ k,
                      const float* __restrict__ M1, const float* __restrict__ M2,
                      float* __restrict__ st)
{
  const int row = blockIdx.x, b = blockIdx.y, tid = threadIdx.x;
  __shared__ float qs[CR_];
  if (tid < CR_) qs[tid] = q[((size_t)b * CR_ + tid) * N_ + row];
  __syncthreads();
  const float* kb_ = k + (size_t)b * CR_ * N_;
  float ev[9], mk1[9], mk2[9];
  const float* r1 = M1 + (size_t)row * N_;
  const float* r2 = M2 + (size_t)row * N_;
#pragma unroll
  for (int i = 0; i < 9; ++i) {
    const int n = tid + i * 256;
    float e = 0.f;
#pragma unroll 8
    for (int c = 0; c < CR_; ++c) e = fmaf(qs[c], kb_[(size_t)c * N_ + n], e);
    ev[i] = e; mk1[i] = r1[n]; mk2[i] = r2[n];
  }
  float mx0 = -3.4e38f, mx1 = -3.4e38f, mx2 = -3.4e38f;
#pragma unroll
  for (int i = 0; i < 9; ++i) {
    const float v = ev[i];
    mx0 = fmaxf(mx0, v);
    if (mk1[i] > 0.f) mx1 = fmaxf(mx1, v);
    if (mk2[i] > 0.f) mx2 = fmaxf(mx2, v);
  }
  __shared__ float red[256];
  mx0 = blockReduceMax(mx0, red);
  mx1 = blockReduceMax(mx1, red);
  mx2 = blockReduceMax(mx2, red);
  float s0 = 0.f, s1 = 0.f, s2 = 0.f;
#pragma unroll
  for (int i = 0; i < 9; ++i) {
    const float v = ev[i];
    s0 += __expf(v - mx0);
    if (mk1[i] > 0.f) s1 += __expf(v - mx1);
    if (mk2[i] > 0.f) s2 += __expf(v - mx2);
  }
  s0 = blockReduceSum(s0, red);
  s1 = blockReduceSum(s1, red);
  s2 = blockReduceSum(s2, red);
  if (tid == 0) {
    float* o = st + ((size_t)b * N_ + row) * 6;
    o[0] = mx0; o[1] = s0; o[2] = mx1; o[3] = s1; o[4] = mx2; o[5] = s2;
  }
}

// ---------------------------------------------------------------- attention apply (FULL)
__global__ __launch_bounds__(256)
void attn_apply(const float* __restrict__ V, const float* __restrict__ E,
                const float* __restrict__ st, int variant,
                const float* __restrict__ mask,
                const float* __restrict__ gammaPtr,
                const float* __restrict__ R, float* __restrict__ Y)
{
  __shared__ float As[TK][LDSP], Bs[TK][LDSP];
  const int b  = blockIdx.z;
  const int c0 = blockIdx.y * 64, m0 = blockIdx.x * 64;
  const int tid = threadIdx.x, tx = tid & 15, ty = tid >> 4;
  const int ia = tid >> 2, ka = (tid & 3) * 4;
  const int jb = tid >> 2, kb = (tid & 3) * 4;
  const int mrow = m0 + jb;
  const float* sp = st + ((size_t)b * N_ + mrow) * 6 + variant * 2;
  const float mx = sp[0];
  const float rs = 1.f / sp[1];
  const float* Vb = V + (size_t)b * C_ * N_;
  const float* Er = E + ((size_t)b * N_ + mrow) * N_;
  const float* Mr = mask ? mask + (size_t)mrow * N_ : nullptr;
  float acc[4][4] = {};
  for (int k0 = 0; k0 < N_; k0 += TK) {
    const float4 a4 = *(const float4*)(Vb + (size_t)(c0 + ia) * N_ + k0 + ka);
    As[ka + 0][ia] = a4.x; As[ka + 1][ia] = a4.y;
    As[ka + 2][ia] = a4.z; As[ka + 3][ia] = a4.w;
    const float4 e4 = *(const float4*)(Er + k0 + kb);
    float w0, w1, w2, w3;
    if (Mr) {
      const float4 m4 = *(const float4*)(Mr + k0 + kb);
      w0 = (m4.x > 0.f) ? __expf(e4.x - mx) * rs : 0.f;
      w1 = (m4.y > 0.f) ? __expf(e4.y - mx) * rs : 0.f;
      w2 = (m4.z > 0.f) ? __expf(e4.z - mx) * rs : 0.f;
      w3 = (m4.w > 0.f) ? __expf(e4.w - mx) * rs : 0.f;
    } else {
      w0 = __expf(e4.x - mx) * rs; w1 = __expf(e4.y - mx) * rs;
      w2 = __expf(e4.z - mx) * rs; w3 = __expf(e4.w - mx) * rs;
    }
    Bs[kb + 0][jb] = w0; Bs[kb + 1][jb] = w1;
    Bs[kb + 2][jb] = w2; Bs[kb + 3][jb] = w3;
    __syncthreads();
    mm16(As, Bs, acc, ty, tx);
    __syncthreads();
  }
  const float g = gammaPtr[0];
  float* Yb = Y + (size_t)b * C_ * N_;
  const float* Rb = R + (size_t)b * C_ * N_;
#pragma unroll
  for (int i = 0; i < 4; ++i) {
    const int row = c0 + ty * 4 + i;
    const size_t off = (size_t)row * N_ + m0 + tx * 4;
    const float4 r4 = *(const float4*)(Rb + off);
    float4 o;
    o.x = g * acc[i][0] + r4.x; o.y = g * acc[i][1] + r4.y;
    o.z = g * acc[i][2] + r4.z; o.w = g * acc[i][3] + r4.w;
    *(float4*)(Yb + off) = o;
  }
}

// ---------------------------------------------------------------- attention apply (LITE: recompute E)
__global__ __launch_bounds__(256)
void attn_apply_rq(const float* __restrict__ V, const float* __restrict__ q,
                   const float* __restrict__ k,
                   const float* __restrict__ st, int variant,
                   const float* __restrict__ mask,
                   const float* __restrict__ gammaPtr,
                   const float* __restrict__ R, float* __restrict__ Y)
{
  __shared__ float As[TK][LDSP], Bs[TK][LDSP];
  __shared__ float qs[CR_][65];
  __shared__ float kss[CR_][17];
  const int b  = blockIdx.z;
  const int c0 = blockIdx.y * 64, m0 = blockIdx.x * 64;
  const int tid = threadIdx.x, tx = tid & 15, ty = tid >> 4;
  const int ia = tid >> 2, ka = (tid & 3) * 4;
  const int jb = tid >> 2, kb = (tid & 3) * 4;
  const int mrow = m0 + jb;
  const float* qb_ = q + (size_t)b * CR_ * N_;
  const float* kb_ = k + (size_t)b * CR_ * N_;
#pragma unroll
  for (int i = 0; i < 16; ++i) {
    const int idx = tid + i * 256;              // 0..4095
    const int c = idx >> 6, j = idx & 63;
    qs[c][j] = qb_[(size_t)c * N_ + m0 + j];
  }
  const float* sp = st + ((size_t)b * N_ + mrow) * 6 + variant * 2;
  const float mx = sp[0];
  const float rs = 1.f / sp[1];
  const float* Vb = V + (size_t)b * C_ * N_;
  const float* Mr = mask ? mask + (size_t)mrow * N_ : nullptr;
  float acc[4][4] = {};
  __syncthreads();                              // qs ready
  for (int k0 = 0; k0 < N_; k0 += TK) {
    const float4 a4 = *(const float4*)(Vb + (size_t)(c0 + ia) * N_ + k0 + ka);
    As[ka + 0][ia] = a4.x; As[ka + 1][ia] = a4.y;
    As[ka + 2][ia] = a4.z; As[ka + 3][ia] = a4.w;
#pragma unroll
    for (int i = 0; i < 4; ++i) {
      const int idx = tid + i * 256;            // 0..1023
      const int c = idx >> 4, nn = idx & 15;
      kss[c][nn] = kb_[(size_t)c * N_ + k0 + nn];
    }
    __syncthreads();                            // As, kss ready
    float e0 = 0.f, e1 = 0.f, e2 = 0.f, e3 = 0.f;
#pragma unroll 16
    for (int c = 0; c < CR_; ++c) {
      const float qv = qs[c][jb];
      e0 = fmaf(qv, kss[c][kb + 0], e0);
      e1 = fmaf(qv, kss[c][kb + 1], e1);
      e2 = fmaf(qv, kss[c][kb + 2], e2);
      e3 = fmaf(qv, kss[c][kb + 3], e3);
    }
    float w0, w1, w2, w3;
    if (Mr) {
      const float4 m4 = *(const float4*)(Mr + k0 + kb);
      w0 = (m4.x > 0.f) ? __expf(e0 - mx) * rs : 0.f;
      w1 = (m4.y > 0.f) ? __expf(e1 - mx) * rs : 0.f;
      w2 = (m4.z > 0.f) ? __expf(e2 - mx) * rs : 0.f;
      w3 = (m4.w > 0.f) ? __expf(e3 - mx) * rs : 0.f;
    } else {
      w0 = __expf(e0 - mx) * rs; w1 = __expf(e1 - mx) * rs;
      w2 = __expf(e2 - mx) * rs; w3 = __expf(e3 - mx) * rs;
    }
    Bs[kb + 0][jb] = w0; Bs[kb + 1][jb] = w1;
    Bs[kb + 2][jb] = w2; Bs[kb + 3][jb] = w3;
    __syncthreads();                            // Bs ready
    mm16(As, Bs, acc, ty, tx);
    __syncthreads();                            // done reading As/Bs/kss
  }
  const float g = gammaPtr[0];
  float* Yb = Y + (size_t)b * C_ * N_;
  const float* Rb = R + (size_t)b * C_ * N_;
#pragma unroll
  for (int i = 0; i < 4; ++i) {
    const int row = c0 + ty * 4 + i;
    const size_t off = (size_t)row * N_ + m0 + tx * 4;
    const float4 r4 = *(const float4*)(Rb + off);
    float4 o;
    o.x = g * acc[i][0] + r4.x; o.y = g * acc[i][1] + r4.y;
    o.z = g * acc[i][2] + r4.z; o.w = g * acc[i][3] + r4.w;
    *(float4*)(Yb + off) = o;
  }
}

// ---------------------------------------------------------------- conv3x3 + BN + ReLU
__global__ __launch_bounds__(256)
void conv3x3_bnrelu(const float* __restrict__ X, const float* __restrict__ Wt,
                    const float* __restrict__ sc, const float* __restrict__ bi,
                    float* __restrict__ Y)
{
  __shared__ float As[TK][LDSP], Bs[TK][LDSP];
  const int b  = blockIdx.z;
  const int o0 = blockIdx.y * 64, n0 = blockIdx.x * 64;
  const int tid = threadIdx.x, tx = tid & 15, ty = tid >> 4;
  const int ia = tid >> 2, ka = (tid & 3) * 4;
  const int jb = tid & 63, kb = (tid >> 6) * 4;
  const int n = n0 + jb, yy = n / W_, xx = n - yy * W_;
  const float* Xb = X + (size_t)b * C_ * N_;
  const int K = C_ * 9;
  float acc[4][4] = {};
  for (int k0 = 0; k0 < K; k0 += TK) {
    const float4 a4 = *(const float4*)(Wt + (size_t)(o0 + ia) * K + k0 + ka);
    As[ka + 0][ia] = a4.x; As[ka + 1][ia] = a4.y;
    As[ka + 2][ia] = a4.z; As[ka + 3][ia] = a4.w;
#pragma unroll
    for (int t = 0; t < 4; ++t) {
      const int kg = k0 + kb + t;
      const int c = kg / 9, tap = kg - c * 9;
      const int t3 = tap / 3;
      const int dy = t3 - 1, dx = tap - t3 * 3 - 1;
      const int iy = yy + dy, ix = xx + dx;
      float v = 0.f;
      if (iy >= 0 && iy < H_ && ix >= 0 && ix < W_)
        v = Xb[(size_t)c * N_ + iy * W_ + ix];
      Bs[kb + t][jb] = v;
    }
    __syncthreads();
    mm16(As, Bs, acc, ty, tx);
    __syncthreads();
  }
#pragma unroll
  for (int i = 0; i < 4; ++i) {
    const int row = o0 + ty * 4 + i;
    const float s = sc[row], bb = bi[row];
    float4 o;
    o.x = fmaxf(acc[i][0] * s + bb, 0.f);
    o.y = fmaxf(acc[i][1] * s + bb, 0.f);
    o.z = fmaxf(acc[i][2] * s + bb, 0.f);
    o.w = fmaxf(acc[i][3] * s + bb, 0.f);
    *(float4*)(Y + ((size_t)b * C_ + row) * N_ + n0 + tx * 4) = o;
  }
}

// ---------------------------------------------------------------- chl row softmax
__global__ __launch_bounds__(256)
void chl_softmax(float* __restrict__ buf)
{
  const int row = blockIdx.x, tid = threadIdx.x;
  float* r = buf + (size_t)row * C_;
  const float v0 = -r[tid], v1 = -r[tid + 256];
  __shared__ float red[256];
  const float mx = blockReduceMax(fmaxf(v0, v1), red);
  const float e0 = __expf(v0 - mx), e1 = __expf(v1 - mx);
  const float s = blockReduceSum(e0 + e1, red);
  const float rs = 1.f / s;
  r[tid] = e0 * rs;
  r[tid + 256] = e1 * rs;
}

// ---------------------------------------------------------------- launch
extern "C" void kernel_launch(void* const* d_in, const int* in_sizes, int n_in,
                              void* d_out, int out_size, void* d_ws, size_t ws_size,
                              hipStream_t stream)
{
  (void)in_sizes; (void)n_in; (void)out_size;
  const float* x      = (const float*)d_in[0];
  const float* wq     = (const float*)d_in[1];
  const float* bq     = (const float*)d_in[2];
  const float* wk     = (const float*)d_in[3];
  const float* bk     = (const float*)d_in[4];
  const float* wv0    = (const float*)d_in[5];
  const float* bv0    = (const float*)d_in[6];
  const float* c1w    = (const float*)d_in[7];
  const float* c1s    = (const float*)d_in[8];
  const float* c1b    = (const float*)d_in[9];
  const float* c2w    = (const float*)d_in[10];
  const float* c2s    = (const float*)d_in[11];
  const float* c2b    = (const float*)d_in[12];
  const float* gamma  = (const float*)d_in[13];
  const float* gamma1 = (const float*)d_in[14];
  const float* gamma2 = (const float*)d_in[15];
  const float* c1qw   = (const float*)d_in[16];
  const float* c1qs   = (const float*)d_in[17];
  const float* c1qb   = (const float*)d_in[18];
  const float* c1ew   = (const float*)d_in[19];
  const float* c1eb   = (const float*)d_in[20];
  const float* c2qw   = (const float*)d_in[21];
  const float* c2qs   = (const float*)d_in[22];
  const float* c2qb   = (const float*)d_in[23];
  const float* c2ew   = (const float*)d_in[24];
  const float* c2eb   = (const float*)d_in[25];
  const float* mask1  = (const float*)d_in[26];
  const float* mask2  = (const float*)d_in[27];

  // FULL tier: materialized energy (132.9 MB). LITE tier: recompute (52.7 MB).
  const size_t QK   = 589824;          // B*CR*N
  const size_t CQ   = 1179648;         // B*C4*N
  const size_t VV   = 4718592;         // B*C*N
  const size_t EE   = 21233664;        // B*N*N
  const size_t ST   = 55296;           // B*N*6
  const size_t CE   = 262144;          // B*C4*C
  const size_t CA   = 1048576;         // B*C*C
  const size_t FULL_ELEMS = CQ + VV + EE + ST + VV + CE + CA;   // 33,216,512
  const int full = (ws_size >= FULL_ELEMS * sizeof(float)) ? 1 : 0;

  float* ws = (float*)d_ws;
  float *qbuf, *kbuf, *cq, *vbuf, *ebuf, *stb, *o0, *ce1, *cat_;
  if (full) {
    qbuf = ws; kbuf = ws + QK;         // dead after energy GEMM
    cq   = ws;                          // aliases q+k
    vbuf = ws + CQ;
    ebuf = vbuf + VV;
    stb  = ebuf + EE;
    o0   = stb + ST;
    ce1  = o0 + VV;
    cat_ = ce1 + CE;
  } else {
    qbuf = ws; kbuf = qbuf + QK;       // live all passes (recompute)
    cq   = kbuf + QK;
    vbuf = cq + CQ;
    stb  = vbuf + VV;
    o0   = stb + ST;
    ce1  = o0 + VV;
    cat_ = ce1 + CE;
    ebuf = nullptr;
  }
  float* t0 = (float*)d_out;           // pre-conv scratch aliases d_out
  float* o1 = o0;

  const dim3 TPB(256);
  const long long sxc = (long long)C_ * N_;
  const long long sqr = (long long)CR_ * N_;
  const long long sq4 = (long long)C4_ * N_;

  // q, k, v (1x1 convs)
  gemm_nn<<<dim3(36, 1, 4), TPB, 0, stream>>>(wq, 0, C_, x, sxc, N_,
                                              qbuf, sqr, N_, C_, nullptr, bq, 0);
  gemm_nn<<<dim3(36, 1, 4), TPB, 0, stream>>>(wk, 0, C_, x, sxc, N_,
                                              kbuf, sqr, N_, C_, nullptr, bk, 0);
  gemm_nn<<<dim3(36, 8, 4), TPB, 0, stream>>>(wv0, 0, C_, x, sxc, N_,
                                              vbuf, sxc, N_, C_, nullptr, bv0, 0);
  if (full) {
    gemm_tn<<<dim3(36, 36, 4), TPB, 0, stream>>>(qbuf, sqr, N_, kbuf, sqr, N_,
                                                 ebuf, (long long)N_ * N_, N_, CR_);
    softmax_stats<<<dim3(N_, 4), TPB, 0, stream>>>(ebuf, mask1, mask2, stb);
    attn_apply<<<dim3(36, 8, 4), TPB, 0, stream>>>(vbuf, ebuf, stb, 0, nullptr,
                                                   gamma, x, t0);
  } else {
    softmax_stats_rq<<<dim3(N_, 4), TPB, 0, stream>>>(qbuf, kbuf, mask1, mask2, stb);
    attn_apply_rq<<<dim3(36, 8, 4), TPB, 0, stream>>>(vbuf, qbuf, kbuf, stb, 0, nullptr,
                                                      gamma, x, t0);
  }
  conv3x3_bnrelu<<<dim3(36, 8, 4), TPB, 0, stream>>>(t0, c1w, c1s, c1b, o0);

  // chl #1 on o0 -> vbuf
  gemm_nn<<<dim3(36, 2, 4), TPB, 0, stream>>>(c1qw, 0, C_, o0, sxc, N_,
                                              cq, sq4, N_, C_, c1qs, c1qb, 1);
  gemm_nt<<<dim3(8, 2, 4), TPB, 0, stream>>>(cq, sq4, N_, o0, sxc, N_,
                                             ce1, (long long)C4_ * C_, C_, N_);
  gemm_nn<<<dim3(8, 8, 4), TPB, 0, stream>>>(c1ew, 0, C4_, ce1, (long long)C4_ * C_, C_,
                                             cat_, (long long)C_ * C_, C_, C4_,
                                             nullptr, c1eb, 0);
  chl_softmax<<<dim3(C_ * 4), TPB, 0, stream>>>(cat_);
  gemm_nn<<<dim3(36, 8, 4), TPB, 0, stream>>>(cat_, (long long)C_ * C_, C_, o0, sxc, N_,
                                              vbuf, sxc, N_, C_, nullptr, nullptr, 0);

  // pass 1
  if (full)
    attn_apply<<<dim3(36, 8, 4), TPB, 0, stream>>>(vbuf, ebuf, stb, 1, mask1,
                                                   gamma1, o0, t0);
  else
    attn_apply_rq<<<dim3(36, 8, 4), TPB, 0, stream>>>(vbuf, qbuf, kbuf, stb, 1, mask1,
                                                      gamma1, o0, t0);
  conv3x3_bnrelu<<<dim3(36, 8, 4), TPB, 0, stream>>>(t0, c2w, c2s, c2b, o1);

  // chl #2 on o1 -> vbuf
  gemm_nn<<<dim3(36, 2, 4), TPB, 0, stream>>>(c2qw, 0, C_, o1, sxc, N_,
                                              cq, sq4, N_, C_, c2qs, c2qb, 1);
  gemm_nt<<<dim3(8, 2, 4), TPB, 0, stream>>>(cq, sq4, N_, o1, sxc, N_,
                                             ce1, (long long)C4_ * C_, C_, N_);
  gemm_nn<<<dim3(8, 8, 4), TPB, 0, stream>>>(c2ew, 0, C4_, ce1, (long long)C4_ * C_, C_,
                                             cat_, (long long)C_ * C_, C_, C4_,
                                             nullptr, c2eb, 0);
  chl_softmax<<<dim3(C_ * 4), TPB, 0, stream>>>(cat_);
  gemm_nn<<<dim3(36, 8, 4), TPB, 0, stream>>>(cat_, (long long)C_ * C_, C_, o1, sxc, N_,
                                              vbuf, sxc, N_, C_, nullptr, nullptr, 0);

  // pass 2 -> d_out
  if (full)
    attn_apply<<<dim3(36, 8, 4), TPB, 0, stream>>>(vbuf, ebuf, stb, 2, mask2,
                                                   gamma2, o1, (float*)d_out);
  else
    attn_apply_rq<<<dim3(36, 8, 4), TPB, 0, stream>>>(vbuf, qbuf, kbuf, stb, 2, mask2,
                                                      gamma2, o1, (float*)d_out);
}

// Round 4
// 2423.275 us; speedup vs baseline: 1.4094x; 1.4094x over previous
//
#include <hip/hip_runtime.h>

#define B_  4
#define C_  512
#define H_  48
#define W_  48
#define N_  2304      // H_*W_
#define CR_ 64        // C_/R
#define C4_ 128       // C_/4
#define TK  16
#define LDSP 68       // fp32 helper tiles: 64 + 4 pad

typedef short  s16x8 __attribute__((ext_vector_type(8)));   // 8 bf16 (4 VGPR)
typedef float  f32x4 __attribute__((ext_vector_type(4)));

// fp32 -> bf16 bits, round-to-nearest-even
__device__ __forceinline__ unsigned short f2bf(float f) {
  union { float f; unsigned int u; } v; v.f = f;
  const unsigned int u = v.u;
  return (unsigned short)((u + 0x7FFFu + ((u >> 16) & 1u)) >> 16);
}
__device__ __forceinline__ float bf2f(unsigned short h) {
  union { unsigned int u; float f; } v; v.u = ((unsigned int)h) << 16;
  return v.f;
}

// ---------------------------------------------------------------- reductions
__device__ __forceinline__ float blockReduceMax(float v, float* red) {
  const int tid = threadIdx.x;
  red[tid] = v; __syncthreads();
  for (int s = 128; s > 0; s >>= 1) {
    if (tid < s) red[tid] = fmaxf(red[tid], red[tid + s]);
    __syncthreads();
  }
  float r = red[0]; __syncthreads();
  return r;
}
__device__ __forceinline__ float blockReduceSum(float v, float* red) {
  const int tid = threadIdx.x;
  red[tid] = v; __syncthreads();
  for (int s = 128; s > 0; s >>= 1) {
    if (tid < s) red[tid] += red[tid + s];
    __syncthreads();
  }
  float r = red[0]; __syncthreads();
  return r;
}

// ---------------------------------------------------------------- fp32 micro-kernel
__device__ __forceinline__ void mm16(const float (*As)[LDSP], const float (*Bs)[LDSP],
                                     float acc[4][4], int ty, int tx)
{
#pragma unroll
  for (int kk = 0; kk < TK; ++kk) {
    const float4 a4 = *(const float4*)(&As[kk][ty * 4]);
    const float4 b4 = *(const float4*)(&Bs[kk][tx * 4]);
    const float av[4] = {a4.x, a4.y, a4.z, a4.w};
    const float bv[4] = {b4.x, b4.y, b4.z, b4.w};
#pragma unroll
    for (int i = 0; i < 4; ++i)
#pragma unroll
      for (int j = 0; j < 4; ++j)
        acc[i][j] = fmaf(av[i], bv[j], acc[i][j]);
  }
}

// ---------------------------------------------------------------- fp32 GEMM NN (softmax-feeding chain)
__global__ __launch_bounds__(256)
void gemm_nn(const float* __restrict__ A, long long aStrideB, int lda,
             const float* __restrict__ B, long long bStrideB, int ldb,
             float* __restrict__ Y, long long yStrideB, int ldy,
             int K,
             const float* __restrict__ scale, const float* __restrict__ bias, int relu)
{
  __shared__ float As[TK][LDSP], Bs[TK][LDSP];
  const int b  = blockIdx.z;
  const int m0 = blockIdx.y * 64, n0 = blockIdx.x * 64;
  const int tid = threadIdx.x, tx = tid & 15, ty = tid >> 4;
  const int ia = tid >> 2, ka = (tid & 3) * 4;
  const int jb = tid & 63, kb = (tid >> 6) * 4;
  const float* Ab = A + (size_t)b * aStrideB;
  const float* Bb = B + (size_t)b * bStrideB;
  float acc[4][4] = {};
  for (int k0 = 0; k0 < K; k0 += TK) {
    const float4 a4 = *(const float4*)(Ab + (size_t)(m0 + ia) * lda + k0 + ka);
    As[ka + 0][ia] = a4.x; As[ka + 1][ia] = a4.y;
    As[ka + 2][ia] = a4.z; As[ka + 3][ia] = a4.w;
#pragma unroll
    for (int t = 0; t < 4; ++t)
      Bs[kb + t][jb] = Bb[(size_t)(k0 + kb + t) * ldb + n0 + jb];
    __syncthreads();
    mm16(As, Bs, acc, ty, tx);
    __syncthreads();
  }
  float* Yb = Y + (size_t)b * yStrideB;
#pragma unroll
  for (int i = 0; i < 4; ++i) {
    const int row = m0 + ty * 4 + i;
    const float s = scale ? scale[row] : 1.f;
    const float bb = bias ? bias[row] : 0.f;
    float4 o;
    o.x = acc[i][0] * s + bb; o.y = acc[i][1] * s + bb;
    o.z = acc[i][2] * s + bb; o.w = acc[i][3] * s + bb;
    if (relu) {
      o.x = fmaxf(o.x, 0.f); o.y = fmaxf(o.y, 0.f);
      o.z = fmaxf(o.z, 0.f); o.w = fmaxf(o.w, 0.f);
    }
    *(float4*)(Yb + (size_t)row * ldy + n0 + tx * 4) = o;
  }
}

// ---------------------------------------------------------------- fp32 GEMM NT (chl energy: ce1 = cq . o0^T)
__global__ __launch_bounds__(256)
void gemm_nt(const float* __restrict__ A, long long aStrideB, int lda,
             const float* __restrict__ B, long long bStrideB, int ldb,
             float* __restrict__ Y, long long yStrideB, int ldy, int K)
{
  __shared__ float As[TK][LDSP], Bs[TK][LDSP];
  const int b  = blockIdx.z;
  const int m0 = blockIdx.y * 64, n0 = blockIdx.x * 64;
  const int tid = threadIdx.x, tx = tid & 15, ty = tid >> 4;
  const int ia = tid >> 2, ka = (tid & 3) * 4;
  const float* Ab = A + (size_t)b * aStrideB;
  const float* Bb = B + (size_t)b * bStrideB;
  float acc[4][4] = {};
  for (int k0 = 0; k0 < K; k0 += TK) {
    const float4 a4 = *(const float4*)(Ab + (size_t)(m0 + ia) * lda + k0 + ka);
    As[ka + 0][ia] = a4.x; As[ka + 1][ia] = a4.y;
    As[ka + 2][ia] = a4.z; As[ka + 3][ia] = a4.w;
    const float4 b4 = *(const float4*)(Bb + (size_t)(n0 + ia) * ldb + k0 + ka);
    Bs[ka + 0][ia] = b4.x; Bs[ka + 1][ia] = b4.y;
    Bs[ka + 2][ia] = b4.z; Bs[ka + 3][ia] = b4.w;
    __syncthreads();
    mm16(As, Bs, acc, ty, tx);
    __syncthreads();
  }
  float* Yb = Y + (size_t)b * yStrideB;
#pragma unroll
  for (int i = 0; i < 4; ++i) {
    const int row = m0 + ty * 4 + i;
    float4 o = {acc[i][0], acc[i][1], acc[i][2], acc[i][3]};
    *(float4*)(Yb + (size_t)row * ldy + n0 + tx * 4) = o;
  }
}

// ---------------------------------------------------------------- fp32 GEMM TN (energy = q^T k)
__global__ __launch_bounds__(256)
void gemm_tn(const float* __restrict__ A, long long aStrideB, int lda,
             const float* __restrict__ B, long long bStrideB, int ldb,
             float* __restrict__ Y, long long yStrideB, int ldy, int K)
{
  __shared__ float As[TK][LDSP], Bs[TK][LDSP];
  const int b  = blockIdx.z;
  const int m0 = blockIdx.y * 64, n0 = blockIdx.x * 64;
  const int tid = threadIdx.x, tx = tid & 15, ty = tid >> 4;
  const int i2 = tid & 63, k2 = (tid >> 6) * 4;
  const float* Ab = A + (size_t)b * aStrideB;
  const float* Bb = B + (size_t)b * bStrideB;
  float acc[4][4] = {};
  for (int k0 = 0; k0 < K; k0 += TK) {
#pragma unroll
    for (int t = 0; t < 4; ++t) {
      As[k2 + t][i2] = Ab[(size_t)(k0 + k2 + t) * lda + m0 + i2];
      Bs[k2 + t][i2] = Bb[(size_t)(k0 + k2 + t) * ldb + n0 + i2];
    }
    __syncthreads();
    mm16(As, Bs, acc, ty, tx);
    __syncthreads();
  }
  float* Yb = Y + (size_t)b * yStrideB;
#pragma unroll
  for (int i = 0; i < 4; ++i) {
    const int row = m0 + ty * 4 + i;
    float4 o = {acc[i][0], acc[i][1], acc[i][2], acc[i][3]};
    *(float4*)(Yb + (size_t)row * ldy + n0 + tx * 4) = o;
  }
}

// ================================================================ MFMA GEMM (bf16; non-logit paths only)
// Y[b,i,j] = epi( sum_k A[b,i,k] * B[...] )
// B modes: bTrans=1: fp32 B[k][j]; bBf16=1: bf16 B[j][k]
__global__ __launch_bounds__(256)
void mfma_gemm(const float* __restrict__ A, long long aSB, int lda,
               const void* __restrict__ Bv, long long bSB, int ldb,
               int bTrans, int bBf16,
               float* __restrict__ Y, long long ySB, int ldy, int K,
               const float* __restrict__ scale, const float* __restrict__ bias,
               int relu,
               const float* __restrict__ gammaPtr, const float* __restrict__ Resid,
               long long rSB)
{
  __shared__ unsigned short As[64][72];
  __shared__ unsigned short Bs[64][72];
  const int b  = blockIdx.z;
  const int m0 = blockIdx.y * 64, n0 = blockIdx.x * 64;
  const int tid  = threadIdx.x;
  const int lane = tid & 63, wave = tid >> 6;
  const int wm = wave >> 1, wn = wave & 1;
  const int lrow = lane & 15, lk8 = (lane >> 4) * 8;
  const int sRow = tid >> 2, sK = (tid & 3) * 16;
  const int tj = tid & 63, tkg = (tid >> 6) * 16;
  const float* Ab = A + (size_t)b * aSB;
  f32x4 acc[2][2] = {};

  for (int k0 = 0; k0 < K; k0 += 64) {
    {
      const float* src = Ab + (size_t)(m0 + sRow) * lda + k0 + sK;
      const float4 x0 = *(const float4*)(src);
      const float4 x1 = *(const float4*)(src + 4);
      const float4 x2 = *(const float4*)(src + 8);
      const float4 x3 = *(const float4*)(src + 12);
      s16x8 p0 = { (short)f2bf(x0.x), (short)f2bf(x0.y), (short)f2bf(x0.z), (short)f2bf(x0.w),
                   (short)f2bf(x1.x), (short)f2bf(x1.y), (short)f2bf(x1.z), (short)f2bf(x1.w) };
      s16x8 p1 = { (short)f2bf(x2.x), (short)f2bf(x2.y), (short)f2bf(x2.z), (short)f2bf(x2.w),
                   (short)f2bf(x3.x), (short)f2bf(x3.y), (short)f2bf(x3.z), (short)f2bf(x3.w) };
      *(s16x8*)&As[sRow][sK]     = p0;
      *(s16x8*)&As[sRow][sK + 8] = p1;
    }
    if (bTrans) {
      const float* Bb = (const float*)Bv + (size_t)b * bSB;
#pragma unroll
      for (int ii = 0; ii < 16; ii += 2) {
        const float v0 = Bb[(size_t)(k0 + tkg + ii)     * ldb + n0 + tj];
        const float v1 = Bb[(size_t)(k0 + tkg + ii + 1) * ldb + n0 + tj];
        *(unsigned int*)&Bs[tj][tkg + ii] =
            (unsigned int)f2bf(v0) | ((unsigned int)f2bf(v1) << 16);
      }
    } else {
      const unsigned short* Bb = (const unsigned short*)Bv + (size_t)b * bSB;
      const unsigned short* src = Bb + (size_t)(n0 + sRow) * ldb + k0 + sK;
      *(s16x8*)&Bs[sRow][sK]     = *(const s16x8*)(src);
      *(s16x8*)&Bs[sRow][sK + 8] = *(const s16x8*)(src + 8);
    }
    __syncthreads();
#pragma unroll
    for (int kc = 0; kc < 2; ++kc) {
      const s16x8 a0 = *(const s16x8*)&As[wm * 32 + lrow     ][kc * 32 + lk8];
      const s16x8 a1 = *(const s16x8*)&As[wm * 32 + 16 + lrow][kc * 32 + lk8];
      const s16x8 b0 = *(const s16x8*)&Bs[wn * 32 + lrow     ][kc * 32 + lk8];
      const s16x8 b1 = *(const s16x8*)&Bs[wn * 32 + 16 + lrow][kc * 32 + lk8];
      acc[0][0] = __builtin_amdgcn_mfma_f32_16x16x32_bf16(a0, b0, acc[0][0], 0, 0, 0);
      acc[0][1] = __builtin_amdgcn_mfma_f32_16x16x32_bf16(a0, b1, acc[0][1], 0, 0, 0);
      acc[1][0] = __builtin_amdgcn_mfma_f32_16x16x32_bf16(a1, b0, acc[1][0], 0, 0, 0);
      acc[1][1] = __builtin_amdgcn_mfma_f32_16x16x32_bf16(a1, b1, acc[1][1], 0, 0, 0);
    }
    __syncthreads();
  }

  float* Yb = Y + (size_t)b * ySB;
  const float g = gammaPtr ? gammaPtr[0] : 0.f;
  const float* Rb = Resid ? Resid + (size_t)b * rSB : nullptr;
#pragma unroll
  for (int mt = 0; mt < 2; ++mt)
#pragma unroll
    for (int nt = 0; nt < 2; ++nt) {
      const int col = n0 + wn * 32 + nt * 16 + lrow;
      const int rbase = m0 + wm * 32 + mt * 16 + (lane >> 4) * 4;
#pragma unroll
      for (int i = 0; i < 4; ++i) {
        const int row = rbase + i;
        float v = acc[mt][nt][i];
        if (Rb) {
          v = g * v + Rb[(size_t)row * ldy + col];
        } else {
          const float s  = scale ? scale[row] : 1.f;
          const float bb = bias ? bias[row] : 0.f;
          v = v * s + bb;
          if (relu) v = fmaxf(v, 0.f);
        }
        Yb[(size_t)row * ldy + col] = v;
      }
    }
}

// ================================================================ split-bf16 MFMA conv3x3 + BN + ReLU
// fp32-grade accuracy: x = xh + xl, acc += Ah*Bh + Ah*Bl + Al*Bh
__global__ __launch_bounds__(256)
void mfma_conv_split(const float* __restrict__ X, const float* __restrict__ Wt,
                     const float* __restrict__ sc, const float* __restrict__ bi,
                     float* __restrict__ Y)
{
  __shared__ unsigned short Ah[64][72], Al[64][72];
  __shared__ unsigned short Bh[64][72], Bl[64][72];
  const int b  = blockIdx.z;
  const int m0 = blockIdx.y * 64, n0 = blockIdx.x * 64;
  const int tid  = threadIdx.x;
  const int lane = tid & 63, wave = tid >> 6;
  const int wm = wave >> 1, wn = wave & 1;
  const int lrow = lane & 15, lk8 = (lane >> 4) * 8;
  const int sRow = tid >> 2, sK = (tid & 3) * 16;
  const int tj = tid & 63, tkg = (tid >> 6) * 16;
  const int n = n0 + tj, yy = n / W_, xx = n - yy * W_;
  const float* Xb = X + (size_t)b * C_ * N_;
  const int K = C_ * 9;
  f32x4 acc[2][2] = {};

  for (int k0 = 0; k0 < K; k0 += 64) {
    { // weights: 16 fp32 -> hi/lo bf16
      const float* src = Wt + (size_t)(m0 + sRow) * K + k0 + sK;
      unsigned short h[16], l[16];
#pragma unroll
      for (int t = 0; t < 16; ++t) {
        const float v = src[t];
        const unsigned short hh = f2bf(v);
        h[t] = hh;
        l[t] = f2bf(v - bf2f(hh));
      }
      *(s16x8*)&Ah[sRow][sK]     = *(s16x8*)&h[0];
      *(s16x8*)&Ah[sRow][sK + 8] = *(s16x8*)&h[8];
      *(s16x8*)&Al[sRow][sK]     = *(s16x8*)&l[0];
      *(s16x8*)&Al[sRow][sK + 8] = *(s16x8*)&l[8];
    }
    { // im2col activations: hi/lo
#pragma unroll
      for (int ii = 0; ii < 16; ii += 2) {
        unsigned int ph = 0, pl = 0;
#pragma unroll
        for (int hft = 0; hft < 2; ++hft) {
          const int kg = k0 + tkg + ii + hft;
          const int c = kg / 9, tap = kg - c * 9;
          const int t3 = tap / 3;
          const int iy = yy + t3 - 1, ix = xx + (tap - t3 * 3) - 1;
          float v = 0.f;
          if (iy >= 0 && iy < H_ && ix >= 0 && ix < W_)
            v = Xb[(size_t)c * N_ + iy * W_ + ix];
          const unsigned short hh = f2bf(v);
          const unsigned short ll = f2bf(v - bf2f(hh));
          ph |= ((unsigned int)hh) << (16 * hft);
          pl |= ((unsigned int)ll) << (16 * hft);
        }
        *(unsigned int*)&Bh[tj][tkg + ii] = ph;
        *(unsigned int*)&Bl[tj][tkg + ii] = pl;
      }
    }
    __syncthreads();
#pragma unroll
    for (int kc = 0; kc < 2; ++kc) {
      const s16x8 ah0 = *(const s16x8*)&Ah[wm * 32 + lrow     ][kc * 32 + lk8];
      const s16x8 ah1 = *(const s16x8*)&Ah[wm * 32 + 16 + lrow][kc * 32 + lk8];
      const s16x8 al0 = *(const s16x8*)&Al[wm * 32 + lrow     ][kc * 32 + lk8];
      const s16x8 al1 = *(const s16x8*)&Al[wm * 32 + 16 + lrow][kc * 32 + lk8];
      const s16x8 bh0 = *(const s16x8*)&Bh[wn * 32 + lrow     ][kc * 32 + lk8];
      const s16x8 bh1 = *(const s16x8*)&Bh[wn * 32 + 16 + lrow][kc * 32 + lk8];
      const s16x8 bl0 = *(const s16x8*)&Bl[wn * 32 + lrow     ][kc * 32 + lk8];
      const s16x8 bl1 = *(const s16x8*)&Bl[wn * 32 + 16 + lrow][kc * 32 + lk8];
      acc[0][0] = __builtin_amdgcn_mfma_f32_16x16x32_bf16(ah0, bh0, acc[0][0], 0, 0, 0);
      acc[0][1] = __builtin_amdgcn_mfma_f32_16x16x32_bf16(ah0, bh1, acc[0][1], 0, 0, 0);
      acc[1][0] = __builtin_amdgcn_mfma_f32_16x16x32_bf16(ah1, bh0, acc[1][0], 0, 0, 0);
      acc[1][1] = __builtin_amdgcn_mfma_f32_16x16x32_bf16(ah1, bh1, acc[1][1], 0, 0, 0);
      acc[0][0] = __builtin_amdgcn_mfma_f32_16x16x32_bf16(ah0, bl0, acc[0][0], 0, 0, 0);
      acc[0][1] = __builtin_amdgcn_mfma_f32_16x16x32_bf16(ah0, bl1, acc[0][1], 0, 0, 0);
      acc[1][0] = __builtin_amdgcn_mfma_f32_16x16x32_bf16(ah1, bl0, acc[1][0], 0, 0, 0);
      acc[1][1] = __builtin_amdgcn_mfma_f32_16x16x32_bf16(ah1, bl1, acc[1][1], 0, 0, 0);
      acc[0][0] = __builtin_amdgcn_mfma_f32_16x16x32_bf16(al0, bh0, acc[0][0], 0, 0, 0);
      acc[0][1] = __builtin_amdgcn_mfma_f32_16x16x32_bf16(al0, bh1, acc[0][1], 0, 0, 0);
      acc[1][0] = __builtin_amdgcn_mfma_f32_16x16x32_bf16(al1, bh0, acc[1][0], 0, 0, 0);
      acc[1][1] = __builtin_amdgcn_mfma_f32_16x16x32_bf16(al1, bh1, acc[1][1], 0, 0, 0);
    }
    __syncthreads();
  }

  float* Yb = Y + (size_t)b * C_ * N_;
#pragma unroll
  for (int mt = 0; mt < 2; ++mt)
#pragma unroll
    for (int nt = 0; nt < 2; ++nt) {
      const int col = n0 + wn * 32 + nt * 16 + lrow;
      const int rbase = m0 + wm * 32 + mt * 16 + (lane >> 4) * 4;
#pragma unroll
      for (int i = 0; i < 4; ++i) {
        const int row = rbase + i;
        const float v = fmaxf(acc[mt][nt][i] * sc[row] + bi[row], 0.f);
        Yb[(size_t)row * N_ + col] = v;
      }
    }
}

// ================================================================ P build (fp32 E -> bf16 P)
__global__ __launch_bounds__(256)
void build_P(const float* __restrict__ E, const float* __restrict__ st,
             int variant, const float* __restrict__ mask,
             unsigned short* __restrict__ P)
{
  const int m = blockIdx.x, b = blockIdx.y, t = threadIdx.x;
  const float* sp = st + ((size_t)b * N_ + m) * 6 + variant * 2;
  const float mx = sp[0], rs = 1.f / sp[1];
  const float* Er = E + ((size_t)b * N_ + m) * N_;
  unsigned short* Pr = P + ((size_t)b * N_ + m) * N_;
  const float* Mr = mask ? mask + (size_t)m * N_ : nullptr;
#pragma unroll
  for (int i = 0; i < 9; ++i) {
    const int idx = t + i * 256;
    float w = __expf(Er[idx] - mx) * rs;
    if (Mr && !(Mr[idx] > 0.f)) w = 0.f;
    Pr[idx] = f2bf(w);
  }
}

// ---------------------------------------------------------------- softmax stats (FULL: reads E)
__global__ __launch_bounds__(256)
void softmax_stats(const float* __restrict__ E, const float* __restrict__ M1,
                   const float* __restrict__ M2, float* __restrict__ st)
{
  const int row = blockIdx.x, b = blockIdx.y, tid = threadIdx.x;
  const float* er = E + ((size_t)b * N_ + row) * N_;
  const float* r1 = M1 + (size_t)row * N_;
  const float* r2 = M2 + (size_t)row * N_;
  float mx0 = -3.4e38f, mx1 = -3.4e38f, mx2 = -3.4e38f;
  for (int n = tid; n < N_; n += 256) {
    const float v = er[n];
    mx0 = fmaxf(mx0, v);
    if (r1[n] > 0.f) mx1 = fmaxf(mx1, v);
    if (r2[n] > 0.f) mx2 = fmaxf(mx2, v);
  }
  __shared__ float red[256];
  mx0 = blockReduceMax(mx0, red);
  mx1 = blockReduceMax(mx1, red);
  mx2 = blockReduceMax(mx2, red);
  float s0 = 0.f, s1 = 0.f, s2 = 0.f;
  for (int n = tid; n < N_; n += 256) {
    const float v = er[n];
    s0 += __expf(v - mx0);
    if (r1[n] > 0.f) s1 += __expf(v - mx1);
    if (r2[n] > 0.f) s2 += __expf(v - mx2);
  }
  s0 = blockReduceSum(s0, red);
  s1 = blockReduceSum(s1, red);
  s2 = blockReduceSum(s2, red);
  if (tid == 0) {
    float* o = st + ((size_t)b * N_ + row) * 6;
    o[0] = mx0; o[1] = s0; o[2] = mx1; o[3] = s1; o[4] = mx2; o[5] = s2;
  }
}

// ---------------------------------------------------------------- softmax stats (LITE: recompute E)
__global__ __launch_bounds__(256)
void softmax_stats_rq(const float* __restrict__ q, const float* __restrict__ k,
                      const float* __restrict__ M1, const float* __restrict__ M2,
                      float* __restrict__ st)
{
  const int row = blockIdx.x, b = blockIdx.y, tid = threadIdx.x;
  __shared__ float qs[CR_];
  if (tid < CR_) qs[tid] = q[((size_t)b * CR_ + tid) * N_ + row];
  __syncthreads();
  const float* kb_ = k + (size_t)b * CR_ * N_;
  float ev[9], mk1[9], mk2[9];
  const float* r1 = M1 + (size_t)row * N_;
  const float* r2 = M2 + (size_t)row * N_;
#pragma unroll
  for (int i = 0; i < 9; ++i) {
    const int n = tid + i * 256;
    float e = 0.f;
#pragma unroll 8
    for (int c = 0; c < CR_; ++c) e = fmaf(qs[c], kb_[(size_t)c * N_ + n], e);
    ev[i] = e; mk1[i] = r1[n]; mk2[i] = r2[n];
  }
  float mx0 = -3.4e38f, mx1 = -3.4e38f, mx2 = -3.4e38f;
#pragma unroll
  for (int i = 0; i < 9; ++i) {
    const float v = ev[i];
    mx0 = fmaxf(mx0, v);
    if (mk1[i] > 0.f) mx1 = fmaxf(mx1, v);
    if (mk2[i] > 0.f) mx2 = fmaxf(mx2, v);
  }
  __shared__ float red[256];
  mx0 = blockReduceMax(mx0, red);
  mx1 = blockReduceMax(mx1, red);
  mx2 = blockReduceMax(mx2, red);
  float s0 = 0.f, s1 = 0.f, s2 = 0.f;
#pragma unroll
  for (int i = 0; i < 9; ++i) {
    const float v = ev[i];
    s0 += __expf(v - mx0);
    if (mk1[i] > 0.f) s1 += __expf(v - mx1);
    if (mk2[i] > 0.f) s2 += __expf(v - mx2);
  }
  s0 = blockReduceSum(s0, red);
  s1 = blockReduceSum(s1, red);
  s2 = blockReduceSum(s2, red);
  if (tid == 0) {
    float* o = st + ((size_t)b * N_ + row) * 6;
    o[0] = mx0; o[1] = s0; o[2] = mx1; o[3] = s1; o[4] = mx2; o[5] = s2;
  }
}

// ---------------------------------------------------------------- attention apply (fp32, tier-1 fallback)
__global__ __launch_bounds__(256)
void attn_apply(const float* __restrict__ V, const float* __restrict__ E,
                const float* __restrict__ st, int variant,
                const float* __restrict__ mask,
                const float* __restrict__ gammaPtr,
                const float* __restrict__ R, float* __restrict__ Y)
{
  __shared__ float As[TK][LDSP], Bs[TK][LDSP];
  const int b  = blockIdx.z;
  const int c0 = blockIdx.y * 64, m0 = blockIdx.x * 64;
  const int tid = threadIdx.x, tx = tid & 15, ty = tid >> 4;
  const int ia = tid >> 2, ka = (tid & 3) * 4;
  const int jb = tid >> 2, kb = (tid & 3) * 4;
  const int mrow = m0 + jb;
  const float* sp = st + ((size_t)b * N_ + mrow) * 6 + variant * 2;
  const float mx = sp[0];
  const float rs = 1.f / sp[1];
  const float* Vb = V + (size_t)b * C_ * N_;
  const float* Er = E + ((size_t)b * N_ + mrow) * N_;
  const float* Mr = mask ? mask + (size_t)mrow * N_ : nullptr;
  float acc[4][4] = {};
  for (int k0 = 0; k0 < N_; k0 += TK) {
    const float4 a4 = *(const float4*)(Vb + (size_t)(c0 + ia) * N_ + k0 + ka);
    As[ka + 0][ia] = a4.x; As[ka + 1][ia] = a4.y;
    As[ka + 2][ia] = a4.z; As[ka + 3][ia] = a4.w;
    const float4 e4 = *(const float4*)(Er + k0 + kb);
    float w0, w1, w2, w3;
    if (Mr) {
      const float4 m4 = *(const float4*)(Mr + k0 + kb);
      w0 = (m4.x > 0.f) ? __expf(e4.x - mx) * rs : 0.f;
      w1 = (m4.y > 0.f) ? __expf(e4.y - mx) * rs : 0.f;
      w2 = (m4.z > 0.f) ? __expf(e4.z - mx) * rs : 0.f;
      w3 = (m4.w > 0.f) ? __expf(e4.w - mx) * rs : 0.f;
    } else {
      w0 = __expf(e4.x - mx) * rs; w1 = __expf(e4.y - mx) * rs;
      w2 = __expf(e4.z - mx) * rs; w3 = __expf(e4.w - mx) * rs;
    }
    Bs[kb + 0][jb] = w0; Bs[kb + 1][jb] = w1;
    Bs[kb + 2][jb] = w2; Bs[kb + 3][jb] = w3;
    __syncthreads();
    mm16(As, Bs, acc, ty, tx);
    __syncthreads();
  }
  const float g = gammaPtr[0];
  float* Yb = Y + (size_t)b * C_ * N_;
  const float* Rb = R + (size_t)b * C_ * N_;
#pragma unroll
  for (int i = 0; i < 4; ++i) {
    const int row = c0 + ty * 4 + i;
    const size_t off = (size_t)row * N_ + m0 + tx * 4;
    const float4 r4 = *(const float4*)(Rb + off);
    float4 o;
    o.x = g * acc[i][0] + r4.x; o.y = g * acc[i][1] + r4.y;
    o.z = g * acc[i][2] + r4.z; o.w = g * acc[i][3] + r4.w;
    *(float4*)(Yb + off) = o;
  }
}

// ---------------------------------------------------------------- attention apply (fp32 LITE, tier-2 fallback)
__global__ __launch_bounds__(256)
void attn_apply_rq(const float* __restrict__ V, const float* __restrict__ q,
                   const float* __restrict__ k,
                   const float* __restrict__ st, int variant,
                   const float* __restrict__ mask,
                   const float* __restrict__ gammaPtr,
                   const float* __restrict__ R, float* __restrict__ Y)
{
  __shared__ float As[TK][LDSP], Bs[TK][LDSP];
  __shared__ float qs[CR_][65];
  __shared__ float kss[CR_][17];
  const int b  = blockIdx.z;
  const int c0 = blockIdx.y * 64, m0 = blockIdx.x * 64;
  const int tid = threadIdx.x, tx = tid & 15, ty = tid >> 4;
  const int ia = tid >> 2, ka = (tid & 3) * 4;
  const int jb = tid >> 2, kb = (tid & 3) * 4;
  const int mrow = m0 + jb;
  const float* qb_ = q + (size_t)b * CR_ * N_;
  const float* kb_ = k + (size_t)b * CR_ * N_;
#pragma unroll
  for (int i = 0; i < 16; ++i) {
    const int idx = tid + i * 256;
    const int c = idx >> 6, j = idx & 63;
    qs[c][j] = qb_[(size_t)c * N_ + m0 + j];
  }
  const float* sp = st + ((size_t)b * N_ + mrow) * 6 + variant * 2;
  const float mx = sp[0];
  const float rs = 1.f / sp[1];
  const float* Vb = V + (size_t)b * C_ * N_;
  const float* Mr = mask ? mask + (size_t)mrow * N_ : nullptr;
  float acc[4][4] = {};
  __syncthreads();
  for (int k0 = 0; k0 < N_; k0 += TK) {
    const float4 a4 = *(const float4*)(Vb + (size_t)(c0 + ia) * N_ + k0 + ka);
    As[ka + 0][ia] = a4.x; As[ka + 1][ia] = a4.y;
    As[ka + 2][ia] = a4.z; As[ka + 3][ia] = a4.w;
#pragma unroll
    for (int i = 0; i < 4; ++i) {
      const int idx = tid + i * 256;
      const int c = idx >> 4, nn = idx & 15;
      kss[c][nn] = kb_[(size_t)c * N_ + k0 + nn];
    }
    __syncthreads();
    float e0 = 0.f, e1 = 0.f, e2 = 0.f, e3 = 0.f;
#pragma unroll 16
    for (int c = 0; c < CR_; ++c) {
      const float qv = qs[c][jb];
      e0 = fmaf(qv, kss[c][kb + 0], e0);
      e1 = fmaf(qv, kss[c][kb + 1], e1);
      e2 = fmaf(qv, kss[c][kb + 2], e2);
      e3 = fmaf(qv, kss[c][kb + 3], e3);
    }
    float w0, w1, w2, w3;
    if (Mr) {
      const float4 m4 = *(const float4*)(Mr + k0 + kb);
      w0 = (m4.x > 0.f) ? __expf(e0 - mx) * rs : 0.f;
      w1 = (m4.y > 0.f) ? __expf(e1 - mx) * rs : 0.f;
      w2 = (m4.z > 0.f) ? __expf(e2 - mx) * rs : 0.f;
      w3 = (m4.w > 0.f) ? __expf(e3 - mx) * rs : 0.f;
    } else {
      w0 = __expf(e0 - mx) * rs; w1 = __expf(e1 - mx) * rs;
      w2 = __expf(e2 - mx) * rs; w3 = __expf(e3 - mx) * rs;
    }
    Bs[kb + 0][jb] = w0; Bs[kb + 1][jb] = w1;
    Bs[kb + 2][jb] = w2; Bs[kb + 3][jb] = w3;
    __syncthreads();
    mm16(As, Bs, acc, ty, tx);
    __syncthreads();
  }
  const float g = gammaPtr[0];
  float* Yb = Y + (size_t)b * C_ * N_;
  const float* Rb = R + (size_t)b * C_ * N_;
#pragma unroll
  for (int i = 0; i < 4; ++i) {
    const int row = c0 + ty * 4 + i;
    const size_t off = (size_t)row * N_ + m0 + tx * 4;
    const float4 r4 = *(const float4*)(Rb + off);
    float4 o;
    o.x = g * acc[i][0] + r4.x; o.y = g * acc[i][1] + r4.y;
    o.z = g * acc[i][2] + r4.z; o.w = g * acc[i][3] + r4.w;
    *(float4*)(Yb + off) = o;
  }
}

// ---------------------------------------------------------------- chl row softmax
__global__ __launch_bounds__(256)
void chl_softmax(float* __restrict__ buf)
{
  const int row = blockIdx.x, tid = threadIdx.x;
  float* r = buf + (size_t)row * C_;
  const float v0 = -r[tid], v1 = -r[tid + 256];
  __shared__ float red[256];
  const float mx = blockReduceMax(fmaxf(v0, v1), red);
  const float e0 = __expf(v0 - mx), e1 = __expf(v1 - mx);
  const float s = blockReduceSum(e0 + e1, red);
  const float rs = 1.f / s;
  r[tid] = e0 * rs;
  r[tid + 256] = e1 * rs;
}

// ================================================================ launch
extern "C" void kernel_launch(void* const* d_in, const int* in_sizes, int n_in,
                              void* d_out, int out_size, void* d_ws, size_t ws_size,
                              hipStream_t stream)
{
  (void)in_sizes; (void)n_in; (void)out_size;
  const float* x      = (const float*)d_in[0];
  const float* wq     = (const float*)d_in[1];
  const float* bq     = (const float*)d_in[2];
  const float* wk     = (const float*)d_in[3];
  const float* bk     = (const float*)d_in[4];
  const float* wv0    = (const float*)d_in[5];
  const float* bv0    = (const float*)d_in[6];
  const float* c1w    = (const float*)d_in[7];
  const float* c1s    = (const float*)d_in[8];
  const float* c1b    = (const float*)d_in[9];
  const float* c2w    = (const float*)d_in[10];
  const float* c2s    = (const float*)d_in[11];
  const float* c2b    = (const float*)d_in[12];
  const float* gamma  = (const float*)d_in[13];
  const float* gamma1 = (const float*)d_in[14];
  const float* gamma2 = (const float*)d_in[15];
  const float* c1qw   = (const float*)d_in[16];
  const float* c1qs   = (const float*)d_in[17];
  const float* c1qb   = (const float*)d_in[18];
  const float* c1ew   = (const float*)d_in[19];
  const float* c1eb   = (const float*)d_in[20];
  const float* c2qw   = (const float*)d_in[21];
  const float* c2qs   = (const float*)d_in[22];
  const float* c2qb   = (const float*)d_in[23];
  const float* c2ew   = (const float*)d_in[24];
  const float* c2eb   = (const float*)d_in[25];
  const float* mask1  = (const float*)d_in[26];
  const float* mask2  = (const float*)d_in[27];

  const size_t QK = 589824;            // B*CR*N
  const size_t CQ = 1179648;           // B*C4*N
  const size_t VV = 4718592;           // B*C*N
  const size_t EE = 21233664;          // B*N*N
  const size_t ST = 55296;             // B*N*6
  const size_t CE = 262144;            // B*C4*C
  const size_t CA = 1048576;           // B*C*C
  const size_t ELEMS_B = CQ + VV + EE + ST + VV + CE + CA;       // 33,216,512
  const size_t ELEMS_A = ELEMS_B + EE / 2;                       // + bf16 P
  const int tier = (ws_size >= ELEMS_A * 4) ? 0
                 : (ws_size >= ELEMS_B * 4) ? 1 : 2;

  float* ws = (float*)d_ws;
  float *qbuf, *kbuf, *cq, *vbuf, *ebuf, *stb, *o0, *ce1, *cat_;
  unsigned short* Pbuf = nullptr;
  if (tier <= 1) {
    qbuf = ws; kbuf = ws + QK;         // dead after energy
    cq   = ws;                          // aliases q+k
    vbuf = ws + CQ;
    ebuf = vbuf + VV;
    stb  = ebuf + EE;
    o0   = stb + ST;
    ce1  = o0 + VV;
    cat_ = ce1 + CE;
    if (tier == 0) Pbuf = (unsigned short*)(cat_ + CA);
  } else {
    qbuf = ws; kbuf = qbuf + QK;       // live all passes
    cq   = kbuf + QK;
    vbuf = cq + CQ;
    stb  = vbuf + VV;
    o0   = stb + ST;
    ce1  = o0 + VV;
    cat_ = ce1 + CE;
    ebuf = nullptr;
  }
  float* t0 = (float*)d_out;           // pre-conv scratch aliases d_out
  float* o1 = o0;

  const dim3 TPB(256);
  const long long sxc = (long long)C_ * N_;
  const long long sqr = (long long)CR_ * N_;
  const long long sq4 = (long long)C4_ * N_;
  const long long sNN = (long long)N_ * N_;

  // ---- q/k projections fp32 (feed softmax logits); v bf16 MFMA (safe path)
  gemm_nn<<<dim3(36, 1, 4), TPB, 0, stream>>>(wq, 0, C_, x, sxc, N_,
                                              qbuf, sqr, N_, C_, nullptr, bq, 0);
  gemm_nn<<<dim3(36, 1, 4), TPB, 0, stream>>>(wk, 0, C_, x, sxc, N_,
                                              kbuf, sqr, N_, C_, nullptr, bk, 0);
  mfma_gemm<<<dim3(36, 8, 4), TPB, 0, stream>>>(wv0, 0, C_, x, sxc, N_, 1, 0,
      vbuf, sxc, N_, C_, nullptr, bv0, 0, nullptr, nullptr, 0);

  if (tier <= 1) {
    gemm_tn<<<dim3(36, 36, 4), TPB, 0, stream>>>(qbuf, sqr, N_, kbuf, sqr, N_,
                                                 ebuf, sNN, N_, CR_);
    softmax_stats<<<dim3(N_, 4), TPB, 0, stream>>>(ebuf, mask1, mask2, stb);
  } else {
    softmax_stats_rq<<<dim3(N_, 4), TPB, 0, stream>>>(qbuf, kbuf, mask1, mask2, stb);
  }

  // ---------------- pass 0
  if (tier == 0) {
    build_P<<<dim3(N_, 4), TPB, 0, stream>>>(ebuf, stb, 0, nullptr, Pbuf);
    mfma_gemm<<<dim3(36, 8, 4), TPB, 0, stream>>>(vbuf, sxc, N_, Pbuf, sNN, N_, 0, 1,
        t0, sxc, N_, N_, nullptr, nullptr, 0, gamma, x, sxc);
  } else if (tier == 1) {
    attn_apply<<<dim3(36, 8, 4), TPB, 0, stream>>>(vbuf, ebuf, stb, 0, nullptr,
                                                   gamma, x, t0);
  } else {
    attn_apply_rq<<<dim3(36, 8, 4), TPB, 0, stream>>>(vbuf, qbuf, kbuf, stb, 0, nullptr,
                                                      gamma, x, t0);
  }
  mfma_conv_split<<<dim3(36, 8, 4), TPB, 0, stream>>>(t0, c1w, c1s, c1b, o0);

  // chl #1 on o0 -> vbuf   (logit chain fp32: cq, ce1, expand)
  gemm_nn<<<dim3(36, 2, 4), TPB, 0, stream>>>(c1qw, 0, C_, o0, sxc, N_,
                                              cq, sq4, N_, C_, c1qs, c1qb, 1);
  gemm_nt<<<dim3(8, 2, 4), TPB, 0, stream>>>(cq, sq4, N_, o0, sxc, N_,
                                             ce1, (long long)C4_ * C_, C_, N_);
  gemm_nn<<<dim3(8, 8, 4), TPB, 0, stream>>>(c1ew, 0, C4_, ce1, (long long)C4_ * C_, C_,
                                             cat_, (long long)C_ * C_, C_, C4_,
                                             nullptr, c1eb, 0);
  chl_softmax<<<dim3(C_ * 4), TPB, 0, stream>>>(cat_);
  mfma_gemm<<<dim3(36, 8, 4), TPB, 0, stream>>>(cat_, (long long)C_ * C_, C_, o0, sxc, N_, 1, 0,
      vbuf, sxc, N_, C_, nullptr, nullptr, 0, nullptr, nullptr, 0);

  // ---------------- pass 1
  if (tier == 0) {
    build_P<<<dim3(N_, 4), TPB, 0, stream>>>(ebuf, stb, 1, mask1, Pbuf);
    mfma_gemm<<<dim3(36, 8, 4), TPB, 0, stream>>>(vbuf, sxc, N_, Pbuf, sNN, N_, 0, 1,
        t0, sxc, N_, N_, nullptr, nullptr, 0, gamma1, o0, sxc);
  } else if (tier == 1) {
    attn_apply<<<dim3(36, 8, 4), TPB, 0, stream>>>(vbuf, ebuf, stb, 1, mask1,
                                                   gamma1, o0, t0);
  } else {
    attn_apply_rq<<<dim3(36, 8, 4), TPB, 0, stream>>>(vbuf, qbuf, kbuf, stb, 1, mask1,
                                                      gamma1, o0, t0);
  }
  mfma_conv_split<<<dim3(36, 8, 4), TPB, 0, stream>>>(t0, c2w, c2s, c2b, o1);

  // chl #2 on o1 -> vbuf
  gemm_nn<<<dim3(36, 2, 4), TPB, 0, stream>>>(c2qw, 0, C_, o1, sxc, N_,
                                              cq, sq4, N_, C_, c2qs, c2qb, 1);
  gemm_nt<<<dim3(8, 2, 4), TPB, 0, stream>>>(cq, sq4, N_, o1, sxc, N_,
                                             ce1, (long long)C4_ * C_, C_, N_);
  gemm_nn<<<dim3(8, 8, 4), TPB, 0, stream>>>(c2ew, 0, C4_, ce1, (long long)C4_ * C_, C_,
                                             cat_, (long long)C_ * C_, C_, C4_,
                                             nullptr, c2eb, 0);
  chl_softmax<<<dim3(C_ * 4), TPB, 0, stream>>>(cat_);
  mfma_gemm<<<dim3(36, 8, 4), TPB, 0, stream>>>(cat_, (long long)C_ * C_, C_, o1, sxc, N_, 1, 0,
      vbuf, sxc, N_, C_, nullptr, nullptr, 0, nullptr, nullptr, 0);

  // ---------------- pass 2 -> d_out
  if (tier == 0) {
    build_P<<<dim3(N_, 4), TPB, 0, stream>>>(ebuf, stb, 2, mask2, Pbuf);
    mfma_gemm<<<dim3(36, 8, 4), TPB, 0, stream>>>(vbuf, sxc, N_, Pbuf, sNN, N_, 0, 1,
        (float*)d_out, sxc, N_, N_, nullptr, nullptr, 0, gamma2, o1, sxc);
  } else if (tier == 1) {
    attn_apply<<<dim3(36, 8, 4), TPB, 0, stream>>>(vbuf, ebuf, stb, 2, mask2,
                                                   gamma2, o1, (float*)d_out);
  } else {
    attn_apply_rq<<<dim3(36, 8, 4), TPB, 0, stream>>>(vbuf, qbuf, kbuf, stb, 2, mask2,
                                                      gamma2, o1, (float*)d_out);
  }
}

// Round 5
// 1392.793 us; speedup vs baseline: 2.4522x; 1.7399x over previous
//
#include <hip/hip_runtime.h>

#define B_  4
#define C_  512
#define H_  48
#define W_  48
#define N_  2304      // H_*W_
#define CR_ 64        // C_/R
#define C4_ 128       // C_/4
#define TK  16
#define LDSP 68       // fp32 helper tiles: 64 + 4 pad
#define PW  50        // padded width/height
#define PN  2500      // PW*PW
#define KW  4608      // C_*9

typedef short  s16x8 __attribute__((ext_vector_type(8)));   // 8 bf16 (4 VGPR)
typedef float  f32x4 __attribute__((ext_vector_type(4)));

// fp32 -> bf16 bits, round-to-nearest-even
__device__ __forceinline__ unsigned short f2bf(float f) {
  union { float f; unsigned int u; } v; v.f = f;
  const unsigned int u = v.u;
  return (unsigned short)((u + 0x7FFFu + ((u >> 16) & 1u)) >> 16);
}
__device__ __forceinline__ float bf2f(unsigned short h) {
  union { unsigned int u; float f; } v; v.u = ((unsigned int)h) << 16;
  return v.f;
}

// ---------------------------------------------------------------- reductions
__device__ __forceinline__ float blockReduceMax(float v, float* red) {
  const int tid = threadIdx.x;
  red[tid] = v; __syncthreads();
  for (int s = 128; s > 0; s >>= 1) {
    if (tid < s) red[tid] = fmaxf(red[tid], red[tid + s]);
    __syncthreads();
  }
  float r = red[0]; __syncthreads();
  return r;
}
__device__ __forceinline__ float blockReduceSum(float v, float* red) {
  const int tid = threadIdx.x;
  red[tid] = v; __syncthreads();
  for (int s = 128; s > 0; s >>= 1) {
    if (tid < s) red[tid] += red[tid + s];
    __syncthreads();
  }
  float r = red[0]; __syncthreads();
  return r;
}

// ---------------------------------------------------------------- fp32 micro-kernel
__device__ __forceinline__ void mm16(const float (*As)[LDSP], const float (*Bs)[LDSP],
                                     float acc[4][4], int ty, int tx)
{
#pragma unroll
  for (int kk = 0; kk < TK; ++kk) {
    const float4 a4 = *(const float4*)(&As[kk][ty * 4]);
    const float4 b4 = *(const float4*)(&Bs[kk][tx * 4]);
    const float av[4] = {a4.x, a4.y, a4.z, a4.w};
    const float bv[4] = {b4.x, b4.y, b4.z, b4.w};
#pragma unroll
    for (int i = 0; i < 4; ++i)
#pragma unroll
      for (int j = 0; j < 4; ++j)
        acc[i][j] = fmaf(av[i], bv[j], acc[i][j]);
  }
}

// ---------------------------------------------------------------- fp32 GEMM NN
__global__ __launch_bounds__(256)
void gemm_nn(const float* __restrict__ A, long long aStrideB, int lda,
             const float* __restrict__ B, long long bStrideB, int ldb,
             float* __restrict__ Y, long long yStrideB, int ldy,
             int K,
             const float* __restrict__ scale, const float* __restrict__ bias, int relu)
{
  __shared__ float As[TK][LDSP], Bs[TK][LDSP];
  const int b  = blockIdx.z;
  const int m0 = blockIdx.y * 64, n0 = blockIdx.x * 64;
  const int tid = threadIdx.x, tx = tid & 15, ty = tid >> 4;
  const int ia = tid >> 2, ka = (tid & 3) * 4;
  const int jb = tid & 63, kb = (tid >> 6) * 4;
  const float* Ab = A + (size_t)b * aStrideB;
  const float* Bb = B + (size_t)b * bStrideB;
  float acc[4][4] = {};
  for (int k0 = 0; k0 < K; k0 += TK) {
    const float4 a4 = *(const float4*)(Ab + (size_t)(m0 + ia) * lda + k0 + ka);
    As[ka + 0][ia] = a4.x; As[ka + 1][ia] = a4.y;
    As[ka + 2][ia] = a4.z; As[ka + 3][ia] = a4.w;
#pragma unroll
    for (int t = 0; t < 4; ++t)
      Bs[kb + t][jb] = Bb[(size_t)(k0 + kb + t) * ldb + n0 + jb];
    __syncthreads();
    mm16(As, Bs, acc, ty, tx);
    __syncthreads();
  }
  float* Yb = Y + (size_t)b * yStrideB;
#pragma unroll
  for (int i = 0; i < 4; ++i) {
    const int row = m0 + ty * 4 + i;
    const float s = scale ? scale[row] : 1.f;
    const float bb = bias ? bias[row] : 0.f;
    float4 o;
    o.x = acc[i][0] * s + bb; o.y = acc[i][1] * s + bb;
    o.z = acc[i][2] * s + bb; o.w = acc[i][3] * s + bb;
    if (relu) {
      o.x = fmaxf(o.x, 0.f); o.y = fmaxf(o.y, 0.f);
      o.z = fmaxf(o.z, 0.f); o.w = fmaxf(o.w, 0.f);
    }
    *(float4*)(Yb + (size_t)row * ldy + n0 + tx * 4) = o;
  }
}

// ---------------------------------------------------------------- fp32 GEMM NT (tiers 1/2)
__global__ __launch_bounds__(256)
void gemm_nt(const float* __restrict__ A, long long aStrideB, int lda,
             const float* __restrict__ B, long long bStrideB, int ldb,
             float* __restrict__ Y, long long yStrideB, int ldy, int K)
{
  __shared__ float As[TK][LDSP], Bs[TK][LDSP];
  const int b  = blockIdx.z;
  const int m0 = blockIdx.y * 64, n0 = blockIdx.x * 64;
  const int tid = threadIdx.x, tx = tid & 15, ty = tid >> 4;
  const int ia = tid >> 2, ka = (tid & 3) * 4;
  const float* Ab = A + (size_t)b * aStrideB;
  const float* Bb = B + (size_t)b * bStrideB;
  float acc[4][4] = {};
  for (int k0 = 0; k0 < K; k0 += TK) {
    const float4 a4 = *(const float4*)(Ab + (size_t)(m0 + ia) * lda + k0 + ka);
    As[ka + 0][ia] = a4.x; As[ka + 1][ia] = a4.y;
    As[ka + 2][ia] = a4.z; As[ka + 3][ia] = a4.w;
    const float4 b4 = *(const float4*)(Bb + (size_t)(n0 + ia) * ldb + k0 + ka);
    Bs[ka + 0][ia] = b4.x; Bs[ka + 1][ia] = b4.y;
    Bs[ka + 2][ia] = b4.z; Bs[ka + 3][ia] = b4.w;
    __syncthreads();
    mm16(As, Bs, acc, ty, tx);
    __syncthreads();
  }
  float* Yb = Y + (size_t)b * yStrideB;
#pragma unroll
  for (int i = 0; i < 4; ++i) {
    const int row = m0 + ty * 4 + i;
    float4 o = {acc[i][0], acc[i][1], acc[i][2], acc[i][3]};
    *(float4*)(Yb + (size_t)row * ldy + n0 + tx * 4) = o;
  }
}

// ---------------------------------------------------------------- fp32 GEMM NT split-K x4 (+atomicAdd)
__global__ __launch_bounds__(256)
void gemm_nt_splitk(const float* __restrict__ A, long long aStrideB, int lda,
                    const float* __restrict__ B, long long bStrideB, int ldb,
                    float* __restrict__ Y, long long yStrideB, int ldy, int K)
{
  __shared__ float As[TK][LDSP], Bs[TK][LDSP];
  const int z = blockIdx.z, b = z >> 2, ks = z & 3;
  const int kBeg = ks * (K / 4), kEnd = kBeg + K / 4;
  const int m0 = blockIdx.y * 64, n0 = blockIdx.x * 64;
  const int tid = threadIdx.x, tx = tid & 15, ty = tid >> 4;
  const int ia = tid >> 2, ka = (tid & 3) * 4;
  const float* Ab = A + (size_t)b * aStrideB;
  const float* Bb = B + (size_t)b * bStrideB;
  float acc[4][4] = {};
  for (int k0 = kBeg; k0 < kEnd; k0 += TK) {
    const float4 a4 = *(const float4*)(Ab + (size_t)(m0 + ia) * lda + k0 + ka);
    As[ka + 0][ia] = a4.x; As[ka + 1][ia] = a4.y;
    As[ka + 2][ia] = a4.z; As[ka + 3][ia] = a4.w;
    const float4 b4 = *(const float4*)(Bb + (size_t)(n0 + ia) * ldb + k0 + ka);
    Bs[ka + 0][ia] = b4.x; Bs[ka + 1][ia] = b4.y;
    Bs[ka + 2][ia] = b4.z; Bs[ka + 3][ia] = b4.w;
    __syncthreads();
    mm16(As, Bs, acc, ty, tx);
    __syncthreads();
  }
  float* Yb = Y + (size_t)b * yStrideB;
#pragma unroll
  for (int i = 0; i < 4; ++i) {
    const int row = m0 + ty * 4 + i;
#pragma unroll
    for (int j = 0; j < 4; ++j)
      atomicAdd(Yb + (size_t)row * ldy + n0 + tx * 4 + j, acc[i][j]);
  }
}

// ---------------------------------------------------------------- zero buffer
__global__ __launch_bounds__(256)
void zero_buf(float4* __restrict__ p, int n4)
{
  const int i = blockIdx.x * 256 + threadIdx.x;
  if (i < n4) p[i] = float4{0.f, 0.f, 0.f, 0.f};
}

// ---------------------------------------------------------------- fp32 GEMM TN (energy)
__global__ __launch_bounds__(256)
void gemm_tn(const float* __restrict__ A, long long aStrideB, int lda,
             const float* __restrict__ B, long long bStrideB, int ldb,
             float* __restrict__ Y, long long yStrideB, int ldy, int K)
{
  __shared__ float As[TK][LDSP], Bs[TK][LDSP];
  const int b  = blockIdx.z;
  const int m0 = blockIdx.y * 64, n0 = blockIdx.x * 64;
  const int tid = threadIdx.x, tx = tid & 15, ty = tid >> 4;
  const int i2 = tid & 63, k2 = (tid >> 6) * 4;
  const float* Ab = A + (size_t)b * aStrideB;
  const float* Bb = B + (size_t)b * bStrideB;
  float acc[4][4] = {};
  for (int k0 = 0; k0 < K; k0 += TK) {
#pragma unroll
    for (int t = 0; t < 4; ++t) {
      As[k2 + t][i2] = Ab[(size_t)(k0 + k2 + t) * lda + m0 + i2];
      Bs[k2 + t][i2] = Bb[(size_t)(k0 + k2 + t) * ldb + n0 + i2];
    }
    __syncthreads();
    mm16(As, Bs, acc, ty, tx);
    __syncthreads();
  }
  float* Yb = Y + (size_t)b * yStrideB;
#pragma unroll
  for (int i = 0; i < 4; ++i) {
    const int row = m0 + ty * 4 + i;
    float4 o = {acc[i][0], acc[i][1], acc[i][2], acc[i][3]};
    *(float4*)(Yb + (size_t)row * ldy + n0 + tx * 4) = o;
  }
}

// ================================================================ MFMA GEMM (flexible)
// A: aBf16? bf16[i][k] : fp32[i][k]
// B: bMode 0 = fp32 B[j][k] ; 1 = fp32 B[k][j] (transpose-stage) ; 2 = bf16 B[j][k]
// Y: outBf16? bf16 : fp32. Epilogue: Resid? gamma*acc+Resid : relu?(scale*acc+bias)
__global__ __launch_bounds__(256)
void mfma_gemm(const void* __restrict__ Av, int aBf16, long long aSB, int lda,
               const void* __restrict__ Bv, long long bSB, int ldb, int bMode,
               void* __restrict__ Yv, int outBf16, long long ySB, int ldy, int K,
               const float* __restrict__ scale, const float* __restrict__ bias,
               int relu,
               const float* __restrict__ gammaPtr, const float* __restrict__ Resid,
               long long rSB)
{
  __shared__ unsigned short As[64][72];
  __shared__ unsigned short Bs[64][72];
  const int b  = blockIdx.z;
  const int m0 = blockIdx.y * 64, n0 = blockIdx.x * 64;
  const int tid  = threadIdx.x;
  const int lane = tid & 63, wave = tid >> 6;
  const int wm = wave >> 1, wn = wave & 1;
  const int lrow = lane & 15, lk8 = (lane >> 4) * 8;
  const int sRow = tid >> 2, sK = (tid & 3) * 16;
  const int tj = tid & 63, tkg = (tid >> 6) * 16;
  f32x4 acc[2][2] = {};

  for (int k0 = 0; k0 < K; k0 += 64) {
    if (aBf16) {
      const unsigned short* Ab = (const unsigned short*)Av + (size_t)b * aSB;
      const unsigned short* src = Ab + (size_t)(m0 + sRow) * lda + k0 + sK;
      *(s16x8*)&As[sRow][sK]     = *(const s16x8*)(src);
      *(s16x8*)&As[sRow][sK + 8] = *(const s16x8*)(src + 8);
    } else {
      const float* Ab = (const float*)Av + (size_t)b * aSB;
      const float* src = Ab + (size_t)(m0 + sRow) * lda + k0 + sK;
      const float4 x0 = *(const float4*)(src);
      const float4 x1 = *(const float4*)(src + 4);
      const float4 x2 = *(const float4*)(src + 8);
      const float4 x3 = *(const float4*)(src + 12);
      s16x8 p0 = { (short)f2bf(x0.x), (short)f2bf(x0.y), (short)f2bf(x0.z), (short)f2bf(x0.w),
                   (short)f2bf(x1.x), (short)f2bf(x1.y), (short)f2bf(x1.z), (short)f2bf(x1.w) };
      s16x8 p1 = { (short)f2bf(x2.x), (short)f2bf(x2.y), (short)f2bf(x2.z), (short)f2bf(x2.w),
                   (short)f2bf(x3.x), (short)f2bf(x3.y), (short)f2bf(x3.z), (short)f2bf(x3.w) };
      *(s16x8*)&As[sRow][sK]     = p0;
      *(s16x8*)&As[sRow][sK + 8] = p1;
    }
    if (bMode == 1) {
      const float* Bb = (const float*)Bv + (size_t)b * bSB;
#pragma unroll
      for (int ii = 0; ii < 16; ii += 2) {
        const float v0 = Bb[(size_t)(k0 + tkg + ii)     * ldb + n0 + tj];
        const float v1 = Bb[(size_t)(k0 + tkg + ii + 1) * ldb + n0 + tj];
        *(unsigned int*)&Bs[tj][tkg + ii] =
            (unsigned int)f2bf(v0) | ((unsigned int)f2bf(v1) << 16);
      }
    } else if (bMode == 2) {
      const unsigned short* Bb = (const unsigned short*)Bv + (size_t)b * bSB;
      const unsigned short* src = Bb + (size_t)(n0 + sRow) * ldb + k0 + sK;
      *(s16x8*)&Bs[sRow][sK]     = *(const s16x8*)(src);
      *(s16x8*)&Bs[sRow][sK + 8] = *(const s16x8*)(src + 8);
    } else {
      const float* Bb = (const float*)Bv + (size_t)b * bSB;
      const float* src = Bb + (size_t)(n0 + sRow) * ldb + k0 + sK;
      const float4 x0 = *(const float4*)(src);
      const float4 x1 = *(const float4*)(src + 4);
      const float4 x2 = *(const float4*)(src + 8);
      const float4 x3 = *(const float4*)(src + 12);
      s16x8 p0 = { (short)f2bf(x0.x), (short)f2bf(x0.y), (short)f2bf(x0.z), (short)f2bf(x0.w),
                   (short)f2bf(x1.x), (short)f2bf(x1.y), (short)f2bf(x1.z), (short)f2bf(x1.w) };
      s16x8 p1 = { (short)f2bf(x2.x), (short)f2bf(x2.y), (short)f2bf(x2.z), (short)f2bf(x2.w),
                   (short)f2bf(x3.x), (short)f2bf(x3.y), (short)f2bf(x3.z), (short)f2bf(x3.w) };
      *(s16x8*)&Bs[sRow][sK]     = p0;
      *(s16x8*)&Bs[sRow][sK + 8] = p1;
    }
    __syncthreads();
#pragma unroll
    for (int kc = 0; kc < 2; ++kc) {
      const s16x8 a0 = *(const s16x8*)&As[wm * 32 + lrow     ][kc * 32 + lk8];
      const s16x8 a1 = *(const s16x8*)&As[wm * 32 + 16 + lrow][kc * 32 + lk8];
      const s16x8 b0 = *(const s16x8*)&Bs[wn * 32 + lrow     ][kc * 32 + lk8];
      const s16x8 b1 = *(const s16x8*)&Bs[wn * 32 + 16 + lrow][kc * 32 + lk8];
      acc[0][0] = __builtin_amdgcn_mfma_f32_16x16x32_bf16(a0, b0, acc[0][0], 0, 0, 0);
      acc[0][1] = __builtin_amdgcn_mfma_f32_16x16x32_bf16(a0, b1, acc[0][1], 0, 0, 0);
      acc[1][0] = __builtin_amdgcn_mfma_f32_16x16x32_bf16(a1, b0, acc[1][0], 0, 0, 0);
      acc[1][1] = __builtin_amdgcn_mfma_f32_16x16x32_bf16(a1, b1, acc[1][1], 0, 0, 0);
    }
    __syncthreads();
  }

  const float g = gammaPtr ? gammaPtr[0] : 0.f;
  const float* Rb = Resid ? Resid + (size_t)b * rSB : nullptr;
#pragma unroll
  for (int mt = 0; mt < 2; ++mt)
#pragma unroll
    for (int nt = 0; nt < 2; ++nt) {
      const int col = n0 + wn * 32 + nt * 16 + lrow;
      const int rbase = m0 + wm * 32 + mt * 16 + (lane >> 4) * 4;
#pragma unroll
      for (int i = 0; i < 4; ++i) {
        const int row = rbase + i;
        float v = acc[mt][nt][i];
        if (Rb) {
          v = g * v + Rb[(size_t)row * ldy + col];
        } else {
          const float s  = scale ? scale[row] : 1.f;
          const float bb = bias ? bias[row] : 0.f;
          v = v * s + bb;
          if (relu) v = fmaxf(v, 0.f);
        }
        if (outBf16)
          ((unsigned short*)Yv)[(size_t)b * ySB + (size_t)row * ldy + col] = f2bf(v);
        else
          ((float*)Yv)[(size_t)b * ySB + (size_t)row * ldy + col] = v;
      }
    }
}

// ================================================================ pre-pad + split + transpose: t0[C][N] -> Xh,Xl bf16 [PN][C]
__global__ __launch_bounds__(256)
void pad_split(const float* __restrict__ X, unsigned short* __restrict__ Xh,
               unsigned short* __restrict__ Xl)
{
  __shared__ float t[64][65];
  const int b = blockIdx.x, n0 = blockIdx.y * 64;
  const int tid = threadIdx.x;
  const float* Xb = X + (size_t)b * C_ * N_;
  unsigned short* Xhb = Xh + (size_t)b * PN * C_;
  unsigned short* Xlb = Xl + (size_t)b * PN * C_;
  for (int cs = 0; cs < 8; ++cs) {
    const int c0 = cs * 64;
    __syncthreads();
#pragma unroll
    for (int i = 0; i < 16; ++i) {
      const int cc = i * 4 + (tid >> 6);
      t[cc][tid & 63] = Xb[(size_t)(c0 + cc) * N_ + n0 + (tid & 63)];
    }
    __syncthreads();
    const int cc = tid & 63;
#pragma unroll
    for (int i = 0; i < 16; ++i) {
      const int nn = i * 4 + (tid >> 6);
      const int n = n0 + nn;
      const float v = t[cc][nn];
      const unsigned short hh = f2bf(v);
      const unsigned short ll = f2bf(v - bf2f(hh));
      const size_t p = (size_t)((n / 48 + 1) * PW + (n % 48) + 1) * C_ + c0 + cc;
      Xhb[p] = hh; Xlb[p] = ll;
    }
  }
}

// zero the padded ring (196 ring pcols x 512 c, both bufs)
__global__ __launch_bounds__(256)
void zero_ring(unsigned short* __restrict__ Xh, unsigned short* __restrict__ Xl)
{
  const int b = blockIdx.y, r = blockIdx.x;
  int pcol;
  if (r < 50)       pcol = r;                        // top row
  else if (r < 100) pcol = 49 * PW + (r - 50);       // bottom row
  else if (r < 148) pcol = (r - 100 + 1) * PW;       // left col (y'=1..48)
  else              pcol = (r - 148 + 1) * PW + 49;  // right col
  unsigned int* h = (unsigned int*)(Xh + ((size_t)b * PN + pcol) * C_);
  unsigned int* l = (unsigned int*)(Xl + ((size_t)b * PN + pcol) * C_);
  h[threadIdx.x] = 0u;
  l[threadIdx.x] = 0u;
}

// weights fp32 [O][c*9+tap] -> Wh,Wl bf16 [O][tap*512+c]
__global__ __launch_bounds__(256)
void wsplit(const float* __restrict__ W, unsigned short* __restrict__ Wh,
            unsigned short* __restrict__ Wl)
{
  const int o = blockIdx.x, tap = blockIdx.y;
#pragma unroll
  for (int i = 0; i < 2; ++i) {
    const int c = threadIdx.x + i * 256;
    const float v = W[(size_t)o * KW + c * 9 + tap];
    const unsigned short hh = f2bf(v);
    Wh[(size_t)o * KW + tap * C_ + c] = hh;
    Wl[(size_t)o * KW + tap * C_ + c] = f2bf(v - bf2f(hh));
  }
}

// fp32 [C][N] -> bf16 [N][C] (for v-proj / chl value-apply B operand)
__global__ __launch_bounds__(256)
void tr_bf16(const float* __restrict__ X, unsigned short* __restrict__ T)
{
  __shared__ float t[64][65];
  const int b = blockIdx.x, n0 = blockIdx.y * 64;
  const int tid = threadIdx.x;
  const float* Xb = X + (size_t)b * C_ * N_;
  unsigned short* Tb = T + (size_t)b * N_ * C_;
  for (int cs = 0; cs < 8; ++cs) {
    const int c0 = cs * 64;
    __syncthreads();
#pragma unroll
    for (int i = 0; i < 16; ++i) {
      const int cc = i * 4 + (tid >> 6);
      t[cc][tid & 63] = Xb[(size_t)(c0 + cc) * N_ + n0 + (tid & 63)];
    }
    __syncthreads();
    const int cc = tid & 63;
#pragma unroll
    for (int i = 0; i < 16; ++i) {
      const int nn = i * 4 + (tid >> 6);
      Tb[(size_t)(n0 + nn) * C_ + c0 + cc] = f2bf(t[cc][nn]);
    }
  }
}

// ================================================================ conv3x3 via tap-outer split-bf16 MFMA (tier 0)
__global__ __launch_bounds__(256)
void mfma_conv2(const unsigned short* __restrict__ Xh, const unsigned short* __restrict__ Xl,
                const unsigned short* __restrict__ Wh, const unsigned short* __restrict__ Wl,
                const float* __restrict__ sc, const float* __restrict__ bi,
                float* __restrict__ Y)
{
  __shared__ unsigned short Ah[64][72], Al[64][72];
  __shared__ unsigned short Bh[64][72], Bl[64][72];
  const int b  = blockIdx.z;
  const int m0 = blockIdx.y * 64, n0 = blockIdx.x * 64;
  const int tid  = threadIdx.x;
  const int lane = tid & 63, wave = tid >> 6;
  const int wm = wave >> 1, wn = wave & 1;
  const int lrow = lane & 15, lk8 = (lane >> 4) * 8;
  const int sRow = tid >> 2, sK = (tid & 3) * 16;
  const int nj = n0 + sRow;
  const int pbase = (nj / 48 + 1) * PW + (nj % 48) + 1;
  const unsigned short* Xhb = Xh + (size_t)b * PN * C_;
  const unsigned short* Xlb = Xl + (size_t)b * PN * C_;
  f32x4 acc[2][2] = {};

#pragma unroll
  for (int tap = 0; tap < 9; ++tap) {
    const int toff = (tap / 3 - 1) * PW + (tap % 3 - 1);
    const size_t bofs = (size_t)(pbase + toff) * C_;
    const size_t wrow = (size_t)(m0 + sRow) * KW + (size_t)tap * C_;
    for (int cs = 0; cs < 8; ++cs) {
      const int c0 = cs * 64;
      {
        const unsigned short* s = Wh + wrow + c0 + sK;
        *(s16x8*)&Ah[sRow][sK]     = *(const s16x8*)(s);
        *(s16x8*)&Ah[sRow][sK + 8] = *(const s16x8*)(s + 8);
        const unsigned short* s2 = Wl + wrow + c0 + sK;
        *(s16x8*)&Al[sRow][sK]     = *(const s16x8*)(s2);
        *(s16x8*)&Al[sRow][sK + 8] = *(const s16x8*)(s2 + 8);
      }
      {
        const unsigned short* s = Xhb + bofs + c0 + sK;
        *(s16x8*)&Bh[sRow][sK]     = *(const s16x8*)(s);
        *(s16x8*)&Bh[sRow][sK + 8] = *(const s16x8*)(s + 8);
        const unsigned short* s2 = Xlb + bofs + c0 + sK;
        *(s16x8*)&Bl[sRow][sK]     = *(const s16x8*)(s2);
        *(s16x8*)&Bl[sRow][sK + 8] = *(const s16x8*)(s2 + 8);
      }
      __syncthreads();
#pragma unroll
      for (int kc = 0; kc < 2; ++kc) {
        const s16x8 ah0 = *(const s16x8*)&Ah[wm * 32 + lrow     ][kc * 32 + lk8];
        const s16x8 ah1 = *(const s16x8*)&Ah[wm * 32 + 16 + lrow][kc * 32 + lk8];
        const s16x8 al0 = *(const s16x8*)&Al[wm * 32 + lrow     ][kc * 32 + lk8];
        const s16x8 al1 = *(const s16x8*)&Al[wm * 32 + 16 + lrow][kc * 32 + lk8];
        const s16x8 bh0 = *(const s16x8*)&Bh[wn * 32 + lrow     ][kc * 32 + lk8];
        const s16x8 bh1 = *(const s16x8*)&Bh[wn * 32 + 16 + lrow][kc * 32 + lk8];
        const s16x8 bl0 = *(const s16x8*)&Bl[wn * 32 + lrow     ][kc * 32 + lk8];
        const s16x8 bl1 = *(const s16x8*)&Bl[wn * 32 + 16 + lrow][kc * 32 + lk8];
        acc[0][0] = __builtin_amdgcn_mfma_f32_16x16x32_bf16(ah0, bh0, acc[0][0], 0, 0, 0);
        acc[0][1] = __builtin_amdgcn_mfma_f32_16x16x32_bf16(ah0, bh1, acc[0][1], 0, 0, 0);
        acc[1][0] = __builtin_amdgcn_mfma_f32_16x16x32_bf16(ah1, bh0, acc[1][0], 0, 0, 0);
        acc[1][1] = __builtin_amdgcn_mfma_f32_16x16x32_bf16(ah1, bh1, acc[1][1], 0, 0, 0);
        acc[0][0] = __builtin_amdgcn_mfma_f32_16x16x32_bf16(ah0, bl0, acc[0][0], 0, 0, 0);
        acc[0][1] = __builtin_amdgcn_mfma_f32_16x16x32_bf16(ah0, bl1, acc[0][1], 0, 0, 0);
        acc[1][0] = __builtin_amdgcn_mfma_f32_16x16x32_bf16(ah1, bl0, acc[1][0], 0, 0, 0);
        acc[1][1] = __builtin_amdgcn_mfma_f32_16x16x32_bf16(ah1, bl1, acc[1][1], 0, 0, 0);
        acc[0][0] = __builtin_amdgcn_mfma_f32_16x16x32_bf16(al0, bh0, acc[0][0], 0, 0, 0);
        acc[0][1] = __builtin_amdgcn_mfma_f32_16x16x32_bf16(al0, bh1, acc[0][1], 0, 0, 0);
        acc[1][0] = __builtin_amdgcn_mfma_f32_16x16x32_bf16(al1, bh0, acc[1][0], 0, 0, 0);
        acc[1][1] = __builtin_amdgcn_mfma_f32_16x16x32_bf16(al1, bh1, acc[1][1], 0, 0, 0);
      }
      __syncthreads();
    }
  }

  float* Yb = Y + (size_t)b * C_ * N_;
#pragma unroll
  for (int mt = 0; mt < 2; ++mt)
#pragma unroll
    for (int nt = 0; nt < 2; ++nt) {
      const int col = n0 + wn * 32 + nt * 16 + lrow;
      const int rbase = m0 + wm * 32 + mt * 16 + (lane >> 4) * 4;
#pragma unroll
      for (int i = 0; i < 4; ++i) {
        const int row = rbase + i;
        const float v = fmaxf(acc[mt][nt][i] * sc[row] + bi[row], 0.f);
        Yb[(size_t)row * N_ + col] = v;
      }
    }
}

// ================================================================ conv3x3 split-bf16 on-the-fly (tiers 1/2 fallback)
__global__ __launch_bounds__(256)
void mfma_conv_split(const float* __restrict__ X, const float* __restrict__ Wt,
                     const float* __restrict__ sc, const float* __restrict__ bi,
                     float* __restrict__ Y)
{
  __shared__ unsigned short Ah[64][72], Al[64][72];
  __shared__ unsigned short Bh[64][72], Bl[64][72];
  const int b  = blockIdx.z;
  const int m0 = blockIdx.y * 64, n0 = blockIdx.x * 64;
  const int tid  = threadIdx.x;
  const int lane = tid & 63, wave = tid >> 6;
  const int wm = wave >> 1, wn = wave & 1;
  const int lrow = lane & 15, lk8 = (lane >> 4) * 8;
  const int sRow = tid >> 2, sK = (tid & 3) * 16;
  const int tj = tid & 63, tkg = (tid >> 6) * 16;
  const int n = n0 + tj, yy = n / W_, xx = n - yy * W_;
  const float* Xb = X + (size_t)b * C_ * N_;
  const int K = KW;
  f32x4 acc[2][2] = {};

  for (int k0 = 0; k0 < K; k0 += 64) {
    {
      const float* src = Wt + (size_t)(m0 + sRow) * K + k0 + sK;
      unsigned short h[16], l[16];
#pragma unroll
      for (int t = 0; t < 16; ++t) {
        const float v = src[t];
        const unsigned short hh = f2bf(v);
        h[t] = hh;
        l[t] = f2bf(v - bf2f(hh));
      }
      *(s16x8*)&Ah[sRow][sK]     = *(s16x8*)&h[0];
      *(s16x8*)&Ah[sRow][sK + 8] = *(s16x8*)&h[8];
      *(s16x8*)&Al[sRow][sK]     = *(s16x8*)&l[0];
      *(s16x8*)&Al[sRow][sK + 8] = *(s16x8*)&l[8];
    }
    {
#pragma unroll
      for (int ii = 0; ii < 16; ii += 2) {
        unsigned int ph = 0, pl = 0;
#pragma unroll
        for (int hft = 0; hft < 2; ++hft) {
          const int kg = k0 + tkg + ii + hft;
          const int c = kg / 9, tap = kg - c * 9;
          const int t3 = tap / 3;
          const int iy = yy + t3 - 1, ix = xx + (tap - t3 * 3) - 1;
          float v = 0.f;
          if (iy >= 0 && iy < H_ && ix >= 0 && ix < W_)
            v = Xb[(size_t)c * N_ + iy * W_ + ix];
          const unsigned short hh = f2bf(v);
          const unsigned short ll = f2bf(v - bf2f(hh));
          ph |= ((unsigned int)hh) << (16 * hft);
          pl |= ((unsigned int)ll) << (16 * hft);
        }
        *(unsigned int*)&Bh[tj][tkg + ii] = ph;
        *(unsigned int*)&Bl[tj][tkg + ii] = pl;
      }
    }
    __syncthreads();
#pragma unroll
    for (int kc = 0; kc < 2; ++kc) {
      const s16x8 ah0 = *(const s16x8*)&Ah[wm * 32 + lrow     ][kc * 32 + lk8];
      const s16x8 ah1 = *(const s16x8*)&Ah[wm * 32 + 16 + lrow][kc * 32 + lk8];
      const s16x8 al0 = *(const s16x8*)&Al[wm * 32 + lrow     ][kc * 32 + lk8];
      const s16x8 al1 = *(const s16x8*)&Al[wm * 32 + 16 + lrow][kc * 32 + lk8];
      const s16x8 bh0 = *(const s16x8*)&Bh[wn * 32 + lrow     ][kc * 32 + lk8];
      const s16x8 bh1 = *(const s16x8*)&Bh[wn * 32 + 16 + lrow][kc * 32 + lk8];
      const s16x8 bl0 = *(const s16x8*)&Bl[wn * 32 + lrow     ][kc * 32 + lk8];
      const s16x8 bl1 = *(const s16x8*)&Bl[wn * 32 + 16 + lrow][kc * 32 + lk8];
      acc[0][0] = __builtin_amdgcn_mfma_f32_16x16x32_bf16(ah0, bh0, acc[0][0], 0, 0, 0);
      acc[0][1] = __builtin_amdgcn_mfma_f32_16x16x32_bf16(ah0, bh1, acc[0][1], 0, 0, 0);
      acc[1][0] = __builtin_amdgcn_mfma_f32_16x16x32_bf16(ah1, bh0, acc[1][0], 0, 0, 0);
      acc[1][1] = __builtin_amdgcn_mfma_f32_16x16x32_bf16(ah1, bh1, acc[1][1], 0, 0, 0);
      acc[0][0] = __builtin_amdgcn_mfma_f32_16x16x32_bf16(ah0, bl0, acc[0][0], 0, 0, 0);
      acc[0][1] = __builtin_amdgcn_mfma_f32_16x16x32_bf16(ah0, bl1, acc[0][1], 0, 0, 0);
      acc[1][0] = __builtin_amdgcn_mfma_f32_16x16x32_bf16(ah1, bl0, acc[1][0], 0, 0, 0);
      acc[1][1] = __builtin_amdgcn_mfma_f32_16x16x32_bf16(ah1, bl1, acc[1][1], 0, 0, 0);
      acc[0][0] = __builtin_amdgcn_mfma_f32_16x16x32_bf16(al0, bh0, acc[0][0], 0, 0, 0);
      acc[0][1] = __builtin_amdgcn_mfma_f32_16x16x32_bf16(al0, bh1, acc[0][1], 0, 0, 0);
      acc[1][0] = __builtin_amdgcn_mfma_f32_16x16x32_bf16(al1, bh0, acc[1][0], 0, 0, 0);
      acc[1][1] = __builtin_amdgcn_mfma_f32_16x16x32_bf16(al1, bh1, acc[1][1], 0, 0, 0);
    }
    __syncthreads();
  }

  float* Yb = Y + (size_t)b * C_ * N_;
#pragma unroll
  for (int mt = 0; mt < 2; ++mt)
#pragma unroll
    for (int nt = 0; nt < 2; ++nt) {
      const int col = n0 + wn * 32 + nt * 16 + lrow;
      const int rbase = m0 + wm * 32 + mt * 16 + (lane >> 4) * 4;
#pragma unroll
      for (int i = 0; i < 4; ++i) {
        const int row = rbase + i;
        const float v = fmaxf(acc[mt][nt][i] * sc[row] + bi[row], 0.f);
        Yb[(size_t)row * N_ + col] = v;
      }
    }
}

// ================================================================ P build (fp32 E -> bf16 P)
__global__ __launch_bounds__(256)
void build_P(const float* __restrict__ E, const float* __restrict__ st,
             int variant, const float* __restrict__ mask,
             unsigned short* __restrict__ P)
{
  const int m = blockIdx.x, b = blockIdx.y, t = threadIdx.x;
  const float* sp = st + ((size_t)b * N_ + m) * 6 + variant * 2;
  const float mx = sp[0], rs = 1.f / sp[1];
  const float* Er = E + ((size_t)b * N_ + m) * N_;
  unsigned short* Pr = P + ((size_t)b * N_ + m) * N_;
  const float* Mr = mask ? mask + (size_t)m * N_ : nullptr;
#pragma unroll
  for (int i = 0; i < 9; ++i) {
    const int idx = t + i * 256;
    float w = __expf(Er[idx] - mx) * rs;
    if (Mr && !(Mr[idx] > 0.f)) w = 0.f;
    Pr[idx] = f2bf(w);
  }
}

// ---------------------------------------------------------------- softmax stats (FULL)
__global__ __launch_bounds__(256)
void softmax_stats(const float* __restrict__ E, const float* __restrict__ M1,
                   const float* __restrict__ M2, float* __restrict__ st)
{
  const int row = blockIdx.x, b = blockIdx.y, tid = threadIdx.x;
  const float* er = E + ((size_t)b * N_ + row) * N_;
  const float* r1 = M1 + (size_t)row * N_;
  const float* r2 = M2 + (size_t)row * N_;
  float mx0 = -3.4e38f, mx1 = -3.4e38f, mx2 = -3.4e38f;
  for (int n = tid; n < N_; n += 256) {
    const float v = er[n];
    mx0 = fmaxf(mx0, v);
    if (r1[n] > 0.f) mx1 = fmaxf(mx1, v);
    if (r2[n] > 0.f) mx2 = fmaxf(mx2, v);
  }
  __shared__ float red[256];
  mx0 = blockReduceMax(mx0, red);
  mx1 = blockReduceMax(mx1, red);
  mx2 = blockReduceMax(mx2, red);
  float s0 = 0.f, s1 = 0.f, s2 = 0.f;
  for (int n = tid; n < N_; n += 256) {
    const float v = er[n];
    s0 += __expf(v - mx0);
    if (r1[n] > 0.f) s1 += __expf(v - mx1);
    if (r2[n] > 0.f) s2 += __expf(v - mx2);
  }
  s0 = blockReduceSum(s0, red);
  s1 = blockReduceSum(s1, red);
  s2 = blockReduceSum(s2, red);
  if (tid == 0) {
    float* o = st + ((size_t)b * N_ + row) * 6;
    o[0] = mx0; o[1] = s0; o[2] = mx1; o[3] = s1; o[4] = mx2; o[5] = s2;
  }
}

// ---------------------------------------------------------------- softmax stats (LITE)
__global__ __launch_bounds__(256)
void softmax_stats_rq(const float* __restrict__ q, const float* __restrict__ k,
                      const float* __restrict__ M1, const float* __restrict__ M2,
                      float* __restrict__ st)
{
  const int row = blockIdx.x, b = blockIdx.y, tid = threadIdx.x;
  __shared__ float qs[CR_];
  if (tid < CR_) qs[tid] = q[((size_t)b * CR_ + tid) * N_ + row];
  __syncthreads();
  const float* kb_ = k + (size_t)b * CR_ * N_;
  float ev[9], mk1[9], mk2[9];
  const float* r1 = M1 + (size_t)row * N_;
  const float* r2 = M2 + (size_t)row * N_;
#pragma unroll
  for (int i = 0; i < 9; ++i) {
    const int n = tid + i * 256;
    float e = 0.f;
#pragma unroll 8
    for (int c = 0; c < CR_; ++c) e = fmaf(qs[c], kb_[(size_t)c * N_ + n], e);
    ev[i] = e; mk1[i] = r1[n]; mk2[i] = r2[n];
  }
  float mx0 = -3.4e38f, mx1 = -3.4e38f, mx2 = -3.4e38f;
#pragma unroll
  for (int i = 0; i < 9; ++i) {
    const float v = ev[i];
    mx0 = fmaxf(mx0, v);
    if (mk1[i] > 0.f) mx1 = fmaxf(mx1, v);
    if (mk2[i] > 0.f) mx2 = fmaxf(mx2, v);
  }
  __shared__ float red[256];
  mx0 = blockReduceMax(mx0, red);
  mx1 = blockReduceMax(mx1, red);
  mx2 = blockReduceMax(mx2, red);
  float s0 = 0.f, s1 = 0.f, s2 = 0.f;
#pragma unroll
  for (int i = 0; i < 9; ++i) {
    const float v = ev[i];
    s0 += __expf(v - mx0);
    if (mk1[i] > 0.f) s1 += __expf(v - mx1);
    if (mk2[i] > 0.f) s2 += __expf(v - mx2);
  }
  s0 = blockReduceSum(s0, red);
  s1 = blockReduceSum(s1, red);
  s2 = blockReduceSum(s2, red);
  if (tid == 0) {
    float* o = st + ((size_t)b * N_ + row) * 6;
    o[0] = mx0; o[1] = s0; o[2] = mx1; o[3] = s1; o[4] = mx2; o[5] = s2;
  }
}

// ---------------------------------------------------------------- attention apply (fp32, tier 1)
__global__ __launch_bounds__(256)
void attn_apply(const float* __restrict__ V, const float* __restrict__ E,
                const float* __restrict__ st, int variant,
                const float* __restrict__ mask,
                const float* __restrict__ gammaPtr,
                const float* __restrict__ R, float* __restrict__ Y)
{
  __shared__ float As[TK][LDSP], Bs[TK][LDSP];
  const int b  = blockIdx.z;
  const int c0 = blockIdx.y * 64, m0 = blockIdx.x * 64;
  const int tid = threadIdx.x, tx = tid & 15, ty = tid >> 4;
  const int ia = tid >> 2, ka = (tid & 3) * 4;
  const int jb = tid >> 2, kb = (tid & 3) * 4;
  const int mrow = m0 + jb;
  const float* sp = st + ((size_t)b * N_ + mrow) * 6 + variant * 2;
  const float mx = sp[0];
  const float rs = 1.f / sp[1];
  const float* Vb = V + (size_t)b * C_ * N_;
  const float* Er = E + ((size_t)b * N_ + mrow) * N_;
  const float* Mr = mask ? mask + (size_t)mrow * N_ : nullptr;
  float acc[4][4] = {};
  for (int k0 = 0; k0 < N_; k0 += TK) {
    const float4 a4 = *(const float4*)(Vb + (size_t)(c0 + ia) * N_ + k0 + ka);
    As[ka + 0][ia] = a4.x; As[ka + 1][ia] = a4.y;
    As[ka + 2][ia] = a4.z; As[ka + 3][ia] = a4.w;
    const float4 e4 = *(const float4*)(Er + k0 + kb);
    float w0, w1, w2, w3;
    if (Mr) {
      const float4 m4 = *(const float4*)(Mr + k0 + kb);
      w0 = (m4.x > 0.f) ? __expf(e4.x - mx) * rs : 0.f;
      w1 = (m4.y > 0.f) ? __expf(e4.y - mx) * rs : 0.f;
      w2 = (m4.z > 0.f) ? __expf(e4.z - mx) * rs : 0.f;
      w3 = (m4.w > 0.f) ? __expf(e4.w - mx) * rs : 0.f;
    } else {
      w0 = __expf(e4.x - mx) * rs; w1 = __expf(e4.y - mx) * rs;
      w2 = __expf(e4.z - mx) * rs; w3 = __expf(e4.w - mx) * rs;
    }
    Bs[kb + 0][jb] = w0; Bs[kb + 1][jb] = w1;
    Bs[kb + 2][jb] = w2; Bs[kb + 3][jb] = w3;
    __syncthreads();
    mm16(As, Bs, acc, ty, tx);
    __syncthreads();
  }
  const float g = gammaPtr[0];
  float* Yb = Y + (size_t)b * C_ * N_;
  const float* Rb = R + (size_t)b * C_ * N_;
#pragma unroll
  for (int i = 0; i < 4; ++i) {
    const int row = c0 + ty * 4 + i;
    const size_t off = (size_t)row * N_ + m0 + tx * 4;
    const float4 r4 = *(const float4*)(Rb + off);
    float4 o;
    o.x = g * acc[i][0] + r4.x; o.y = g * acc[i][1] + r4.y;
    o.z = g * acc[i][2] + r4.z; o.w = g * acc[i][3] + r4.w;
    *(float4*)(Yb + off) = o;
  }
}

// ---------------------------------------------------------------- attention apply (fp32 LITE, tier 2)
__global__ __launch_bounds__(256)
void attn_apply_rq(const float* __restrict__ V, const float* __restrict__ q,
                   const float* __restrict__ k,
                   const float* __restrict__ st, int variant,
                   const float* __restrict__ mask,
                   const float* __restrict__ gammaPtr,
                   const float* __restrict__ R, float* __restrict__ Y)
{
  __shared__ float As[TK][LDSP], Bs[TK][LDSP];
  __shared__ float qs[CR_][65];
  __shared__ float kss[CR_][17];
  const int b  = blockIdx.z;
  const int c0 = blockIdx.y * 64, m0 = blockIdx.x * 64;
  const int tid = threadIdx.x, tx = tid & 15, ty = tid >> 4;
  const int ia = tid >> 2, ka = (tid & 3) * 4;
  const int jb = tid >> 2, kb = (tid & 3) * 4;
  const int mrow = m0 + jb;
  const float* qb_ = q + (size_t)b * CR_ * N_;
  const float* kb_ = k + (size_t)b * CR_ * N_;
#pragma unroll
  for (int i = 0; i < 16; ++i) {
    const int idx = tid + i * 256;
    const int c = idx >> 6, j = idx & 63;
    qs[c][j] = qb_[(size_t)c * N_ + m0 + j];
  }
  const float* sp = st + ((size_t)b * N_ + mrow) * 6 + variant * 2;
  const float mx = sp[0];
  const float rs = 1.f / sp[1];
  const float* Vb = V + (size_t)b * C_ * N_;
  const float* Mr = mask ? mask + (size_t)mrow * N_ : nullptr;
  float acc[4][4] = {};
  __syncthreads();
  for (int k0 = 0; k0 < N_; k0 += TK) {
    const float4 a4 = *(const float4*)(Vb + (size_t)(c0 + ia) * N_ + k0 + ka);
    As[ka + 0][ia] = a4.x; As[ka + 1][ia] = a4.y;
    As[ka + 2][ia] = a4.z; As[ka + 3][ia] = a4.w;
#pragma unroll
    for (int i = 0; i < 4; ++i) {
      const int idx = tid + i * 256;
      const int c = idx >> 4, nn = idx & 15;
      kss[c][nn] = kb_[(size_t)c * N_ + k0 + nn];
    }
    __syncthreads();
    float e0 = 0.f, e1 = 0.f, e2 = 0.f, e3 = 0.f;
#pragma unroll 16
    for (int c = 0; c < CR_; ++c) {
      const float qv = qs[c][jb];
      e0 = fmaf(qv, kss[c][kb + 0], e0);
      e1 = fmaf(qv, kss[c][kb + 1], e1);
      e2 = fmaf(qv, kss[c][kb + 2], e2);
      e3 = fmaf(qv, kss[c][kb + 3], e3);
    }
    float w0, w1, w2, w3;
    if (Mr) {
      const float4 m4 = *(const float4*)(Mr + k0 + kb);
      w0 = (m4.x > 0.f) ? __expf(e0 - mx) * rs : 0.f;
      w1 = (m4.y > 0.f) ? __expf(e1 - mx) * rs : 0.f;
      w2 = (m4.z > 0.f) ? __expf(e2 - mx) * rs : 0.f;
      w3 = (m4.w > 0.f) ? __expf(e3 - mx) * rs : 0.f;
    } else {
      w0 = __expf(e0 - mx) * rs; w1 = __expf(e1 - mx) * rs;
      w2 = __expf(e2 - mx) * rs; w3 = __expf(e3 - mx) * rs;
    }
    Bs[kb + 0][jb] = w0; Bs[kb + 1][jb] = w1;
    Bs[kb + 2][jb] = w2; Bs[kb + 3][jb] = w3;
    __syncthreads();
    mm16(As, Bs, acc, ty, tx);
    __syncthreads();
  }
  const float g = gammaPtr[0];
  float* Yb = Y + (size_t)b * C_ * N_;
  const float* Rb = R + (size_t)b * C_ * N_;
#pragma unroll
  for (int i = 0; i < 4; ++i) {
    const int row = c0 + ty * 4 + i;
    const size_t off = (size_t)row * N_ + m0 + tx * 4;
    const float4 r4 = *(const float4*)(Rb + off);
    float4 o;
    o.x = g * acc[i][0] + r4.x; o.y = g * acc[i][1] + r4.y;
    o.z = g * acc[i][2] + r4.z; o.w = g * acc[i][3] + r4.w;
    *(float4*)(Yb + off) = o;
  }
}

// ---------------------------------------------------------------- chl row softmax
__global__ __launch_bounds__(256)
void chl_softmax(float* __restrict__ buf)
{
  const int row = blockIdx.x, tid = threadIdx.x;
  float* r = buf + (size_t)row * C_;
  const float v0 = -r[tid], v1 = -r[tid + 256];
  __shared__ float red[256];
  const float mx = blockReduceMax(fmaxf(v0, v1), red);
  const float e0 = __expf(v0 - mx), e1 = __expf(v1 - mx);
  const float s = blockReduceSum(e0 + e1, red);
  const float rs = 1.f / s;
  r[tid] = e0 * rs;
  r[tid + 256] = e1 * rs;
}

// ================================================================ launch
extern "C" void kernel_launch(void* const* d_in, const int* in_sizes, int n_in,
                              void* d_out, int out_size, void* d_ws, size_t ws_size,
                              hipStream_t stream)
{
  (void)in_sizes; (void)n_in; (void)out_size;
  const float* x      = (const float*)d_in[0];
  const float* wq     = (const float*)d_in[1];
  const float* bq     = (const float*)d_in[2];
  const float* wk     = (const float*)d_in[3];
  const float* bk     = (const float*)d_in[4];
  const float* wv0    = (const float*)d_in[5];
  const float* bv0    = (const float*)d_in[6];
  const float* c1w    = (const float*)d_in[7];
  const float* c1s    = (const float*)d_in[8];
  const float* c1b    = (const float*)d_in[9];
  const float* c2w    = (const float*)d_in[10];
  const float* c2s    = (const float*)d_in[11];
  const float* c2b    = (const float*)d_in[12];
  const float* gamma  = (const float*)d_in[13];
  const float* gamma1 = (const float*)d_in[14];
  const float* gamma2 = (const float*)d_in[15];
  const float* c1qw   = (const float*)d_in[16];
  const float* c1qs   = (const float*)d_in[17];
  const float* c1qb   = (const float*)d_in[18];
  const float* c1ew   = (const float*)d_in[19];
  const float* c1eb   = (const float*)d_in[20];
  const float* c2qw   = (const float*)d_in[21];
  const float* c2qs   = (const float*)d_in[22];
  const float* c2qb   = (const float*)d_in[23];
  const float* c2ew   = (const float*)d_in[24];
  const float* c2eb   = (const float*)d_in[25];
  const float* mask1  = (const float*)d_in[26];
  const float* mask2  = (const float*)d_in[27];

  const size_t QK = 589824;            // B*CR*N
  const size_t CQ = 1179648;           // B*C4*N
  const size_t VV = 4718592;           // B*C*N
  const size_t EE = 21233664;          // B*N*N
  const size_t ST = 55296;             // B*N*6
  const size_t CE = 262144;            // B*C4*C
  const size_t CA = 1048576;           // B*C*C
  const size_t ELEMS_B = CQ + VV + EE + ST + VV + CE + CA;       // 33,216,512
  const size_t ELEMS_A = ELEMS_B + EE / 2;                       // + P/scratch region
  const int tier = (ws_size >= ELEMS_A * 4) ? 0
                 : (ws_size >= ELEMS_B * 4) ? 1 : 2;

  float* ws = (float*)d_ws;
  float *qbuf, *kbuf, *cq, *vbuf, *ebuf, *stb, *o0, *ce1, *cat_;
  unsigned short *Pbuf = nullptr, *oT = nullptr, *Xh = nullptr, *Xl = nullptr,
                 *Whs = nullptr, *Wls = nullptr;
  if (tier <= 1) {
    qbuf = ws; kbuf = ws + QK;         // dead after energy
    cq   = ws;                          // aliases q+k
    vbuf = ws + CQ;
    ebuf = vbuf + VV;
    stb  = ebuf + EE;
    o0   = stb + ST;
    ce1  = o0 + VV;
    cat_ = ce1 + CE;
    if (tier == 0) {
      unsigned short* reg = (unsigned short*)(cat_ + CA);   // EE shorts, time-shared
      Pbuf = reg;                      // live: build_P .. P-apply
      oT   = reg;                      // 4,718,592 shorts (x^T / o0^T / o1^T bf16)
      Xh   = reg + 4718592;            // 5,120,000 shorts (padded act hi)
      Xl   = Xh + 5120000;             // 5,120,000
      Whs  = Xl + 5120000;             // 2,359,296 (weights hi)
      Wls  = Whs + 2359296;            // 2,359,296 -> total 19,677,184 <= EE
    }
  } else {
    qbuf = ws; kbuf = qbuf + QK;       // live all passes
    cq   = kbuf + QK;
    vbuf = cq + CQ;
    stb  = vbuf + VV;
    o0   = stb + ST;
    ce1  = o0 + VV;
    cat_ = ce1 + CE;
    ebuf = nullptr;
  }
  float* t0 = (float*)d_out;           // pre-conv scratch aliases d_out
  float* o1 = o0;
  unsigned short* vb16 = (unsigned short*)vbuf;  // tier-0: bf16 V in vbuf region

  const dim3 TPB(256);
  const long long sxc = (long long)C_ * N_;
  const long long sqr = (long long)CR_ * N_;
  const long long sq4 = (long long)C4_ * N_;
  const long long sNN = (long long)N_ * N_;
  const long long sNC = (long long)N_ * C_;
  const long long sCC = (long long)C_ * C_;
  const long long sEC = (long long)C4_ * C_;

  // ---- q/k projections fp32 (feed softmax logits)
  gemm_nn<<<dim3(36, 1, 4), TPB, 0, stream>>>(wq, 0, C_, x, sxc, N_,
                                              qbuf, sqr, N_, C_, nullptr, bq, 0);
  gemm_nn<<<dim3(36, 1, 4), TPB, 0, stream>>>(wk, 0, C_, x, sxc, N_,
                                              kbuf, sqr, N_, C_, nullptr, bk, 0);
  // ---- v projection
  if (tier == 0) {
    tr_bf16<<<dim3(B_, 36), TPB, 0, stream>>>(x, oT);
    mfma_gemm<<<dim3(36, 8, 4), TPB, 0, stream>>>(wv0, 0, 0, C_, oT, sNC, C_, 2,
        vb16, 1, sxc, N_, C_, nullptr, bv0, 0, nullptr, nullptr, 0);
  } else {
    mfma_gemm<<<dim3(36, 8, 4), TPB, 0, stream>>>(wv0, 0, 0, C_, x, sxc, N_, 1,
        vbuf, 0, sxc, N_, C_, nullptr, bv0, 0, nullptr, nullptr, 0);
  }

  if (tier <= 1) {
    gemm_tn<<<dim3(36, 36, 4), TPB, 0, stream>>>(qbuf, sqr, N_, kbuf, sqr, N_,
                                                 ebuf, sNN, N_, CR_);
    softmax_stats<<<dim3(N_, 4), TPB, 0, stream>>>(ebuf, mask1, mask2, stb);
  } else {
    softmax_stats_rq<<<dim3(N_, 4), TPB, 0, stream>>>(qbuf, kbuf, mask1, mask2, stb);
  }

  for (int pass = 0; pass < 3; ++pass) {
    const float* msk = (pass == 0) ? nullptr : (pass == 1 ? mask1 : mask2);
    const float* gm  = (pass == 0) ? gamma : (pass == 1 ? gamma1 : gamma2);
    const float* res = (pass == 0) ? x : o0;
    float* dst = (pass == 2) ? (float*)d_out : t0;

    // ---- attention apply: dst = gm * V . P^T + res
    if (tier == 0) {
      build_P<<<dim3(N_, 4), TPB, 0, stream>>>(ebuf, stb, pass, msk, Pbuf);
      mfma_gemm<<<dim3(36, 8, 4), TPB, 0, stream>>>(vb16, 1, sxc, N_, Pbuf, sNN, N_, 2,
          dst, 0, sxc, N_, N_, nullptr, nullptr, 0, gm, res, sxc);
    } else if (tier == 1) {
      attn_apply<<<dim3(36, 8, 4), TPB, 0, stream>>>(vbuf, ebuf, stb, pass, msk,
                                                     gm, res, dst);
    } else {
      attn_apply_rq<<<dim3(36, 8, 4), TPB, 0, stream>>>(vbuf, qbuf, kbuf, stb, pass, msk,
                                                        gm, res, dst);
    }
    if (pass == 2) break;

    // ---- conv3x3 + BN + ReLU  (dst -> o0)
    const float* cw = (pass == 0) ? c1w : c2w;
    const float* cs = (pass == 0) ? c1s : c2s;
    const float* cb = (pass == 0) ? c1b : c2b;
    if (tier == 0) {
      pad_split<<<dim3(B_, 36), TPB, 0, stream>>>(dst, Xh, Xl);
      zero_ring<<<dim3(196, B_), TPB, 0, stream>>>(Xh, Xl);
      wsplit<<<dim3(512, 9), TPB, 0, stream>>>(cw, Whs, Wls);
      mfma_conv2<<<dim3(36, 8, 4), TPB, 0, stream>>>(Xh, Xl, Whs, Wls, cs, cb, o0);
    } else {
      mfma_conv_split<<<dim3(36, 8, 4), TPB, 0, stream>>>(dst, cw, cs, cb, o0);
    }

    // ---- chl block on o0 -> vbuf (logit chain fp32)
    const float* qw = (pass == 0) ? c1qw : c2qw;
    const float* qs = (pass == 0) ? c1qs : c2qs;
    const float* qb = (pass == 0) ? c1qb : c2qb;
    const float* ew = (pass == 0) ? c1ew : c2ew;
    const float* eb = (pass == 0) ? c1eb : c2eb;
    gemm_nn<<<dim3(36, 2, 4), TPB, 0, stream>>>(qw, 0, C_, o0, sxc, N_,
                                                cq, sq4, N_, C_, qs, qb, 1);
    zero_buf<<<dim3(256), TPB, 0, stream>>>((float4*)ce1, (int)(CE / 4));
    gemm_nt_splitk<<<dim3(8, 2, 16), TPB, 0, stream>>>(cq, sq4, N_, o0, sxc, N_,
                                                       ce1, sEC, C_, N_);
    gemm_nn<<<dim3(8, 8, 4), TPB, 0, stream>>>(ew, 0, C4_, ce1, sEC, C_,
                                               cat_, sCC, C_, C4_, nullptr, eb, 0);
    chl_softmax<<<dim3(C_ * 4), TPB, 0, stream>>>(cat_);
    if (tier == 0) {
      tr_bf16<<<dim3(B_, 36), TPB, 0, stream>>>(o0, oT);
      mfma_gemm<<<dim3(36, 8, 4), TPB, 0, stream>>>(cat_, 0, sCC, C_, oT, sNC, C_, 2,
          vb16, 1, sxc, N_, C_, nullptr, nullptr, 0, nullptr, nullptr, 0);
    } else {
      mfma_gemm<<<dim3(36, 8, 4), TPB, 0, stream>>>(cat_, 0, sCC, C_, o0, sxc, N_, 1,
          vbuf, 0, sxc, N_, C_, nullptr, nullptr, 0, nullptr, nullptr, 0);
    }
  }
  (void)o1;
}

// Round 6
// 1304.610 us; speedup vs baseline: 2.6180x; 1.0676x over previous
//
#include <hip/hip_runtime.h>

#define B_  4
#define C_  512
#define H_  48
#define W_  48
#define N_  2304      // H_*W_
#define CR_ 64        // C_/R
#define C4_ 128       // C_/4
#define TK  16
#define LDSP 68       // fp32 helper tiles: 64 + 4 pad
#define PW  50        // padded width/height
#define PN  2500      // PW*PW
#define KW  4608      // C_*9

typedef short  s16x8 __attribute__((ext_vector_type(8)));   // 8 bf16 (4 VGPR)
typedef float  f32x4 __attribute__((ext_vector_type(4)));

// fp32 -> bf16 bits, round-to-nearest-even
__device__ __forceinline__ unsigned short f2bf(float f) {
  union { float f; unsigned int u; } v; v.f = f;
  const unsigned int u = v.u;
  return (unsigned short)((u + 0x7FFFu + ((u >> 16) & 1u)) >> 16);
}
__device__ __forceinline__ float bf2f(unsigned short h) {
  union { unsigned int u; float f; } v; v.u = ((unsigned int)h) << 16;
  return v.f;
}

// ---------------------------------------------------------------- reductions
__device__ __forceinline__ float blockReduceMax(float v, float* red) {
  const int tid = threadIdx.x;
  red[tid] = v; __syncthreads();
  for (int s = 128; s > 0; s >>= 1) {
    if (tid < s) red[tid] = fmaxf(red[tid], red[tid + s]);
    __syncthreads();
  }
  float r = red[0]; __syncthreads();
  return r;
}
__device__ __forceinline__ float blockReduceSum(float v, float* red) {
  const int tid = threadIdx.x;
  red[tid] = v; __syncthreads();
  for (int s = 128; s > 0; s >>= 1) {
    if (tid < s) red[tid] += red[tid + s];
    __syncthreads();
  }
  float r = red[0]; __syncthreads();
  return r;
}

// ---------------------------------------------------------------- fp32 micro-kernel (fallback tiers)
__device__ __forceinline__ void mm16(const float (*As)[LDSP], const float (*Bs)[LDSP],
                                     float acc[4][4], int ty, int tx)
{
#pragma unroll
  for (int kk = 0; kk < TK; ++kk) {
    const float4 a4 = *(const float4*)(&As[kk][ty * 4]);
    const float4 b4 = *(const float4*)(&Bs[kk][tx * 4]);
    const float av[4] = {a4.x, a4.y, a4.z, a4.w};
    const float bv[4] = {b4.x, b4.y, b4.z, b4.w};
#pragma unroll
    for (int i = 0; i < 4; ++i)
#pragma unroll
      for (int j = 0; j < 4; ++j)
        acc[i][j] = fmaf(av[i], bv[j], acc[i][j]);
  }
}

// ---------------------------------------------------------------- fp32 GEMM NN (fallback)
__global__ __launch_bounds__(256)
void gemm_nn(const float* __restrict__ A, long long aStrideB, int lda,
             const float* __restrict__ B, long long bStrideB, int ldb,
             float* __restrict__ Y, long long yStrideB, int ldy,
             int K,
             const float* __restrict__ scale, const float* __restrict__ bias, int relu)
{
  __shared__ float As[TK][LDSP], Bs[TK][LDSP];
  const int b  = blockIdx.z;
  const int m0 = blockIdx.y * 64, n0 = blockIdx.x * 64;
  const int tid = threadIdx.x, tx = tid & 15, ty = tid >> 4;
  const int ia = tid >> 2, ka = (tid & 3) * 4;
  const int jb = tid & 63, kb = (tid >> 6) * 4;
  const float* Ab = A + (size_t)b * aStrideB;
  const float* Bb = B + (size_t)b * bStrideB;
  float acc[4][4] = {};
  for (int k0 = 0; k0 < K; k0 += TK) {
    const float4 a4 = *(const float4*)(Ab + (size_t)(m0 + ia) * lda + k0 + ka);
    As[ka + 0][ia] = a4.x; As[ka + 1][ia] = a4.y;
    As[ka + 2][ia] = a4.z; As[ka + 3][ia] = a4.w;
#pragma unroll
    for (int t = 0; t < 4; ++t)
      Bs[kb + t][jb] = Bb[(size_t)(k0 + kb + t) * ldb + n0 + jb];
    __syncthreads();
    mm16(As, Bs, acc, ty, tx);
    __syncthreads();
  }
  float* Yb = Y + (size_t)b * yStrideB;
#pragma unroll
  for (int i = 0; i < 4; ++i) {
    const int row = m0 + ty * 4 + i;
    const float s = scale ? scale[row] : 1.f;
    const float bb = bias ? bias[row] : 0.f;
    float4 o;
    o.x = acc[i][0] * s + bb; o.y = acc[i][1] * s + bb;
    o.z = acc[i][2] * s + bb; o.w = acc[i][3] * s + bb;
    if (relu) {
      o.x = fmaxf(o.x, 0.f); o.y = fmaxf(o.y, 0.f);
      o.z = fmaxf(o.z, 0.f); o.w = fmaxf(o.w, 0.f);
    }
    *(float4*)(Yb + (size_t)row * ldy + n0 + tx * 4) = o;
  }
}

// ---------------------------------------------------------------- fp32 GEMM NT split-K x4 (fallback)
__global__ __launch_bounds__(256)
void gemm_nt_splitk(const float* __restrict__ A, long long aStrideB, int lda,
                    const float* __restrict__ B, long long bStrideB, int ldb,
                    float* __restrict__ Y, long long yStrideB, int ldy, int K)
{
  __shared__ float As[TK][LDSP], Bs[TK][LDSP];
  const int z = blockIdx.z, b = z >> 2, ks = z & 3;
  const int kBeg = ks * (K / 4), kEnd = kBeg + K / 4;
  const int m0 = blockIdx.y * 64, n0 = blockIdx.x * 64;
  const int tid = threadIdx.x, tx = tid & 15, ty = tid >> 4;
  const int ia = tid >> 2, ka = (tid & 3) * 4;
  const float* Ab = A + (size_t)b * aStrideB;
  const float* Bb = B + (size_t)b * bStrideB;
  float acc[4][4] = {};
  for (int k0 = kBeg; k0 < kEnd; k0 += TK) {
    const float4 a4 = *(const float4*)(Ab + (size_t)(m0 + ia) * lda + k0 + ka);
    As[ka + 0][ia] = a4.x; As[ka + 1][ia] = a4.y;
    As[ka + 2][ia] = a4.z; As[ka + 3][ia] = a4.w;
    const float4 b4 = *(const float4*)(Bb + (size_t)(n0 + ia) * ldb + k0 + ka);
    Bs[ka + 0][ia] = b4.x; Bs[ka + 1][ia] = b4.y;
    Bs[ka + 2][ia] = b4.z; Bs[ka + 3][ia] = b4.w;
    __syncthreads();
    mm16(As, Bs, acc, ty, tx);
    __syncthreads();
  }
  float* Yb = Y + (size_t)b * yStrideB;
#pragma unroll
  for (int i = 0; i < 4; ++i) {
    const int row = m0 + ty * 4 + i;
#pragma unroll
    for (int j = 0; j < 4; ++j)
      atomicAdd(Yb + (size_t)row * ldy + n0 + tx * 4 + j, acc[i][j]);
  }
}

// ---------------------------------------------------------------- zero buffer
__global__ __launch_bounds__(256)
void zero_buf(float4* __restrict__ p, int n4)
{
  const int i = blockIdx.x * 256 + threadIdx.x;
  if (i < n4) p[i] = float4{0.f, 0.f, 0.f, 0.f};
}

// ---------------------------------------------------------------- fp32 GEMM TN (fallback energy)
__global__ __launch_bounds__(256)
void gemm_tn(const float* __restrict__ A, long long aStrideB, int lda,
             const float* __restrict__ B, long long bStrideB, int ldb,
             float* __restrict__ Y, long long yStrideB, int ldy, int K)
{
  __shared__ float As[TK][LDSP], Bs[TK][LDSP];
  const int b  = blockIdx.z;
  const int m0 = blockIdx.y * 64, n0 = blockIdx.x * 64;
  const int tid = threadIdx.x, tx = tid & 15, ty = tid >> 4;
  const int i2 = tid & 63, k2 = (tid >> 6) * 4;
  const float* Ab = A + (size_t)b * aStrideB;
  const float* Bb = B + (size_t)b * bStrideB;
  float acc[4][4] = {};
  for (int k0 = 0; k0 < K; k0 += TK) {
#pragma unroll
    for (int t = 0; t < 4; ++t) {
      As[k2 + t][i2] = Ab[(size_t)(k0 + k2 + t) * lda + m0 + i2];
      Bs[k2 + t][i2] = Bb[(size_t)(k0 + k2 + t) * ldb + n0 + i2];
    }
    __syncthreads();
    mm16(As, Bs, acc, ty, tx);
    __syncthreads();
  }
  float* Yb = Y + (size_t)b * yStrideB;
#pragma unroll
  for (int i = 0; i < 4; ++i) {
    const int row = m0 + ty * 4 + i;
    float4 o = {acc[i][0], acc[i][1], acc[i][2], acc[i][3]};
    *(float4*)(Yb + (size_t)row * ldy + n0 + tx * 4) = o;
  }
}

// ================================================================ MFMA GEMM (single bf16, non-logit paths)
// A: aBf16? bf16[i][k] : fp32[i][k]
// B: bMode 0 = fp32 B[j][k] ; 1 = fp32 B[k][j] (transpose-stage) ; 2 = bf16 B[j][k]
__global__ __launch_bounds__(256)
void mfma_gemm(const void* __restrict__ Av, int aBf16, long long aSB, int lda,
               const void* __restrict__ Bv, long long bSB, int ldb, int bMode,
               void* __restrict__ Yv, int outBf16, long long ySB, int ldy, int K,
               const float* __restrict__ scale, const float* __restrict__ bias,
               int relu,
               const float* __restrict__ gammaPtr, const float* __restrict__ Resid,
               long long rSB)
{
  __shared__ unsigned short As[64][72];
  __shared__ unsigned short Bs[64][72];
  const int b  = blockIdx.z;
  const int m0 = blockIdx.y * 64, n0 = blockIdx.x * 64;
  const int tid  = threadIdx.x;
  const int lane = tid & 63, wave = tid >> 6;
  const int wm = wave >> 1, wn = wave & 1;
  const int lrow = lane & 15, lk8 = (lane >> 4) * 8;
  const int sRow = tid >> 2, sK = (tid & 3) * 16;
  const int tj = tid & 63, tkg = (tid >> 6) * 16;
  f32x4 acc[2][2] = {};

  for (int k0 = 0; k0 < K; k0 += 64) {
    if (aBf16) {
      const unsigned short* Ab = (const unsigned short*)Av + (size_t)b * aSB;
      const unsigned short* src = Ab + (size_t)(m0 + sRow) * lda + k0 + sK;
      *(s16x8*)&As[sRow][sK]     = *(const s16x8*)(src);
      *(s16x8*)&As[sRow][sK + 8] = *(const s16x8*)(src + 8);
    } else {
      const float* Ab = (const float*)Av + (size_t)b * aSB;
      const float* src = Ab + (size_t)(m0 + sRow) * lda + k0 + sK;
      const float4 x0 = *(const float4*)(src);
      const float4 x1 = *(const float4*)(src + 4);
      const float4 x2 = *(const float4*)(src + 8);
      const float4 x3 = *(const float4*)(src + 12);
      s16x8 p0 = { (short)f2bf(x0.x), (short)f2bf(x0.y), (short)f2bf(x0.z), (short)f2bf(x0.w),
                   (short)f2bf(x1.x), (short)f2bf(x1.y), (short)f2bf(x1.z), (short)f2bf(x1.w) };
      s16x8 p1 = { (short)f2bf(x2.x), (short)f2bf(x2.y), (short)f2bf(x2.z), (short)f2bf(x2.w),
                   (short)f2bf(x3.x), (short)f2bf(x3.y), (short)f2bf(x3.z), (short)f2bf(x3.w) };
      *(s16x8*)&As[sRow][sK]     = p0;
      *(s16x8*)&As[sRow][sK + 8] = p1;
    }
    if (bMode == 1) {
      const float* Bb = (const float*)Bv + (size_t)b * bSB;
#pragma unroll
      for (int ii = 0; ii < 16; ii += 2) {
        const float v0 = Bb[(size_t)(k0 + tkg + ii)     * ldb + n0 + tj];
        const float v1 = Bb[(size_t)(k0 + tkg + ii + 1) * ldb + n0 + tj];
        *(unsigned int*)&Bs[tj][tkg + ii] =
            (unsigned int)f2bf(v0) | ((unsigned int)f2bf(v1) << 16);
      }
    } else if (bMode == 2) {
      const unsigned short* Bb = (const unsigned short*)Bv + (size_t)b * bSB;
      const unsigned short* src = Bb + (size_t)(n0 + sRow) * ldb + k0 + sK;
      *(s16x8*)&Bs[sRow][sK]     = *(const s16x8*)(src);
      *(s16x8*)&Bs[sRow][sK + 8] = *(const s16x8*)(src + 8);
    } else {
      const float* Bb = (const float*)Bv + (size_t)b * bSB;
      const float* src = Bb + (size_t)(n0 + sRow) * ldb + k0 + sK;
      const float4 x0 = *(const float4*)(src);
      const float4 x1 = *(const float4*)(src + 4);
      const float4 x2 = *(const float4*)(src + 8);
      const float4 x3 = *(const float4*)(src + 12);
      s16x8 p0 = { (short)f2bf(x0.x), (short)f2bf(x0.y), (short)f2bf(x0.z), (short)f2bf(x0.w),
                   (short)f2bf(x1.x), (short)f2bf(x1.y), (short)f2bf(x1.z), (short)f2bf(x1.w) };
      s16x8 p1 = { (short)f2bf(x2.x), (short)f2bf(x2.y), (short)f2bf(x2.z), (short)f2bf(x2.w),
                   (short)f2bf(x3.x), (short)f2bf(x3.y), (short)f2bf(x3.z), (short)f2bf(x3.w) };
      *(s16x8*)&Bs[sRow][sK]     = p0;
      *(s16x8*)&Bs[sRow][sK + 8] = p1;
    }
    __syncthreads();
#pragma unroll
    for (int kc = 0; kc < 2; ++kc) {
      const s16x8 a0 = *(const s16x8*)&As[wm * 32 + lrow     ][kc * 32 + lk8];
      const s16x8 a1 = *(const s16x8*)&As[wm * 32 + 16 + lrow][kc * 32 + lk8];
      const s16x8 b0 = *(const s16x8*)&Bs[wn * 32 + lrow     ][kc * 32 + lk8];
      const s16x8 b1 = *(const s16x8*)&Bs[wn * 32 + 16 + lrow][kc * 32 + lk8];
      acc[0][0] = __builtin_amdgcn_mfma_f32_16x16x32_bf16(a0, b0, acc[0][0], 0, 0, 0);
      acc[0][1] = __builtin_amdgcn_mfma_f32_16x16x32_bf16(a0, b1, acc[0][1], 0, 0, 0);
      acc[1][0] = __builtin_amdgcn_mfma_f32_16x16x32_bf16(a1, b0, acc[1][0], 0, 0, 0);
      acc[1][1] = __builtin_amdgcn_mfma_f32_16x16x32_bf16(a1, b1, acc[1][1], 0, 0, 0);
    }
    __syncthreads();
  }

  const float g = gammaPtr ? gammaPtr[0] : 0.f;
  const float* Rb = Resid ? Resid + (size_t)b * rSB : nullptr;
#pragma unroll
  for (int mt = 0; mt < 2; ++mt)
#pragma unroll
    for (int nt = 0; nt < 2; ++nt) {
      const int col = n0 + wn * 32 + nt * 16 + lrow;
      const int rbase = m0 + wm * 32 + mt * 16 + (lane >> 4) * 4;
#pragma unroll
      for (int i = 0; i < 4; ++i) {
        const int row = rbase + i;
        float v = acc[mt][nt][i];
        if (Rb) {
          v = g * v + Rb[(size_t)row * ldy + col];
        } else {
          const float s  = scale ? scale[row] : 1.f;
          const float bb = bias ? bias[row] : 0.f;
          v = v * s + bb;
          if (relu) v = fmaxf(v, 0.f);
        }
        if (outBf16)
          ((unsigned short*)Yv)[(size_t)b * ySB + (size_t)row * ldy + col] = f2bf(v);
        else
          ((float*)Yv)[(size_t)b * ySB + (size_t)row * ldy + col] = v;
      }
    }
}

// ================================================================ split-bf16 MFMA GEMM (fp32-grade, logit chain)
// Y[i][j] = sum_k A[i][k]*B[j][k]   (both operands k-contiguous)
// A: fp32, split on the fly. B: bPre? (B0=hi,B1=lo bf16 [j][k]) : fp32 B0[j][k] split-fly.
// outMode: 0 Y[i*ldy+j] ; 1 Y[j*ldy+i] ; 2 atomicAdd(Y[j*ldy+i]) (caller zeroes; scale/bias must be null)
// splitK: gridDim.z = B_ * nSplit.
__global__ __launch_bounds__(256)
void mfma_sp(const float* __restrict__ A, long long aSB, int lda,
             const void* __restrict__ B0v, const void* __restrict__ B1v,
             long long bSB, int ldb, int bPre,
             float* __restrict__ Y, long long ySB, int ldy, int outMode,
             int K, int nSplit,
             const float* __restrict__ scale, const float* __restrict__ bias, int relu)
{
  __shared__ unsigned short Ah[64][72], Al[64][72];
  __shared__ unsigned short Bh[64][72], Bl[64][72];
  const int z = blockIdx.z;
  const int b = z / nSplit, ks = z % nSplit;
  const int kLen = K / nSplit, kBeg = ks * kLen, kEnd = kBeg + kLen;
  const int m0 = blockIdx.y * 64, n0 = blockIdx.x * 64;
  const int tid  = threadIdx.x;
  const int lane = tid & 63, wave = tid >> 6;
  const int wm = wave >> 1, wn = wave & 1;
  const int lrow = lane & 15, lk8 = (lane >> 4) * 8;
  const int sRow = tid >> 2, sK = (tid & 3) * 16;
  const float* Ab = A + (size_t)b * aSB;
  f32x4 acc[2][2] = {};

  for (int k0 = kBeg; k0 < kEnd; k0 += 64) {
    { // A: 16 fp32 -> hi/lo
      const float* src = Ab + (size_t)(m0 + sRow) * lda + k0 + sK;
      s16x8 h0, l0, h1, l1;
#pragma unroll
      for (int t = 0; t < 8; ++t) {
        const float v = src[t];
        const unsigned short hh = f2bf(v);
        h0[t] = (short)hh; l0[t] = (short)f2bf(v - bf2f(hh));
      }
#pragma unroll
      for (int t = 0; t < 8; ++t) {
        const float v = src[8 + t];
        const unsigned short hh = f2bf(v);
        h1[t] = (short)hh; l1[t] = (short)f2bf(v - bf2f(hh));
      }
      *(s16x8*)&Ah[sRow][sK] = h0; *(s16x8*)&Ah[sRow][sK + 8] = h1;
      *(s16x8*)&Al[sRow][sK] = l0; *(s16x8*)&Al[sRow][sK + 8] = l1;
    }
    if (bPre) {
      const unsigned short* Bh_ = (const unsigned short*)B0v + (size_t)b * bSB;
      const unsigned short* Bl_ = (const unsigned short*)B1v + (size_t)b * bSB;
      const size_t off = (size_t)(n0 + sRow) * ldb + k0 + sK;
      *(s16x8*)&Bh[sRow][sK]     = *(const s16x8*)(Bh_ + off);
      *(s16x8*)&Bh[sRow][sK + 8] = *(const s16x8*)(Bh_ + off + 8);
      *(s16x8*)&Bl[sRow][sK]     = *(const s16x8*)(Bl_ + off);
      *(s16x8*)&Bl[sRow][sK + 8] = *(const s16x8*)(Bl_ + off + 8);
    } else {
      const float* Bb = (const float*)B0v + (size_t)b * bSB;
      const float* src = Bb + (size_t)(n0 + sRow) * ldb + k0 + sK;
      s16x8 h0, l0, h1, l1;
#pragma unroll
      for (int t = 0; t < 8; ++t) {
        const float v = src[t];
        const unsigned short hh = f2bf(v);
        h0[t] = (short)hh; l0[t] = (short)f2bf(v - bf2f(hh));
      }
#pragma unroll
      for (int t = 0; t < 8; ++t) {
        const float v = src[8 + t];
        const unsigned short hh = f2bf(v);
        h1[t] = (short)hh; l1[t] = (short)f2bf(v - bf2f(hh));
      }
      *(s16x8*)&Bh[sRow][sK] = h0; *(s16x8*)&Bh[sRow][sK + 8] = h1;
      *(s16x8*)&Bl[sRow][sK] = l0; *(s16x8*)&Bl[sRow][sK + 8] = l1;
    }
    __syncthreads();
#pragma unroll
    for (int kc = 0; kc < 2; ++kc) {
      const s16x8 ah0 = *(const s16x8*)&Ah[wm * 32 + lrow     ][kc * 32 + lk8];
      const s16x8 ah1 = *(const s16x8*)&Ah[wm * 32 + 16 + lrow][kc * 32 + lk8];
      const s16x8 al0 = *(const s16x8*)&Al[wm * 32 + lrow     ][kc * 32 + lk8];
      const s16x8 al1 = *(const s16x8*)&Al[wm * 32 + 16 + lrow][kc * 32 + lk8];
      const s16x8 bh0 = *(const s16x8*)&Bh[wn * 32 + lrow     ][kc * 32 + lk8];
      const s16x8 bh1 = *(const s16x8*)&Bh[wn * 32 + 16 + lrow][kc * 32 + lk8];
      const s16x8 bl0 = *(const s16x8*)&Bl[wn * 32 + lrow     ][kc * 32 + lk8];
      const s16x8 bl1 = *(const s16x8*)&Bl[wn * 32 + 16 + lrow][kc * 32 + lk8];
      acc[0][0] = __builtin_amdgcn_mfma_f32_16x16x32_bf16(ah0, bh0, acc[0][0], 0, 0, 0);
      acc[0][1] = __builtin_amdgcn_mfma_f32_16x16x32_bf16(ah0, bh1, acc[0][1], 0, 0, 0);
      acc[1][0] = __builtin_amdgcn_mfma_f32_16x16x32_bf16(ah1, bh0, acc[1][0], 0, 0, 0);
      acc[1][1] = __builtin_amdgcn_mfma_f32_16x16x32_bf16(ah1, bh1, acc[1][1], 0, 0, 0);
      acc[0][0] = __builtin_amdgcn_mfma_f32_16x16x32_bf16(ah0, bl0, acc[0][0], 0, 0, 0);
      acc[0][1] = __builtin_amdgcn_mfma_f32_16x16x32_bf16(ah0, bl1, acc[0][1], 0, 0, 0);
      acc[1][0] = __builtin_amdgcn_mfma_f32_16x16x32_bf16(ah1, bl0, acc[1][0], 0, 0, 0);
      acc[1][1] = __builtin_amdgcn_mfma_f32_16x16x32_bf16(ah1, bl1, acc[1][1], 0, 0, 0);
      acc[0][0] = __builtin_amdgcn_mfma_f32_16x16x32_bf16(al0, bh0, acc[0][0], 0, 0, 0);
      acc[0][1] = __builtin_amdgcn_mfma_f32_16x16x32_bf16(al0, bh1, acc[0][1], 0, 0, 0);
      acc[1][0] = __builtin_amdgcn_mfma_f32_16x16x32_bf16(al1, bh0, acc[1][0], 0, 0, 0);
      acc[1][1] = __builtin_amdgcn_mfma_f32_16x16x32_bf16(al1, bh1, acc[1][1], 0, 0, 0);
    }
    __syncthreads();
  }

  float* Yb = Y + (size_t)b * ySB;
#pragma unroll
  for (int mt = 0; mt < 2; ++mt)
#pragma unroll
    for (int nt = 0; nt < 2; ++nt) {
      const int col = n0 + wn * 32 + nt * 16 + lrow;
      const int rbase = m0 + wm * 32 + mt * 16 + (lane >> 4) * 4;
#pragma unroll
      for (int i = 0; i < 4; ++i) {
        const int row = rbase + i;
        float v = acc[mt][nt][i];
        const float s  = scale ? scale[row] : 1.f;
        const float bb = bias ? bias[row] : 0.f;
        v = v * s + bb;
        if (relu) v = fmaxf(v, 0.f);
        if (outMode == 0)      Yb[(size_t)row * ldy + col] = v;
        else if (outMode == 1) Yb[(size_t)col * ldy + row] = v;
        else                   atomicAdd(Yb + (size_t)col * ldy + row, v);
      }
    }
}

// ================================================================ pre-pad + split + transpose: [C][N] fp32 -> [PN][C] bf16 hi/lo
__global__ __launch_bounds__(256)
void pad_split(const float* __restrict__ X, unsigned short* __restrict__ Xh,
               unsigned short* __restrict__ Xl)
{
  __shared__ float t[64][65];
  const int b = blockIdx.x, n0 = blockIdx.y * 64;
  const int tid = threadIdx.x;
  const float* Xb = X + (size_t)b * C_ * N_;
  unsigned short* Xhb = Xh + (size_t)b * PN * C_;
  unsigned short* Xlb = Xl + (size_t)b * PN * C_;
  for (int cs = 0; cs < 8; ++cs) {
    const int c0 = cs * 64;
    __syncthreads();
#pragma unroll
    for (int i = 0; i < 16; ++i) {
      const int cc = i * 4 + (tid >> 6);
      t[cc][tid & 63] = Xb[(size_t)(c0 + cc) * N_ + n0 + (tid & 63)];
    }
    __syncthreads();
    const int cc = tid & 63;
#pragma unroll
    for (int i = 0; i < 16; ++i) {
      const int nn = i * 4 + (tid >> 6);
      const int n = n0 + nn;
      const float v = t[cc][nn];
      const unsigned short hh = f2bf(v);
      const unsigned short ll = f2bf(v - bf2f(hh));
      const size_t p = (size_t)((n / 48 + 1) * PW + (n % 48) + 1) * C_ + c0 + cc;
      Xhb[p] = hh; Xlb[p] = ll;
    }
  }
}

// zero the padded ring
__global__ __launch_bounds__(256)
void zero_ring(unsigned short* __restrict__ Xh, unsigned short* __restrict__ Xl)
{
  const int b = blockIdx.y, r = blockIdx.x;
  int pcol;
  if (r < 50)       pcol = r;
  else if (r < 100) pcol = 49 * PW + (r - 50);
  else if (r < 148) pcol = (r - 100 + 1) * PW;
  else              pcol = (r - 148 + 1) * PW + 49;
  unsigned int* h = (unsigned int*)(Xh + ((size_t)b * PN + pcol) * C_);
  unsigned int* l = (unsigned int*)(Xl + ((size_t)b * PN + pcol) * C_);
  h[threadIdx.x] = 0u;
  l[threadIdx.x] = 0u;
}

// weights fp32 [O][c*9+tap] -> hi/lo bf16 [O][tap*512+c]
__global__ __launch_bounds__(256)
void wsplit(const float* __restrict__ W, unsigned short* __restrict__ Wh,
            unsigned short* __restrict__ Wl)
{
  const int o = blockIdx.x, tap = blockIdx.y;
#pragma unroll
  for (int i = 0; i < 2; ++i) {
    const int c = threadIdx.x + i * 256;
    const float v = W[(size_t)o * KW + c * 9 + tap];
    const unsigned short hh = f2bf(v);
    Wh[(size_t)o * KW + tap * C_ + c] = hh;
    Wl[(size_t)o * KW + tap * C_ + c] = f2bf(v - bf2f(hh));
  }
}

// fp32 [C][N] -> bf16 hi/lo [N][C]
__global__ __launch_bounds__(256)
void tr_split(const float* __restrict__ X, unsigned short* __restrict__ Th,
              unsigned short* __restrict__ Tl)
{
  __shared__ float t[64][65];
  const int b = blockIdx.x, n0 = blockIdx.y * 64;
  const int tid = threadIdx.x;
  const float* Xb = X + (size_t)b * C_ * N_;
  unsigned short* Thb = Th + (size_t)b * N_ * C_;
  unsigned short* Tlb = Tl + (size_t)b * N_ * C_;
  for (int cs = 0; cs < 8; ++cs) {
    const int c0 = cs * 64;
    __syncthreads();
#pragma unroll
    for (int i = 0; i < 16; ++i) {
      const int cc = i * 4 + (tid >> 6);
      t[cc][tid & 63] = Xb[(size_t)(c0 + cc) * N_ + n0 + (tid & 63)];
    }
    __syncthreads();
    const int cc = tid & 63;
#pragma unroll
    for (int i = 0; i < 16; ++i) {
      const int nn = i * 4 + (tid >> 6);
      const float v = t[cc][nn];
      const unsigned short hh = f2bf(v);
      Thb[(size_t)(n0 + nn) * C_ + c0 + cc] = hh;
      Tlb[(size_t)(n0 + nn) * C_ + c0 + cc] = f2bf(v - bf2f(hh));
    }
  }
}

// ================================================================ conv3x3 tap-outer split-bf16 MFMA with reg-prefetch (tier 0)
__global__ __launch_bounds__(256)
void mfma_conv2(const unsigned short* __restrict__ Xh, const unsigned short* __restrict__ Xl,
                const unsigned short* __restrict__ Wh, const unsigned short* __restrict__ Wl,
                const float* __restrict__ sc, const float* __restrict__ bi,
                float* __restrict__ Y)
{
  __shared__ unsigned short Ah[64][72], Al[64][72];
  __shared__ unsigned short Bh[64][72], Bl[64][72];
  const int b  = blockIdx.z;
  const int m0 = blockIdx.y * 64, n0 = blockIdx.x * 64;
  const int tid  = threadIdx.x;
  const int lane = tid & 63, wave = tid >> 6;
  const int wm = wave >> 1, wn = wave & 1;
  const int lrow = lane & 15, lk8 = (lane >> 4) * 8;
  const int sRow = tid >> 2, sK = (tid & 3) * 16;
  const int nj = n0 + sRow;
  const int pbase = (nj / 48 + 1) * PW + (nj % 48) + 1;
  const unsigned short* Xhb = Xh + (size_t)b * PN * C_;
  const unsigned short* Xlb = Xl + (size_t)b * PN * C_;
  f32x4 acc[2][2] = {};
  s16x8 r0, r1, r2, r3, r4, r5, r6, r7;

#define CONV_LD(IT)                                                        \
  {                                                                        \
    const int tap_ = (IT) >> 3, c0_ = ((IT) & 7) * 64;                     \
    const int t3_ = tap_ / 3;                                              \
    const int toff_ = (t3_ - 1) * PW + (tap_ - t3_ * 3 - 1);               \
    const size_t bofs_ = (size_t)(pbase + toff_) * C_ + c0_ + sK;          \
    const size_t wrow_ = (size_t)(m0 + sRow) * KW + (size_t)tap_ * C_ + c0_ + sK; \
    r0 = *(const s16x8*)(Wh + wrow_);     r1 = *(const s16x8*)(Wh + wrow_ + 8); \
    r2 = *(const s16x8*)(Wl + wrow_);     r3 = *(const s16x8*)(Wl + wrow_ + 8); \
    r4 = *(const s16x8*)(Xhb + bofs_);    r5 = *(const s16x8*)(Xhb + bofs_ + 8); \
    r6 = *(const s16x8*)(Xlb + bofs_);    r7 = *(const s16x8*)(Xlb + bofs_ + 8); \
  }

  CONV_LD(0);
  for (int it = 0; it < 72; ++it) {
    *(s16x8*)&Ah[sRow][sK] = r0; *(s16x8*)&Ah[sRow][sK + 8] = r1;
    *(s16x8*)&Al[sRow][sK] = r2; *(s16x8*)&Al[sRow][sK + 8] = r3;
    *(s16x8*)&Bh[sRow][sK] = r4; *(s16x8*)&Bh[sRow][sK + 8] = r5;
    *(s16x8*)&Bl[sRow][sK] = r6; *(s16x8*)&Bl[sRow][sK + 8] = r7;
    __syncthreads();
    if (it < 71) CONV_LD(it + 1);     // next-iter loads fly under the MFMAs
#pragma unroll
    for (int kc = 0; kc < 2; ++kc) {
      const s16x8 ah0 = *(const s16x8*)&Ah[wm * 32 + lrow     ][kc * 32 + lk8];
      const s16x8 ah1 = *(const s16x8*)&Ah[wm * 32 + 16 + lrow][kc * 32 + lk8];
      const s16x8 al0 = *(const s16x8*)&Al[wm * 32 + lrow     ][kc * 32 + lk8];
      const s16x8 al1 = *(const s16x8*)&Al[wm * 32 + 16 + lrow][kc * 32 + lk8];
      const s16x8 bh0 = *(const s16x8*)&Bh[wn * 32 + lrow     ][kc * 32 + lk8];
      const s16x8 bh1 = *(const s16x8*)&Bh[wn * 32 + 16 + lrow][kc * 32 + lk8];
      const s16x8 bl0 = *(const s16x8*)&Bl[wn * 32 + lrow     ][kc * 32 + lk8];
      const s16x8 bl1 = *(const s16x8*)&Bl[wn * 32 + 16 + lrow][kc * 32 + lk8];
      acc[0][0] = __builtin_amdgcn_mfma_f32_16x16x32_bf16(ah0, bh0, acc[0][0], 0, 0, 0);
      acc[0][1] = __builtin_amdgcn_mfma_f32_16x16x32_bf16(ah0, bh1, acc[0][1], 0, 0, 0);
      acc[1][0] = __builtin_amdgcn_mfma_f32_16x16x32_bf16(ah1, bh0, acc[1][0], 0, 0, 0);
      acc[1][1] = __builtin_amdgcn_mfma_f32_16x16x32_bf16(ah1, bh1, acc[1][1], 0, 0, 0);
      acc[0][0] = __builtin_amdgcn_mfma_f32_16x16x32_bf16(ah0, bl0, acc[0][0], 0, 0, 0);
      acc[0][1] = __builtin_amdgcn_mfma_f32_16x16x32_bf16(ah0, bl1, acc[0][1], 0, 0, 0);
      acc[1][0] = __builtin_amdgcn_mfma_f32_16x16x32_bf16(ah1, bl0, acc[1][0], 0, 0, 0);
      acc[1][1] = __builtin_amdgcn_mfma_f32_16x16x32_bf16(ah1, bl1, acc[1][1], 0, 0, 0);
      acc[0][0] = __builtin_amdgcn_mfma_f32_16x16x32_bf16(al0, bh0, acc[0][0], 0, 0, 0);
      acc[0][1] = __builtin_amdgcn_mfma_f32_16x16x32_bf16(al0, bh1, acc[0][1], 0, 0, 0);
      acc[1][0] = __builtin_amdgcn_mfma_f32_16x16x32_bf16(al1, bh0, acc[1][0], 0, 0, 0);
      acc[1][1] = __builtin_amdgcn_mfma_f32_16x16x32_bf16(al1, bh1, acc[1][1], 0, 0, 0);
    }
    __syncthreads();
  }
#undef CONV_LD

  float* Yb = Y + (size_t)b * C_ * N_;
#pragma unroll
  for (int mt = 0; mt < 2; ++mt)
#pragma unroll
    for (int nt = 0; nt < 2; ++nt) {
      const int col = n0 + wn * 32 + nt * 16 + lrow;
      const int rbase = m0 + wm * 32 + mt * 16 + (lane >> 4) * 4;
#pragma unroll
      for (int i = 0; i < 4; ++i) {
        const int row = rbase + i;
        const float v = fmaxf(acc[mt][nt][i] * sc[row] + bi[row], 0.f);
        Yb[(size_t)row * N_ + col] = v;
      }
    }
}

// ================================================================ conv3x3 split-bf16 on-the-fly (tiers 1/2 fallback)
__global__ __launch_bounds__(256)
void mfma_conv_split(const float* __restrict__ X, const float* __restrict__ Wt,
                     const float* __restrict__ sc, const float* __restrict__ bi,
                     float* __restrict__ Y)
{
  __shared__ unsigned short Ah[64][72], Al[64][72];
  __shared__ unsigned short Bh[64][72], Bl[64][72];
  const int b  = blockIdx.z;
  const int m0 = blockIdx.y * 64, n0 = blockIdx.x * 64;
  const int tid  = threadIdx.x;
  const int lane = tid & 63, wave = tid >> 6;
  const int wm = wave >> 1, wn = wave & 1;
  const int lrow = lane & 15, lk8 = (lane >> 4) * 8;
  const int sRow = tid >> 2, sK = (tid & 3) * 16;
  const int tj = tid & 63, tkg = (tid >> 6) * 16;
  const int n = n0 + tj, yy = n / W_, xx = n - yy * W_;
  const float* Xb = X + (size_t)b * C_ * N_;
  f32x4 acc[2][2] = {};

  for (int k0 = 0; k0 < KW; k0 += 64) {
    {
      const float* src = Wt + (size_t)(m0 + sRow) * KW + k0 + sK;
      unsigned short h[16], l[16];
#pragma unroll
      for (int t = 0; t < 16; ++t) {
        const float v = src[t];
        const unsigned short hh = f2bf(v);
        h[t] = hh;
        l[t] = f2bf(v - bf2f(hh));
      }
      *(s16x8*)&Ah[sRow][sK]     = *(s16x8*)&h[0];
      *(s16x8*)&Ah[sRow][sK + 8] = *(s16x8*)&h[8];
      *(s16x8*)&Al[sRow][sK]     = *(s16x8*)&l[0];
      *(s16x8*)&Al[sRow][sK + 8] = *(s16x8*)&l[8];
    }
    {
#pragma unroll
      for (int ii = 0; ii < 16; ii += 2) {
        unsigned int ph = 0, pl = 0;
#pragma unroll
        for (int hft = 0; hft < 2; ++hft) {
          const int kg = k0 + tkg + ii + hft;
          const int c = kg / 9, tap = kg - c * 9;
          const int t3 = tap / 3;
          const int iy = yy + t3 - 1, ix = xx + (tap - t3 * 3) - 1;
          float v = 0.f;
          if (iy >= 0 && iy < H_ && ix >= 0 && ix < W_)
            v = Xb[(size_t)c * N_ + iy * W_ + ix];
          const unsigned short hh = f2bf(v);
          const unsigned short ll = f2bf(v - bf2f(hh));
          ph |= ((unsigned int)hh) << (16 * hft);
          pl |= ((unsigned int)ll) << (16 * hft);
        }
        *(unsigned int*)&Bh[tj][tkg + ii] = ph;
        *(unsigned int*)&Bl[tj][tkg + ii] = pl;
      }
    }
    __syncthreads();
#pragma unroll
    for (int kc = 0; kc < 2; ++kc) {
      const s16x8 ah0 = *(const s16x8*)&Ah[wm * 32 + lrow     ][kc * 32 + lk8];
      const s16x8 ah1 = *(const s16x8*)&Ah[wm * 32 + 16 + lrow][kc * 32 + lk8];
      const s16x8 al0 = *(const s16x8*)&Al[wm * 32 + lrow     ][kc * 32 + lk8];
      const s16x8 al1 = *(const s16x8*)&Al[wm * 32 + 16 + lrow][kc * 32 + lk8];
      const s16x8 bh0 = *(const s16x8*)&Bh[wn * 32 + lrow     ][kc * 32 + lk8];
      const s16x8 bh1 = *(const s16x8*)&Bh[wn * 32 + 16 + lrow][kc * 32 + lk8];
      const s16x8 bl0 = *(const s16x8*)&Bl[wn * 32 + lrow     ][kc * 32 + lk8];
      const s16x8 bl1 = *(const s16x8*)&Bl[wn * 32 + 16 + lrow][kc * 32 + lk8];
      acc[0][0] = __builtin_amdgcn_mfma_f32_16x16x32_bf16(ah0, bh0, acc[0][0], 0, 0, 0);
      acc[0][1] = __builtin_amdgcn_mfma_f32_16x16x32_bf16(ah0, bh1, acc[0][1], 0, 0, 0);
      acc[1][0] = __builtin_amdgcn_mfma_f32_16x16x32_bf16(ah1, bh0, acc[1][0], 0, 0, 0);
      acc[1][1] = __builtin_amdgcn_mfma_f32_16x16x32_bf16(ah1, bh1, acc[1][1], 0, 0, 0);
      acc[0][0] = __builtin_amdgcn_mfma_f32_16x16x32_bf16(ah0, bl0, acc[0][0], 0, 0, 0);
      acc[0][1] = __builtin_amdgcn_mfma_f32_16x16x32_bf16(ah0, bl1, acc[0][1], 0, 0, 0);
      acc[1][0] = __builtin_amdgcn_mfma_f32_16x16x32_bf16(ah1, bl0, acc[1][0], 0, 0, 0);
      acc[1][1] = __builtin_amdgcn_mfma_f32_16x16x32_bf16(ah1, bl1, acc[1][1], 0, 0, 0);
      acc[0][0] = __builtin_amdgcn_mfma_f32_16x16x32_bf16(al0, bh0, acc[0][0], 0, 0, 0);
      acc[0][1] = __builtin_amdgcn_mfma_f32_16x16x32_bf16(al0, bh1, acc[0][1], 0, 0, 0);
      acc[1][0] = __builtin_amdgcn_mfma_f32_16x16x32_bf16(al1, bh0, acc[1][0], 0, 0, 0);
      acc[1][1] = __builtin_amdgcn_mfma_f32_16x16x32_bf16(al1, bh1, acc[1][1], 0, 0, 0);
    }
    __syncthreads();
  }

  float* Yb = Y + (size_t)b * C_ * N_;
#pragma unroll
  for (int mt = 0; mt < 2; ++mt)
#pragma unroll
    for (int nt = 0; nt < 2; ++nt) {
      const int col = n0 + wn * 32 + nt * 16 + lrow;
      const int rbase = m0 + wm * 32 + mt * 16 + (lane >> 4) * 4;
#pragma unroll
      for (int i = 0; i < 4; ++i) {
        const int row = rbase + i;
        const float v = fmaxf(acc[mt][nt][i] * sc[row] + bi[row], 0.f);
        Yb[(size_t)row * N_ + col] = v;
      }
    }
}

// ================================================================ P build (fp32 E -> bf16 P)
__global__ __launch_bounds__(256)
void build_P(const float* __restrict__ E, const float* __restrict__ st,
             int variant, const float* __restrict__ mask,
             unsigned short* __restrict__ P)
{
  const int m = blockIdx.x, b = blockIdx.y, t = threadIdx.x;
  const float* sp = st + ((size_t)b * N_ + m) * 6 + variant * 2;
  const float mx = sp[0], rs = 1.f / sp[1];
  const float* Er = E + ((size_t)b * N_ + m) * N_;
  unsigned short* Pr = P + ((size_t)b * N_ + m) * N_;
  const float* Mr = mask ? mask + (size_t)m * N_ : nullptr;
#pragma unroll
  for (int i = 0; i < 9; ++i) {
    const int idx = t + i * 256;
    float w = __expf(Er[idx] - mx) * rs;
    if (Mr && !(Mr[idx] > 0.f)) w = 0.f;
    Pr[idx] = f2bf(w);
  }
}

// ---------------------------------------------------------------- softmax stats (reads E)
__global__ __launch_bounds__(256)
void softmax_stats(const float* __restrict__ E, const float* __restrict__ M1,
                   const float* __restrict__ M2, float* __restrict__ st)
{
  const int row = blockIdx.x, b = blockIdx.y, tid = threadIdx.x;
  const float* er = E + ((size_t)b * N_ + row) * N_;
  const float* r1 = M1 + (size_t)row * N_;
  const float* r2 = M2 + (size_t)row * N_;
  float mx0 = -3.4e38f, mx1 = -3.4e38f, mx2 = -3.4e38f;
  for (int n = tid; n < N_; n += 256) {
    const float v = er[n];
    mx0 = fmaxf(mx0, v);
    if (r1[n] > 0.f) mx1 = fmaxf(mx1, v);
    if (r2[n] > 0.f) mx2 = fmaxf(mx2, v);
  }
  __shared__ float red[256];
  mx0 = blockReduceMax(mx0, red);
  mx1 = blockReduceMax(mx1, red);
  mx2 = blockReduceMax(mx2, red);
  float s0 = 0.f, s1 = 0.f, s2 = 0.f;
  for (int n = tid; n < N_; n += 256) {
    const float v = er[n];
    s0 += __expf(v - mx0);
    if (r1[n] > 0.f) s1 += __expf(v - mx1);
    if (r2[n] > 0.f) s2 += __expf(v - mx2);
  }
  s0 = blockReduceSum(s0, red);
  s1 = blockReduceSum(s1, red);
  s2 = blockReduceSum(s2, red);
  if (tid == 0) {
    float* o = st + ((size_t)b * N_ + row) * 6;
    o[0] = mx0; o[1] = s0; o[2] = mx1; o[3] = s1; o[4] = mx2; o[5] = s2;
  }
}

// ---------------------------------------------------------------- softmax stats (LITE, tier 2)
__global__ __launch_bounds__(256)
void softmax_stats_rq(const float* __restrict__ q, const float* __restrict__ k,
                      const float* __restrict__ M1, const float* __restrict__ M2,
                      float* __restrict__ st)
{
  const int row = blockIdx.x, b = blockIdx.y, tid = threadIdx.x;
  __shared__ float qs[CR_];
  if (tid < CR_) qs[tid] = q[((size_t)b * CR_ + tid) * N_ + row];
  __syncthreads();
  const float* kb_ = k + (size_t)b * CR_ * N_;
  float ev[9], mk1[9], mk2[9];
  const float* r1 = M1 + (size_t)row * N_;
  const float* r2 = M2 + (size_t)row * N_;
#pragma unroll
  for (int i = 0; i < 9; ++i) {
    const int n = tid + i * 256;
    float e = 0.f;
#pragma unroll 8
    for (int c = 0; c < CR_; ++c) e = fmaf(qs[c], kb_[(size_t)c * N_ + n], e);
    ev[i] = e; mk1[i] = r1[n]; mk2[i] = r2[n];
  }
  float mx0 = -3.4e38f, mx1 = -3.4e38f, mx2 = -3.4e38f;
#pragma unroll
  for (int i = 0; i < 9; ++i) {
    const float v = ev[i];
    mx0 = fmaxf(mx0, v);
    if (mk1[i] > 0.f) mx1 = fmaxf(mx1, v);
    if (mk2[i] > 0.f) mx2 = fmaxf(mx2, v);
  }
  __shared__ float red[256];
  mx0 = blockReduceMax(mx0, red);
  mx1 = blockReduceMax(mx1, red);
  mx2 = blockReduceMax(mx2, red);
  float s0 = 0.f, s1 = 0.f, s2 = 0.f;
#pragma unroll
  for (int i = 0; i < 9; ++i) {
    const float v = ev[i];
    s0 += __expf(v - mx0);
    if (mk1[i] > 0.f) s1 += __expf(v - mx1);
    if (mk2[i] > 0.f) s2 += __expf(v - mx2);
  }
  s0 = blockReduceSum(s0, red);
  s1 = blockReduceSum(s1, red);
  s2 = blockReduceSum(s2, red);
  if (tid == 0) {
    float* o = st + ((size_t)b * N_ + row) * 6;
    o[0] = mx0; o[1] = s0; o[2] = mx1; o[3] = s1; o[4] = mx2; o[5] = s2;
  }
}

// ---------------------------------------------------------------- attention apply (fp32, tier 1)
__global__ __launch_bounds__(256)
void attn_apply(const float* __restrict__ V, const float* __restrict__ E,
                const float* __restrict__ st, int variant,
                const float* __restrict__ mask,
                const float* __restrict__ gammaPtr,
                const float* __restrict__ R, float* __restrict__ Y)
{
  __shared__ float As[TK][LDSP], Bs[TK][LDSP];
  const int b  = blockIdx.z;
  const int c0 = blockIdx.y * 64, m0 = blockIdx.x * 64;
  const int tid = threadIdx.x, tx = tid & 15, ty = tid >> 4;
  const int ia = tid >> 2, ka = (tid & 3) * 4;
  const int jb = tid >> 2, kb = (tid & 3) * 4;
  const int mrow = m0 + jb;
  const float* sp = st + ((size_t)b * N_ + mrow) * 6 + variant * 2;
  const float mx = sp[0];
  const float rs = 1.f / sp[1];
  const float* Vb = V + (size_t)b * C_ * N_;
  const float* Er = E + ((size_t)b * N_ + mrow) * N_;
  const float* Mr = mask ? mask + (size_t)mrow * N_ : nullptr;
  float acc[4][4] = {};
  for (int k0 = 0; k0 < N_; k0 += TK) {
    const float4 a4 = *(const float4*)(Vb + (size_t)(c0 + ia) * N_ + k0 + ka);
    As[ka + 0][ia] = a4.x; As[ka + 1][ia] = a4.y;
    As[ka + 2][ia] = a4.z; As[ka + 3][ia] = a4.w;
    const float4 e4 = *(const float4*)(Er + k0 + kb);
    float w0, w1, w2, w3;
    if (Mr) {
      const float4 m4 = *(const float4*)(Mr + k0 + kb);
      w0 = (m4.x > 0.f) ? __expf(e4.x - mx) * rs : 0.f;
      w1 = (m4.y > 0.f) ? __expf(e4.y - mx) * rs : 0.f;
      w2 = (m4.z > 0.f) ? __expf(e4.z - mx) * rs : 0.f;
      w3 = (m4.w > 0.f) ? __expf(e4.w - mx) * rs : 0.f;
    } else {
      w0 = __expf(e4.x - mx) * rs; w1 = __expf(e4.y - mx) * rs;
      w2 = __expf(e4.z - mx) * rs; w3 = __expf(e4.w - mx) * rs;
    }
    Bs[kb + 0][jb] = w0; Bs[kb + 1][jb] = w1;
    Bs[kb + 2][jb] = w2; Bs[kb + 3][jb] = w3;
    __syncthreads();
    mm16(As, Bs, acc, ty, tx);
    __syncthreads();
  }
  const float g = gammaPtr[0];
  float* Yb = Y + (size_t)b * C_ * N_;
  const float* Rb = R + (size_t)b * C_ * N_;
#pragma unroll
  for (int i = 0; i < 4; ++i) {
    const int row = c0 + ty * 4 + i;
    const size_t off = (size_t)row * N_ + m0 + tx * 4;
    const float4 r4 = *(const float4*)(Rb + off);
    float4 o;
    o.x = g * acc[i][0] + r4.x; o.y = g * acc[i][1] + r4.y;
    o.z = g * acc[i][2] + r4.z; o.w = g * acc[i][3] + r4.w;
    *(float4*)(Yb + off) = o;
  }
}

// ---------------------------------------------------------------- attention apply (fp32 LITE, tier 2)
__global__ __launch_bounds__(256)
void attn_apply_rq(const float* __restrict__ V, const float* __restrict__ q,
                   const float* __restrict__ k,
                   const float* __restrict__ st, int variant,
                   const float* __restrict__ mask,
                   const float* __restrict__ gammaPtr,
                   const float* __restrict__ R, float* __restrict__ Y)
{
  __shared__ float As[TK][LDSP], Bs[TK][LDSP];
  __shared__ float qs[CR_][65];
  __shared__ float kss[CR_][17];
  const int b  = blockIdx.z;
  const int c0 = blockIdx.y * 64, m0 = blockIdx.x * 64;
  const int tid = threadIdx.x, tx = tid & 15, ty = tid >> 4;
  const int ia = tid >> 2, ka = (tid & 3) * 4;
  const int jb = tid >> 2, kb = (tid & 3) * 4;
  const int mrow = m0 + jb;
  const float* qb_ = q + (size_t)b * CR_ * N_;
  const float* kb_ = k + (size_t)b * CR_ * N_;
#pragma unroll
  for (int i = 0; i < 16; ++i) {
    const int idx = tid + i * 256;
    const int c = idx >> 6, j = idx & 63;
    qs[c][j] = qb_[(size_t)c * N_ + m0 + j];
  }
  const float* sp = st + ((size_t)b * N_ + mrow) * 6 + variant * 2;
  const float mx = sp[0];
  const float rs = 1.f / sp[1];
  const float* Vb = V + (size_t)b * C_ * N_;
  const float* Mr = mask ? mask + (size_t)mrow * N_ : nullptr;
  float acc[4][4] = {};
  __syncthreads();
  for (int k0 = 0; k0 < N_; k0 += TK) {
    const float4 a4 = *(const float4*)(Vb + (size_t)(c0 + ia) * N_ + k0 + ka);
    As[ka + 0][ia] = a4.x; As[ka + 1][ia] = a4.y;
    As[ka + 2][ia] = a4.z; As[ka + 3][ia] = a4.w;
#pragma unroll
    for (int i = 0; i < 4; ++i) {
      const int idx = tid + i * 256;
      const int c = idx >> 4, nn = idx & 15;
      kss[c][nn] = kb_[(size_t)c * N_ + k0 + nn];
    }
    __syncthreads();
    float e0 = 0.f, e1 = 0.f, e2 = 0.f, e3 = 0.f;
#pragma unroll 16
    for (int c = 0; c < CR_; ++c) {
      const float qv = qs[c][jb];
      e0 = fmaf(qv, kss[c][kb + 0], e0);
      e1 = fmaf(qv, kss[c][kb + 1], e1);
      e2 = fmaf(qv, kss[c][kb + 2], e2);
      e3 = fmaf(qv, kss[c][kb + 3], e3);
    }
    float w0, w1, w2, w3;
    if (Mr) {
      const float4 m4 = *(const float4*)(Mr + k0 + kb);
      w0 = (m4.x > 0.f) ? __expf(e0 - mx) * rs : 0.f;
      w1 = (m4.y > 0.f) ? __expf(e1 - mx) * rs : 0.f;
      w2 = (m4.z > 0.f) ? __expf(e2 - mx) * rs : 0.f;
      w3 = (m4.w > 0.f) ? __expf(e3 - mx) * rs : 0.f;
    } else {
      w0 = __expf(e0 - mx) * rs; w1 = __expf(e1 - mx) * rs;
      w2 = __expf(e2 - mx) * rs; w3 = __expf(e3 - mx) * rs;
    }
    Bs[kb + 0][jb] = w0; Bs[kb + 1][jb] = w1;
    Bs[kb + 2][jb] = w2; Bs[kb + 3][jb] = w3;
    __syncthreads();
    mm16(As, Bs, acc, ty, tx);
    __syncthreads();
  }
  const float g = gammaPtr[0];
  float* Yb = Y + (size_t)b * C_ * N_;
  const float* Rb = R + (size_t)b * C_ * N_;
#pragma unroll
  for (int i = 0; i < 4; ++i) {
    const int row = c0 + ty * 4 + i;
    const size_t off = (size_t)row * N_ + m0 + tx * 4;
    const float4 r4 = *(const float4*)(Rb + off);
    float4 o;
    o.x = g * acc[i][0] + r4.x; o.y = g * acc[i][1] + r4.y;
    o.z = g * acc[i][2] + r4.z; o.w = g * acc[i][3] + r4.w;
    *(float4*)(Yb + off) = o;
  }
}

// ---------------------------------------------------------------- chl row softmax
__global__ __launch_bounds__(256)
void chl_softmax(float* __restrict__ buf)
{
  const int row = blockIdx.x, tid = threadIdx.x;
  float* r = buf + (size_t)row * C_;
  const float v0 = -r[tid], v1 = -r[tid + 256];
  __shared__ float red[256];
  const float mx = blockReduceMax(fmaxf(v0, v1), red);
  const float e0 = __expf(v0 - mx), e1 = __expf(v1 - mx);
  const float s = blockReduceSum(e0 + e1, red);
  const float rs = 1.f / s;
  r[tid] = e0 * rs;
  r[tid + 256] = e1 * rs;
}

// ================================================================ launch
extern "C" void kernel_launch(void* const* d_in, const int* in_sizes, int n_in,
                              void* d_out, int out_size, void* d_ws, size_t ws_size,
                              hipStream_t stream)
{
  (void)in_sizes; (void)n_in; (void)out_size;
  const float* x      = (const float*)d_in[0];
  const float* wq     = (const float*)d_in[1];
  const float* bq     = (const float*)d_in[2];
  const float* wk     = (const float*)d_in[3];
  const float* bk     = (const float*)d_in[4];
  const float* wv0    = (const float*)d_in[5];
  const float* bv0    = (const float*)d_in[6];
  const float* c1w    = (const float*)d_in[7];
  const float* c1s    = (const float*)d_in[8];
  const float* c1b    = (const float*)d_in[9];
  const float* c2w    = (const float*)d_in[10];
  const float* c2s    = (const float*)d_in[11];
  const float* c2b    = (const float*)d_in[12];
  const float* gamma  = (const float*)d_in[13];
  const float* gamma1 = (const float*)d_in[14];
  const float* gamma2 = (const float*)d_in[15];
  const float* c1qw   = (const float*)d_in[16];
  const float* c1qs   = (const float*)d_in[17];
  const float* c1qb   = (const float*)d_in[18];
  const float* c1ew   = (const float*)d_in[19];
  const float* c1eb   = (const float*)d_in[20];
  const float* c2qw   = (const float*)d_in[21];
  const float* c2qs   = (const float*)d_in[22];
  const float* c2qb   = (const float*)d_in[23];
  const float* c2ew   = (const float*)d_in[24];
  const float* c2eb   = (const float*)d_in[25];
  const float* mask1  = (const float*)d_in[26];
  const float* mask2  = (const float*)d_in[27];

  const size_t QK = 589824;            // B*CR*N
  const size_t CQ = 1179648;           // B*C4*N
  const size_t VV = 4718592;           // B*C*N
  const size_t EE = 21233664;          // B*N*N
  const size_t ST = 55296;             // B*N*6
  const size_t CE = 262144;            // B*C4*C
  const size_t CA = 1048576;           // B*C*C
  const size_t ELEMS_B = CQ + VV + EE + ST + VV + CE + CA;       // 33,216,512
  const size_t ELEMS_A = ELEMS_B + EE / 2;                       // + time-shared bf16 region
  const int tier = (ws_size >= ELEMS_A * 4) ? 0
                 : (ws_size >= ELEMS_B * 4) ? 1 : 2;

  float* ws = (float*)d_ws;
  float *qbuf, *kbuf, *cq, *vbuf, *ebuf, *stb, *o0, *ce1, *cat_;
  unsigned short *Pbuf = nullptr, *Xh = nullptr, *Xl = nullptr,
                 *Whs = nullptr, *Wls = nullptr,
                 *xTh = nullptr, *xTl = nullptr, *oTh = nullptr, *oTl = nullptr;
  float *qTf = nullptr, *kTf = nullptr;
  if (tier <= 1) {
    qbuf = ws; kbuf = ws + QK;         // (tier1 only; dead after energy)
    cq   = ws;                          // aliases q+k region
    vbuf = ws + CQ;
    ebuf = vbuf + VV;
    stb  = ebuf + EE;
    o0   = stb + ST;
    ce1  = o0 + VV;
    cat_ = ce1 + CE;
    if (tier == 0) {
      unsigned short* reg = (unsigned short*)(cat_ + CA);   // EE shorts, time-shared
      // phase A (pre-loop): x^T hi/lo + q^T/k^T fp32
      xTh = reg;                       // 4,718,592
      xTl = reg + 4718592;             // -> 9,437,184
      qTf = (float*)(reg + 9437184);   // 589,824 f -> 1,179,648 shorts
      kTf = qTf + 589824;              // ends 11,796,480 shorts
      // phase B (per pass): P
      Pbuf = reg;                      // full EE shorts
      // phase C (per pass, conv): padded act + weights
      Xh  = reg;                       // 5,120,000
      Xl  = reg + 5120000;             // -> 10,240,000
      Whs = reg + 10240000;            // 2,359,296
      Wls = reg + 12599296;            // ends 14,958,592
      // phase D (per pass, chl): o^T hi/lo
      oTh = reg;                       // 4,718,592
      oTl = reg + 4718592;             // -> 9,437,184
    }
  } else {
    qbuf = ws; kbuf = qbuf + QK;       // live all passes
    cq   = kbuf + QK;
    vbuf = cq + CQ;
    stb  = vbuf + VV;
    o0   = stb + ST;
    ce1  = o0 + VV;
    cat_ = ce1 + CE;
    ebuf = nullptr;
  }
  float* t0 = (float*)d_out;           // pre-conv scratch aliases d_out
  unsigned short* vb16 = (unsigned short*)vbuf;  // tier-0: bf16 V in vbuf region

  const dim3 TPB(256);
  const long long sxc = (long long)C_ * N_;
  const long long sqr = (long long)CR_ * N_;
  const long long sq4 = (long long)C4_ * N_;
  const long long sNN = (long long)N_ * N_;
  const long long sNC = (long long)N_ * C_;
  const long long sCC = (long long)C_ * C_;
  const long long sEC = (long long)C4_ * C_;
  const long long sNR = (long long)N_ * CR_;

  if (tier == 0) {
    // x^T hi/lo once
    tr_split<<<dim3(B_, 36), TPB, 0, stream>>>(x, xTh, xTl);
    // q,k projections (split-bf16, transposed out) -> qT,kT [N][64] fp32
    mfma_sp<<<dim3(36, 1, 4), TPB, 0, stream>>>(wq, 0, C_, xTh, xTl, sNC, C_, 1,
        qTf, sNR, CR_, 1, C_, 1, nullptr, bq, 0);
    mfma_sp<<<dim3(36, 1, 4), TPB, 0, stream>>>(wk, 0, C_, xTh, xTl, sNC, C_, 1,
        kTf, sNR, CR_, 1, C_, 1, nullptr, bk, 0);
    // v projection (single bf16) -> vb16
    mfma_gemm<<<dim3(36, 8, 4), TPB, 0, stream>>>(wv0, 0, 0, C_, xTh, sNC, C_, 2,
        vb16, 1, sxc, N_, C_, nullptr, bv0, 0, nullptr, nullptr, 0);
    // energy = qT . kT^T (NT, K=64, split-bf16)
    mfma_sp<<<dim3(36, 36, 4), TPB, 0, stream>>>(qTf, sNR, CR_, kTf, nullptr, sNR, CR_, 0,
        ebuf, sNN, N_, 0, CR_, 1, nullptr, nullptr, 0);
    softmax_stats<<<dim3(N_, 4), TPB, 0, stream>>>(ebuf, mask1, mask2, stb);
  } else if (tier == 1) {
    gemm_nn<<<dim3(36, 1, 4), TPB, 0, stream>>>(wq, 0, C_, x, sxc, N_,
                                                qbuf, sqr, N_, C_, nullptr, bq, 0);
    gemm_nn<<<dim3(36, 1, 4), TPB, 0, stream>>>(wk, 0, C_, x, sxc, N_,
                                                kbuf, sqr, N_, C_, nullptr, bk, 0);
    mfma_gemm<<<dim3(36, 8, 4), TPB, 0, stream>>>(wv0, 0, 0, C_, x, sxc, N_, 1,
        vbuf, 0, sxc, N_, C_, nullptr, bv0, 0, nullptr, nullptr, 0);
    gemm_tn<<<dim3(36, 36, 4), TPB, 0, stream>>>(qbuf, sqr, N_, kbuf, sqr, N_,
                                                 ebuf, sNN, N_, CR_);
    softmax_stats<<<dim3(N_, 4), TPB, 0, stream>>>(ebuf, mask1, mask2, stb);
  } else {
    gemm_nn<<<dim3(36, 1, 4), TPB, 0, stream>>>(wq, 0, C_, x, sxc, N_,
                                                qbuf, sqr, N_, C_, nullptr, bq, 0);
    gemm_nn<<<dim3(36, 1, 4), TPB, 0, stream>>>(wk, 0, C_, x, sxc, N_,
                                                kbuf, sqr, N_, C_, nullptr, bk, 0);
    mfma_gemm<<<dim3(36, 8, 4), TPB, 0, stream>>>(wv0, 0, 0, C_, x, sxc, N_, 1,
        vbuf, 0, sxc, N_, C_, nullptr, bv0, 0, nullptr, nullptr, 0);
    softmax_stats_rq<<<dim3(N_, 4), TPB, 0, stream>>>(qbuf, kbuf, mask1, mask2, stb);
  }

  for (int pass = 0; pass < 3; ++pass) {
    const float* msk = (pass == 0) ? nullptr : (pass == 1 ? mask1 : mask2);
    const float* gm  = (pass == 0) ? gamma : (pass == 1 ? gamma1 : gamma2);
    const float* res = (pass == 0) ? x : o0;
    float* dst = (pass == 2) ? (float*)d_out : t0;

    // ---- attention apply: dst = gm * V . P^T + res
    if (tier == 0) {
      build_P<<<dim3(N_, 4), TPB, 0, stream>>>(ebuf, stb, pass, msk, Pbuf);
      mfma_gemm<<<dim3(36, 8, 4), TPB, 0, stream>>>(vb16, 1, sxc, N_, Pbuf, sNN, N_, 2,
          dst, 0, sxc, N_, N_, nullptr, nullptr, 0, gm, res, sxc);
    } else if (tier == 1) {
      attn_apply<<<dim3(36, 8, 4), TPB, 0, stream>>>(vbuf, ebuf, stb, pass, msk,
                                                     gm, res, dst);
    } else {
      attn_apply_rq<<<dim3(36, 8, 4), TPB, 0, stream>>>(vbuf, qbuf, kbuf, stb, pass, msk,
                                                        gm, res, dst);
    }
    if (pass == 2) break;

    // ---- conv3x3 + BN + ReLU  (dst -> o0)
    const float* cw = (pass == 0) ? c1w : c2w;
    const float* cs = (pass == 0) ? c1s : c2s;
    const float* cb = (pass == 0) ? c1b : c2b;
    if (tier == 0) {
      pad_split<<<dim3(B_, 36), TPB, 0, stream>>>(dst, Xh, Xl);
      zero_ring<<<dim3(196, B_), TPB, 0, stream>>>(Xh, Xl);
      wsplit<<<dim3(512, 9), TPB, 0, stream>>>(cw, Whs, Wls);
      mfma_conv2<<<dim3(36, 8, 4), TPB, 0, stream>>>(Xh, Xl, Whs, Wls, cs, cb, o0);
    } else {
      mfma_conv_split<<<dim3(36, 8, 4), TPB, 0, stream>>>(dst, cw, cs, cb, o0);
    }

    // ---- chl block on o0 -> vbuf
    const float* qw = (pass == 0) ? c1qw : c2qw;
    const float* qs = (pass == 0) ? c1qs : c2qs;
    const float* qb = (pass == 0) ? c1qb : c2qb;
    const float* ew = (pass == 0) ? c1ew : c2ew;
    const float* eb = (pass == 0) ? c1eb : c2eb;
    if (tier == 0) {
      tr_split<<<dim3(B_, 36), TPB, 0, stream>>>(o0, oTh, oTl);
      // cq = relu(qs*(qw.o0)+qb)  [C4][N] fp32
      mfma_sp<<<dim3(36, 2, 4), TPB, 0, stream>>>(qw, 0, C_, oTh, oTl, sNC, C_, 1,
          cq, sq4, N_, 0, C_, 1, qs, qb, 1);
      // ce1T[c2][q] = sum_n cq[q][n]*o0[c2][n]  (split-K x4, atomic)
      zero_buf<<<dim3(256), TPB, 0, stream>>>((float4*)ce1, (int)(CE / 4));
      mfma_sp<<<dim3(8, 2, 16), TPB, 0, stream>>>(cq, sq4, N_, o0, nullptr, sxc, N_, 0,
          ce1, sEC, C4_, 2, N_, 4, nullptr, nullptr, 0);
      // cat_[o][c2] = ew . ce1T^T + eb
      mfma_sp<<<dim3(8, 8, 4), TPB, 0, stream>>>(ew, 0, C4_, ce1, nullptr, sEC, C4_, 0,
          cat_, sCC, C_, 0, C4_, 1, nullptr, eb, 0);
      chl_softmax<<<dim3(C_ * 4), TPB, 0, stream>>>(cat_);
      // v_next = cat_ . o0 (single bf16) -> vb16
      mfma_gemm<<<dim3(36, 8, 4), TPB, 0, stream>>>(cat_, 0, sCC, C_, oTh, sNC, C_, 2,
          vb16, 1, sxc, N_, C_, nullptr, nullptr, 0, nullptr, nullptr, 0);
    } else {
      gemm_nn<<<dim3(36, 2, 4), TPB, 0, stream>>>(qw, 0, C_, o0, sxc, N_,
                                                  cq, sq4, N_, C_, qs, qb, 1);
      zero_buf<<<dim3(256), TPB, 0, stream>>>((float4*)ce1, (int)(CE / 4));
      gemm_nt_splitk<<<dim3(8, 2, 16), TPB, 0, stream>>>(cq, sq4, N_, o0, sxc, N_,
                                                         ce1, sEC, C_, N_);
      gemm_nn<<<dim3(8, 8, 4), TPB, 0, stream>>>(ew, 0, C4_, ce1, sEC, C_,
                                                 cat_, sCC, C_, C4_, nullptr, eb, 0);
      chl_softmax<<<dim3(C_ * 4), TPB, 0, stream>>>(cat_);
      mfma_gemm<<<dim3(36, 8, 4), TPB, 0, stream>>>(cat_, 0, sCC, C_, o0, sxc, N_, 1,
          vbuf, 0, sxc, N_, C_, nullptr, nullptr, 0, nullptr, nullptr, 0);
    }
  }
}

// Round 7
// 1283.255 us; speedup vs baseline: 2.6615x; 1.0166x over previous
//
#include <hip/hip_runtime.h>

#define B_  4
#define C_  512
#define H_  48
#define W_  48
#define N_  2304      // H_*W_
#define CR_ 64        // C_/R
#define C4_ 128       // C_/4
#define TK  16
#define LDSP 68       // fp32 helper tiles: 64 + 4 pad
#define PW  50        // padded width/height
#define PN  2500      // PW*PW
#define KW  4608      // C_*9

typedef short  s16x8 __attribute__((ext_vector_type(8)));   // 8 bf16 (4 VGPR)
typedef float  f32x4 __attribute__((ext_vector_type(4)));

// fp32 -> bf16 bits, round-to-nearest-even
__device__ __forceinline__ unsigned short f2bf(float f) {
  union { float f; unsigned int u; } v; v.f = f;
  const unsigned int u = v.u;
  return (unsigned short)((u + 0x7FFFu + ((u >> 16) & 1u)) >> 16);
}
__device__ __forceinline__ float bf2f(unsigned short h) {
  union { unsigned int u; float f; } v; v.u = ((unsigned int)h) << 16;
  return v.f;
}

// ---------------------------------------------------------------- reductions
__device__ __forceinline__ float blockReduceMax(float v, float* red) {
  const int tid = threadIdx.x;
  red[tid] = v; __syncthreads();
  for (int s = 128; s > 0; s >>= 1) {
    if (tid < s) red[tid] = fmaxf(red[tid], red[tid + s]);
    __syncthreads();
  }
  float r = red[0]; __syncthreads();
  return r;
}
__device__ __forceinline__ float blockReduceSum(float v, float* red) {
  const int tid = threadIdx.x;
  red[tid] = v; __syncthreads();
  for (int s = 128; s > 0; s >>= 1) {
    if (tid < s) red[tid] += red[tid + s];
    __syncthreads();
  }
  float r = red[0]; __syncthreads();
  return r;
}

// ---------------------------------------------------------------- fp32 micro-kernel (fallback tiers)
__device__ __forceinline__ void mm16(const float (*As)[LDSP], const float (*Bs)[LDSP],
                                     float acc[4][4], int ty, int tx)
{
#pragma unroll
  for (int kk = 0; kk < TK; ++kk) {
    const float4 a4 = *(const float4*)(&As[kk][ty * 4]);
    const float4 b4 = *(const float4*)(&Bs[kk][tx * 4]);
    const float av[4] = {a4.x, a4.y, a4.z, a4.w};
    const float bv[4] = {b4.x, b4.y, b4.z, b4.w};
#pragma unroll
    for (int i = 0; i < 4; ++i)
#pragma unroll
      for (int j = 0; j < 4; ++j)
        acc[i][j] = fmaf(av[i], bv[j], acc[i][j]);
  }
}

// ---------------------------------------------------------------- fp32 GEMM NN (fallback)
__global__ __launch_bounds__(256)
void gemm_nn(const float* __restrict__ A, long long aStrideB, int lda,
             const float* __restrict__ B, long long bStrideB, int ldb,
             float* __restrict__ Y, long long yStrideB, int ldy,
             int K,
             const float* __restrict__ scale, const float* __restrict__ bias, int relu)
{
  __shared__ float As[TK][LDSP], Bs[TK][LDSP];
  const int b  = blockIdx.z;
  const int m0 = blockIdx.y * 64, n0 = blockIdx.x * 64;
  const int tid = threadIdx.x, tx = tid & 15, ty = tid >> 4;
  const int ia = tid >> 2, ka = (tid & 3) * 4;
  const int jb = tid & 63, kb = (tid >> 6) * 4;
  const float* Ab = A + (size_t)b * aStrideB;
  const float* Bb = B + (size_t)b * bStrideB;
  float acc[4][4] = {};
  for (int k0 = 0; k0 < K; k0 += TK) {
    const float4 a4 = *(const float4*)(Ab + (size_t)(m0 + ia) * lda + k0 + ka);
    As[ka + 0][ia] = a4.x; As[ka + 1][ia] = a4.y;
    As[ka + 2][ia] = a4.z; As[ka + 3][ia] = a4.w;
#pragma unroll
    for (int t = 0; t < 4; ++t)
      Bs[kb + t][jb] = Bb[(size_t)(k0 + kb + t) * ldb + n0 + jb];
    __syncthreads();
    mm16(As, Bs, acc, ty, tx);
    __syncthreads();
  }
  float* Yb = Y + (size_t)b * yStrideB;
#pragma unroll
  for (int i = 0; i < 4; ++i) {
    const int row = m0 + ty * 4 + i;
    const float s = scale ? scale[row] : 1.f;
    const float bb = bias ? bias[row] : 0.f;
    float4 o;
    o.x = acc[i][0] * s + bb; o.y = acc[i][1] * s + bb;
    o.z = acc[i][2] * s + bb; o.w = acc[i][3] * s + bb;
    if (relu) {
      o.x = fmaxf(o.x, 0.f); o.y = fmaxf(o.y, 0.f);
      o.z = fmaxf(o.z, 0.f); o.w = fmaxf(o.w, 0.f);
    }
    *(float4*)(Yb + (size_t)row * ldy + n0 + tx * 4) = o;
  }
}

// ---------------------------------------------------------------- fp32 GEMM NT split-K x4 (fallback)
__global__ __launch_bounds__(256)
void gemm_nt_splitk(const float* __restrict__ A, long long aStrideB, int lda,
                    const float* __restrict__ B, long long bStrideB, int ldb,
                    float* __restrict__ Y, long long yStrideB, int ldy, int K)
{
  __shared__ float As[TK][LDSP], Bs[TK][LDSP];
  const int z = blockIdx.z, b = z >> 2, ks = z & 3;
  const int kBeg = ks * (K / 4), kEnd = kBeg + K / 4;
  const int m0 = blockIdx.y * 64, n0 = blockIdx.x * 64;
  const int tid = threadIdx.x, tx = tid & 15, ty = tid >> 4;
  const int ia = tid >> 2, ka = (tid & 3) * 4;
  const float* Ab = A + (size_t)b * aStrideB;
  const float* Bb = B + (size_t)b * bStrideB;
  float acc[4][4] = {};
  for (int k0 = kBeg; k0 < kEnd; k0 += TK) {
    const float4 a4 = *(const float4*)(Ab + (size_t)(m0 + ia) * lda + k0 + ka);
    As[ka + 0][ia] = a4.x; As[ka + 1][ia] = a4.y;
    As[ka + 2][ia] = a4.z; As[ka + 3][ia] = a4.w;
    const float4 b4 = *(const float4*)(Bb + (size_t)(n0 + ia) * ldb + k0 + ka);
    Bs[ka + 0][ia] = b4.x; Bs[ka + 1][ia] = b4.y;
    Bs[ka + 2][ia] = b4.z; Bs[ka + 3][ia] = b4.w;
    __syncthreads();
    mm16(As, Bs, acc, ty, tx);
    __syncthreads();
  }
  float* Yb = Y + (size_t)b * yStrideB;
#pragma unroll
  for (int i = 0; i < 4; ++i) {
    const int row = m0 + ty * 4 + i;
#pragma unroll
    for (int j = 0; j < 4; ++j)
      atomicAdd(Yb + (size_t)row * ldy + n0 + tx * 4 + j, acc[i][j]);
  }
}

// ---------------------------------------------------------------- zero buffer
__global__ __launch_bounds__(256)
void zero_buf(float4* __restrict__ p, int n4)
{
  const int i = blockIdx.x * 256 + threadIdx.x;
  if (i < n4) p[i] = float4{0.f, 0.f, 0.f, 0.f};
}

// ---------------------------------------------------------------- fp32 GEMM TN (fallback energy)
__global__ __launch_bounds__(256)
void gemm_tn(const float* __restrict__ A, long long aStrideB, int lda,
             const float* __restrict__ B, long long bStrideB, int ldb,
             float* __restrict__ Y, long long yStrideB, int ldy, int K)
{
  __shared__ float As[TK][LDSP], Bs[TK][LDSP];
  const int b  = blockIdx.z;
  const int m0 = blockIdx.y * 64, n0 = blockIdx.x * 64;
  const int tid = threadIdx.x, tx = tid & 15, ty = tid >> 4;
  const int i2 = tid & 63, k2 = (tid >> 6) * 4;
  const float* Ab = A + (size_t)b * aStrideB;
  const float* Bb = B + (size_t)b * bStrideB;
  float acc[4][4] = {};
  for (int k0 = 0; k0 < K; k0 += TK) {
#pragma unroll
    for (int t = 0; t < 4; ++t) {
      As[k2 + t][i2] = Ab[(size_t)(k0 + k2 + t) * lda + m0 + i2];
      Bs[k2 + t][i2] = Bb[(size_t)(k0 + k2 + t) * ldb + n0 + i2];
    }
    __syncthreads();
    mm16(As, Bs, acc, ty, tx);
    __syncthreads();
  }
  float* Yb = Y + (size_t)b * yStrideB;
#pragma unroll
  for (int i = 0; i < 4; ++i) {
    const int row = m0 + ty * 4 + i;
    float4 o = {acc[i][0], acc[i][1], acc[i][2], acc[i][3]};
    *(float4*)(Yb + (size_t)row * ldy + n0 + tx * 4) = o;
  }
}

// ================================================================ MFMA GEMM (single bf16, non-logit paths)
// A: aBf16? bf16[i][k] : fp32[i][k]
// B: bMode 0 = fp32 B[j][k] ; 1 = fp32 B[k][j] (transpose-stage) ; 2 = bf16 B[j][k]
__global__ __launch_bounds__(256)
void mfma_gemm(const void* __restrict__ Av, int aBf16, long long aSB, int lda,
               const void* __restrict__ Bv, long long bSB, int ldb, int bMode,
               void* __restrict__ Yv, int outBf16, long long ySB, int ldy, int K,
               const float* __restrict__ scale, const float* __restrict__ bias,
               int relu,
               const float* __restrict__ gammaPtr, const float* __restrict__ Resid,
               long long rSB)
{
  __shared__ unsigned short As[64][72];
  __shared__ unsigned short Bs[64][72];
  const int b  = blockIdx.z;
  const int m0 = blockIdx.y * 64, n0 = blockIdx.x * 64;
  const int tid  = threadIdx.x;
  const int lane = tid & 63, wave = tid >> 6;
  const int wm = wave >> 1, wn = wave & 1;
  const int lrow = lane & 15, lk8 = (lane >> 4) * 8;
  const int sRow = tid >> 2, sK = (tid & 3) * 16;
  const int tj = tid & 63, tkg = (tid >> 6) * 16;
  f32x4 acc[2][2] = {};

  for (int k0 = 0; k0 < K; k0 += 64) {
    if (aBf16) {
      const unsigned short* Ab = (const unsigned short*)Av + (size_t)b * aSB;
      const unsigned short* src = Ab + (size_t)(m0 + sRow) * lda + k0 + sK;
      *(s16x8*)&As[sRow][sK]     = *(const s16x8*)(src);
      *(s16x8*)&As[sRow][sK + 8] = *(const s16x8*)(src + 8);
    } else {
      const float* Ab = (const float*)Av + (size_t)b * aSB;
      const float* src = Ab + (size_t)(m0 + sRow) * lda + k0 + sK;
      const float4 x0 = *(const float4*)(src);
      const float4 x1 = *(const float4*)(src + 4);
      const float4 x2 = *(const float4*)(src + 8);
      const float4 x3 = *(const float4*)(src + 12);
      s16x8 p0 = { (short)f2bf(x0.x), (short)f2bf(x0.y), (short)f2bf(x0.z), (short)f2bf(x0.w),
                   (short)f2bf(x1.x), (short)f2bf(x1.y), (short)f2bf(x1.z), (short)f2bf(x1.w) };
      s16x8 p1 = { (short)f2bf(x2.x), (short)f2bf(x2.y), (short)f2bf(x2.z), (short)f2bf(x2.w),
                   (short)f2bf(x3.x), (short)f2bf(x3.y), (short)f2bf(x3.z), (short)f2bf(x3.w) };
      *(s16x8*)&As[sRow][sK]     = p0;
      *(s16x8*)&As[sRow][sK + 8] = p1;
    }
    if (bMode == 1) {
      const float* Bb = (const float*)Bv + (size_t)b * bSB;
#pragma unroll
      for (int ii = 0; ii < 16; ii += 2) {
        const float v0 = Bb[(size_t)(k0 + tkg + ii)     * ldb + n0 + tj];
        const float v1 = Bb[(size_t)(k0 + tkg + ii + 1) * ldb + n0 + tj];
        *(unsigned int*)&Bs[tj][tkg + ii] =
            (unsigned int)f2bf(v0) | ((unsigned int)f2bf(v1) << 16);
      }
    } else if (bMode == 2) {
      const unsigned short* Bb = (const unsigned short*)Bv + (size_t)b * bSB;
      const unsigned short* src = Bb + (size_t)(n0 + sRow) * ldb + k0 + sK;
      *(s16x8*)&Bs[sRow][sK]     = *(const s16x8*)(src);
      *(s16x8*)&Bs[sRow][sK + 8] = *(const s16x8*)(src + 8);
    } else {
      const float* Bb = (const float*)Bv + (size_t)b * bSB;
      const float* src = Bb + (size_t)(n0 + sRow) * ldb + k0 + sK;
      const float4 x0 = *(const float4*)(src);
      const float4 x1 = *(const float4*)(src + 4);
      const float4 x2 = *(const float4*)(src + 8);
      const float4 x3 = *(const float4*)(src + 12);
      s16x8 p0 = { (short)f2bf(x0.x), (short)f2bf(x0.y), (short)f2bf(x0.z), (short)f2bf(x0.w),
                   (short)f2bf(x1.x), (short)f2bf(x1.y), (short)f2bf(x1.z), (short)f2bf(x1.w) };
      s16x8 p1 = { (short)f2bf(x2.x), (short)f2bf(x2.y), (short)f2bf(x2.z), (short)f2bf(x2.w),
                   (short)f2bf(x3.x), (short)f2bf(x3.y), (short)f2bf(x3.z), (short)f2bf(x3.w) };
      *(s16x8*)&Bs[sRow][sK]     = p0;
      *(s16x8*)&Bs[sRow][sK + 8] = p1;
    }
    __syncthreads();
#pragma unroll
    for (int kc = 0; kc < 2; ++kc) {
      const s16x8 a0 = *(const s16x8*)&As[wm * 32 + lrow     ][kc * 32 + lk8];
      const s16x8 a1 = *(const s16x8*)&As[wm * 32 + 16 + lrow][kc * 32 + lk8];
      const s16x8 b0 = *(const s16x8*)&Bs[wn * 32 + lrow     ][kc * 32 + lk8];
      const s16x8 b1 = *(const s16x8*)&Bs[wn * 32 + 16 + lrow][kc * 32 + lk8];
      acc[0][0] = __builtin_amdgcn_mfma_f32_16x16x32_bf16(a0, b0, acc[0][0], 0, 0, 0);
      acc[0][1] = __builtin_amdgcn_mfma_f32_16x16x32_bf16(a0, b1, acc[0][1], 0, 0, 0);
      acc[1][0] = __builtin_amdgcn_mfma_f32_16x16x32_bf16(a1, b0, acc[1][0], 0, 0, 0);
      acc[1][1] = __builtin_amdgcn_mfma_f32_16x16x32_bf16(a1, b1, acc[1][1], 0, 0, 0);
    }
    __syncthreads();
  }

  const float g = gammaPtr ? gammaPtr[0] : 0.f;
  const float* Rb = Resid ? Resid + (size_t)b * rSB : nullptr;
#pragma unroll
  for (int mt = 0; mt < 2; ++mt)
#pragma unroll
    for (int nt = 0; nt < 2; ++nt) {
      const int col = n0 + wn * 32 + nt * 16 + lrow;
      const int rbase = m0 + wm * 32 + mt * 16 + (lane >> 4) * 4;
#pragma unroll
      for (int i = 0; i < 4; ++i) {
        const int row = rbase + i;
        float v = acc[mt][nt][i];
        if (Rb) {
          v = g * v + Rb[(size_t)row * ldy + col];
        } else {
          const float s  = scale ? scale[row] : 1.f;
          const float bb = bias ? bias[row] : 0.f;
          v = v * s + bb;
          if (relu) v = fmaxf(v, 0.f);
        }
        if (outBf16)
          ((unsigned short*)Yv)[(size_t)b * ySB + (size_t)row * ldy + col] = f2bf(v);
        else
          ((float*)Yv)[(size_t)b * ySB + (size_t)row * ldy + col] = v;
      }
    }
}

// ================================================================ split-bf16 MFMA GEMM (fp32-grade, logit chain)
// Y[i][j] = sum_k A[i][k]*B[j][k]   (both operands k-contiguous)
// A: fp32, split on the fly. B: bPre? (B0=hi,B1=lo bf16 [j][k]) : fp32 B0[j][k] split-fly.
// outMode: 0 Y[i*ldy+j] ; 1 Y[j*ldy+i] ; 2 atomicAdd(Y[j*ldy+i])
__global__ __launch_bounds__(256)
void mfma_sp(const float* __restrict__ A, long long aSB, int lda,
             const void* __restrict__ B0v, const void* __restrict__ B1v,
             long long bSB, int ldb, int bPre,
             float* __restrict__ Y, long long ySB, int ldy, int outMode,
             int K, int nSplit,
             const float* __restrict__ scale, const float* __restrict__ bias, int relu)
{
  __shared__ unsigned short Ah[64][72], Al[64][72];
  __shared__ unsigned short Bh[64][72], Bl[64][72];
  const int z = blockIdx.z;
  const int b = z / nSplit, ks = z % nSplit;
  const int kLen = K / nSplit, kBeg = ks * kLen, kEnd = kBeg + kLen;
  const int m0 = blockIdx.y * 64, n0 = blockIdx.x * 64;
  const int tid  = threadIdx.x;
  const int lane = tid & 63, wave = tid >> 6;
  const int wm = wave >> 1, wn = wave & 1;
  const int lrow = lane & 15, lk8 = (lane >> 4) * 8;
  const int sRow = tid >> 2, sK = (tid & 3) * 16;
  const float* Ab = A + (size_t)b * aSB;
  f32x4 acc[2][2] = {};

  for (int k0 = kBeg; k0 < kEnd; k0 += 64) {
    {
      const float* src = Ab + (size_t)(m0 + sRow) * lda + k0 + sK;
      s16x8 h0, l0, h1, l1;
#pragma unroll
      for (int t = 0; t < 8; ++t) {
        const float v = src[t];
        const unsigned short hh = f2bf(v);
        h0[t] = (short)hh; l0[t] = (short)f2bf(v - bf2f(hh));
      }
#pragma unroll
      for (int t = 0; t < 8; ++t) {
        const float v = src[8 + t];
        const unsigned short hh = f2bf(v);
        h1[t] = (short)hh; l1[t] = (short)f2bf(v - bf2f(hh));
      }
      *(s16x8*)&Ah[sRow][sK] = h0; *(s16x8*)&Ah[sRow][sK + 8] = h1;
      *(s16x8*)&Al[sRow][sK] = l0; *(s16x8*)&Al[sRow][sK + 8] = l1;
    }
    if (bPre) {
      const unsigned short* Bh_ = (const unsigned short*)B0v + (size_t)b * bSB;
      const unsigned short* Bl_ = (const unsigned short*)B1v + (size_t)b * bSB;
      const size_t off = (size_t)(n0 + sRow) * ldb + k0 + sK;
      *(s16x8*)&Bh[sRow][sK]     = *(const s16x8*)(Bh_ + off);
      *(s16x8*)&Bh[sRow][sK + 8] = *(const s16x8*)(Bh_ + off + 8);
      *(s16x8*)&Bl[sRow][sK]     = *(const s16x8*)(Bl_ + off);
      *(s16x8*)&Bl[sRow][sK + 8] = *(const s16x8*)(Bl_ + off + 8);
    } else {
      const float* Bb = (const float*)B0v + (size_t)b * bSB;
      const float* src = Bb + (size_t)(n0 + sRow) * ldb + k0 + sK;
      s16x8 h0, l0, h1, l1;
#pragma unroll
      for (int t = 0; t < 8; ++t) {
        const float v = src[t];
        const unsigned short hh = f2bf(v);
        h0[t] = (short)hh; l0[t] = (short)f2bf(v - bf2f(hh));
      }
#pragma unroll
      for (int t = 0; t < 8; ++t) {
        const float v = src[8 + t];
        const unsigned short hh = f2bf(v);
        h1[t] = (short)hh; l1[t] = (short)f2bf(v - bf2f(hh));
      }
      *(s16x8*)&Bh[sRow][sK] = h0; *(s16x8*)&Bh[sRow][sK + 8] = h1;
      *(s16x8*)&Bl[sRow][sK] = l0; *(s16x8*)&Bl[sRow][sK + 8] = l1;
    }
    __syncthreads();
#pragma unroll
    for (int kc = 0; kc < 2; ++kc) {
      const s16x8 ah0 = *(const s16x8*)&Ah[wm * 32 + lrow     ][kc * 32 + lk8];
      const s16x8 ah1 = *(const s16x8*)&Ah[wm * 32 + 16 + lrow][kc * 32 + lk8];
      const s16x8 al0 = *(const s16x8*)&Al[wm * 32 + lrow     ][kc * 32 + lk8];
      const s16x8 al1 = *(const s16x8*)&Al[wm * 32 + 16 + lrow][kc * 32 + lk8];
      const s16x8 bh0 = *(const s16x8*)&Bh[wn * 32 + lrow     ][kc * 32 + lk8];
      const s16x8 bh1 = *(const s16x8*)&Bh[wn * 32 + 16 + lrow][kc * 32 + lk8];
      const s16x8 bl0 = *(const s16x8*)&Bl[wn * 32 + lrow     ][kc * 32 + lk8];
      const s16x8 bl1 = *(const s16x8*)&Bl[wn * 32 + 16 + lrow][kc * 32 + lk8];
      acc[0][0] = __builtin_amdgcn_mfma_f32_16x16x32_bf16(ah0, bh0, acc[0][0], 0, 0, 0);
      acc[0][1] = __builtin_amdgcn_mfma_f32_16x16x32_bf16(ah0, bh1, acc[0][1], 0, 0, 0);
      acc[1][0] = __builtin_amdgcn_mfma_f32_16x16x32_bf16(ah1, bh0, acc[1][0], 0, 0, 0);
      acc[1][1] = __builtin_amdgcn_mfma_f32_16x16x32_bf16(ah1, bh1, acc[1][1], 0, 0, 0);
      acc[0][0] = __builtin_amdgcn_mfma_f32_16x16x32_bf16(ah0, bl0, acc[0][0], 0, 0, 0);
      acc[0][1] = __builtin_amdgcn_mfma_f32_16x16x32_bf16(ah0, bl1, acc[0][1], 0, 0, 0);
      acc[1][0] = __builtin_amdgcn_mfma_f32_16x16x32_bf16(ah1, bl0, acc[1][0], 0, 0, 0);
      acc[1][1] = __builtin_amdgcn_mfma_f32_16x16x32_bf16(ah1, bl1, acc[1][1], 0, 0, 0);
      acc[0][0] = __builtin_amdgcn_mfma_f32_16x16x32_bf16(al0, bh0, acc[0][0], 0, 0, 0);
      acc[0][1] = __builtin_amdgcn_mfma_f32_16x16x32_bf16(al0, bh1, acc[0][1], 0, 0, 0);
      acc[1][0] = __builtin_amdgcn_mfma_f32_16x16x32_bf16(al1, bh0, acc[1][0], 0, 0, 0);
      acc[1][1] = __builtin_amdgcn_mfma_f32_16x16x32_bf16(al1, bh1, acc[1][1], 0, 0, 0);
    }
    __syncthreads();
  }

  float* Yb = Y + (size_t)b * ySB;
#pragma unroll
  for (int mt = 0; mt < 2; ++mt)
#pragma unroll
    for (int nt = 0; nt < 2; ++nt) {
      const int col = n0 + wn * 32 + nt * 16 + lrow;
      const int rbase = m0 + wm * 32 + mt * 16 + (lane >> 4) * 4;
#pragma unroll
      for (int i = 0; i < 4; ++i) {
        const int row = rbase + i;
        float v = acc[mt][nt][i];
        const float s  = scale ? scale[row] : 1.f;
        const float bb = bias ? bias[row] : 0.f;
        v = v * s + bb;
        if (relu) v = fmaxf(v, 0.f);
        if (outMode == 0)      Yb[(size_t)row * ldy + col] = v;
        else if (outMode == 1) Yb[(size_t)col * ldy + row] = v;
        else                   atomicAdd(Yb + (size_t)col * ldy + row, v);
      }
    }
}

// ================================================================ pre-pad + split + transpose + ring-zero (grid (B_, 37))
__global__ __launch_bounds__(256)
void pad_split2(const float* __restrict__ X, unsigned short* __restrict__ Xh,
                unsigned short* __restrict__ Xl)
{
  const int b = blockIdx.x;
  const int tid = threadIdx.x;
  unsigned short* Xhb = Xh + (size_t)b * PN * C_;
  unsigned short* Xlb = Xl + (size_t)b * PN * C_;
  if (blockIdx.y == 36) {       // ring-zero block
    for (int idx = tid; idx < 196 * 256; idx += 256) {
      const int r = idx >> 8, u = idx & 255;
      int pcol;
      if (r < 50)       pcol = r;
      else if (r < 100) pcol = 49 * PW + (r - 50);
      else if (r < 148) pcol = (r - 100 + 1) * PW;
      else              pcol = (r - 148 + 1) * PW + 49;
      ((unsigned int*)(Xhb + (size_t)pcol * C_))[u] = 0u;
      ((unsigned int*)(Xlb + (size_t)pcol * C_))[u] = 0u;
    }
    return;
  }
  __shared__ float t[64][65];
  const int n0 = blockIdx.y * 64;
  const float* Xb = X + (size_t)b * C_ * N_;
  for (int cs = 0; cs < 8; ++cs) {
    const int c0 = cs * 64;
    __syncthreads();
#pragma unroll
    for (int i = 0; i < 16; ++i) {
      const int cc = i * 4 + (tid >> 6);
      t[cc][tid & 63] = Xb[(size_t)(c0 + cc) * N_ + n0 + (tid & 63)];
    }
    __syncthreads();
    const int cc = tid & 63;
#pragma unroll
    for (int i = 0; i < 16; ++i) {
      const int nn = i * 4 + (tid >> 6);
      const int n = n0 + nn;
      const float v = t[cc][nn];
      const unsigned short hh = f2bf(v);
      const unsigned short ll = f2bf(v - bf2f(hh));
      const size_t p = (size_t)((n / 48 + 1) * PW + (n % 48) + 1) * C_ + c0 + cc;
      Xhb[p] = hh; Xlb[p] = ll;
    }
  }
}

// weights fp32 [O][c*9+tap] -> hi/lo bf16 [O][tap*512+c]
__global__ __launch_bounds__(256)
void wsplit(const float* __restrict__ W, unsigned short* __restrict__ Wh,
            unsigned short* __restrict__ Wl)
{
  const int o = blockIdx.x, tap = blockIdx.y;
#pragma unroll
  for (int i = 0; i < 2; ++i) {
    const int c = threadIdx.x + i * 256;
    const float v = W[(size_t)o * KW + c * 9 + tap];
    const unsigned short hh = f2bf(v);
    Wh[(size_t)o * KW + tap * C_ + c] = hh;
    Wl[(size_t)o * KW + tap * C_ + c] = f2bf(v - bf2f(hh));
  }
}

// fp32 [C][N] -> bf16 hi/lo [N][C]
__global__ __launch_bounds__(256)
void tr_split(const float* __restrict__ X, unsigned short* __restrict__ Th,
              unsigned short* __restrict__ Tl)
{
  __shared__ float t[64][65];
  const int b = blockIdx.x, n0 = blockIdx.y * 64;
  const int tid = threadIdx.x;
  const float* Xb = X + (size_t)b * C_ * N_;
  unsigned short* Thb = Th + (size_t)b * N_ * C_;
  unsigned short* Tlb = Tl + (size_t)b * N_ * C_;
  for (int cs = 0; cs < 8; ++cs) {
    const int c0 = cs * 64;
    __syncthreads();
#pragma unroll
    for (int i = 0; i < 16; ++i) {
      const int cc = i * 4 + (tid >> 6);
      t[cc][tid & 63] = Xb[(size_t)(c0 + cc) * N_ + n0 + (tid & 63)];
    }
    __syncthreads();
    const int cc = tid & 63;
#pragma unroll
    for (int i = 0; i < 16; ++i) {
      const int nn = i * 4 + (tid >> 6);
      const float v = t[cc][nn];
      const unsigned short hh = f2bf(v);
      Thb[(size_t)(n0 + nn) * C_ + c0 + cc] = hh;
      Tlb[(size_t)(n0 + nn) * C_ + c0 + cc] = f2bf(v - bf2f(hh));
    }
  }
}

// ================================================================ conv3x3 128x64 tap-outer split-bf16 MFMA (tier 0)
// A = weights (128 o-rows), B = padded activations (64 n-cols). 72 iters.
__global__ __launch_bounds__(256)
void mfma_conv3(const unsigned short* __restrict__ Xh, const unsigned short* __restrict__ Xl,
                const unsigned short* __restrict__ Wh, const unsigned short* __restrict__ Wl,
                const float* __restrict__ sc, const float* __restrict__ bi,
                float* __restrict__ Y)
{
  __shared__ unsigned short Ah[128][72], Al[128][72];
  __shared__ unsigned short Bh[64][72], Bl[64][72];
  const int b  = blockIdx.z;
  const int m0 = blockIdx.y * 128, n0 = blockIdx.x * 64;
  const int tid  = threadIdx.x;
  const int lane = tid & 63, wave = tid >> 6;
  const int wm = wave >> 1, wn = wave & 1;           // wm: 64-row half, wn: 32-col half
  const int lrow = lane & 15, lk8 = (lane >> 4) * 8;
  const int aRow = tid >> 1, aK = (tid & 1) * 32;    // A staging: 128 rows x 32k
  const int bRow = tid >> 2, bK = (tid & 3) * 16;    // B staging: 64 rows x 16k
  const int nj = n0 + bRow;
  const int pbase = (nj / 48 + 1) * PW + (nj % 48) + 1;
  const unsigned short* Xhb = Xh + (size_t)b * PN * C_;
  const unsigned short* Xlb = Xl + (size_t)b * PN * C_;
  f32x4 acc[4][2] = {};
  s16x8 a0h, a1h, a2h, a3h, a0l, a1l, a2l, a3l, b0h, b1h, b0l, b1l;

#define CONV_LD(IT)                                                             \
  {                                                                             \
    const int tap_ = (IT) >> 3, c0_ = ((IT) & 7) * 64;                          \
    const int t3_ = tap_ / 3;                                                   \
    const int toff_ = (t3_ - 1) * PW + (tap_ - t3_ * 3 - 1);                    \
    const size_t bofs_ = (size_t)(pbase + toff_) * C_ + c0_ + bK;               \
    const size_t wrow_ = (size_t)(m0 + aRow) * KW + (size_t)tap_ * C_ + c0_ + aK; \
    a0h = *(const s16x8*)(Wh + wrow_);      a1h = *(const s16x8*)(Wh + wrow_ + 8);  \
    a2h = *(const s16x8*)(Wh + wrow_ + 16); a3h = *(const s16x8*)(Wh + wrow_ + 24); \
    a0l = *(const s16x8*)(Wl + wrow_);      a1l = *(const s16x8*)(Wl + wrow_ + 8);  \
    a2l = *(const s16x8*)(Wl + wrow_ + 16); a3l = *(const s16x8*)(Wl + wrow_ + 24); \
    b0h = *(const s16x8*)(Xhb + bofs_);     b1h = *(const s16x8*)(Xhb + bofs_ + 8); \
    b0l = *(const s16x8*)(Xlb + bofs_);     b1l = *(const s16x8*)(Xlb + bofs_ + 8); \
  }

  CONV_LD(0);
  for (int it = 0; it < 72; ++it) {
    *(s16x8*)&Ah[aRow][aK]      = a0h; *(s16x8*)&Ah[aRow][aK + 8]  = a1h;
    *(s16x8*)&Ah[aRow][aK + 16] = a2h; *(s16x8*)&Ah[aRow][aK + 24] = a3h;
    *(s16x8*)&Al[aRow][aK]      = a0l; *(s16x8*)&Al[aRow][aK + 8]  = a1l;
    *(s16x8*)&Al[aRow][aK + 16] = a2l; *(s16x8*)&Al[aRow][aK + 24] = a3l;
    *(s16x8*)&Bh[bRow][bK]      = b0h; *(s16x8*)&Bh[bRow][bK + 8]  = b1h;
    *(s16x8*)&Bl[bRow][bK]      = b0l; *(s16x8*)&Bl[bRow][bK + 8]  = b1l;
    __syncthreads();
    if (it < 71) CONV_LD(it + 1);
#pragma unroll
    for (int kc = 0; kc < 2; ++kc) {
      s16x8 ah[4], al[4], bh[2], bl[2];
#pragma unroll
      for (int mt = 0; mt < 4; ++mt) {
        ah[mt] = *(const s16x8*)&Ah[wm * 64 + mt * 16 + lrow][kc * 32 + lk8];
        al[mt] = *(const s16x8*)&Al[wm * 64 + mt * 16 + lrow][kc * 32 + lk8];
      }
#pragma unroll
      for (int nt = 0; nt < 2; ++nt) {
        bh[nt] = *(const s16x8*)&Bh[wn * 32 + nt * 16 + lrow][kc * 32 + lk8];
        bl[nt] = *(const s16x8*)&Bl[wn * 32 + nt * 16 + lrow][kc * 32 + lk8];
      }
#pragma unroll
      for (int mt = 0; mt < 4; ++mt)
#pragma unroll
        for (int nt = 0; nt < 2; ++nt) {
          acc[mt][nt] = __builtin_amdgcn_mfma_f32_16x16x32_bf16(ah[mt], bh[nt], acc[mt][nt], 0, 0, 0);
          acc[mt][nt] = __builtin_amdgcn_mfma_f32_16x16x32_bf16(ah[mt], bl[nt], acc[mt][nt], 0, 0, 0);
          acc[mt][nt] = __builtin_amdgcn_mfma_f32_16x16x32_bf16(al[mt], bh[nt], acc[mt][nt], 0, 0, 0);
        }
    }
    __syncthreads();
  }
#undef CONV_LD

  float* Yb = Y + (size_t)b * C_ * N_;
#pragma unroll
  for (int mt = 0; mt < 4; ++mt)
#pragma unroll
    for (int nt = 0; nt < 2; ++nt) {
      const int col = n0 + wn * 32 + nt * 16 + lrow;
      const int rbase = m0 + wm * 64 + mt * 16 + (lane >> 4) * 4;
#pragma unroll
      for (int i = 0; i < 4; ++i) {
        const int row = rbase + i;
        const float v = fmaxf(acc[mt][nt][i] * sc[row] + bi[row], 0.f);
        Yb[(size_t)row * N_ + col] = v;
      }
    }
}

// ================================================================ fused-softmax attention apply (tier 0)
// Y[c][m] = gamma * sum_n V[c][n] * P[m][n] + Resid[c][m],
// P computed on the fly from fp32 E + stats (+mask). Tile 128c x 64m.
__global__ __launch_bounds__(256)
void mfma_apply(const unsigned short* __restrict__ V, const float* __restrict__ E,
                const float* __restrict__ st, int variant,
                const float* __restrict__ mask,
                const float* __restrict__ gammaPtr,
                const float* __restrict__ Resid, float* __restrict__ Y)
{
  __shared__ unsigned short As[128][72];
  __shared__ unsigned short Bs[64][72];
  const int b  = blockIdx.z;
  const int c0 = blockIdx.y * 128, m0 = blockIdx.x * 64;
  const int tid  = threadIdx.x;
  const int lane = tid & 63, wave = tid >> 6;
  const int wm = wave >> 1, wn = wave & 1;
  const int lrow = lane & 15, lk8 = (lane >> 4) * 8;
  const int aRow = tid >> 1, aK = (tid & 1) * 32;
  const int bRow = tid >> 2, bK = (tid & 3) * 16;
  const int mrow = m0 + bRow;
  const float* sp = st + ((size_t)b * N_ + mrow) * 6 + variant * 2;
  const float mx = sp[0], rs = 1.f / sp[1];
  const unsigned short* Vb = V + (size_t)b * C_ * N_;
  const float* Er = E + ((size_t)b * N_ + mrow) * N_;
  const float* Mr = mask ? mask + (size_t)mrow * N_ : nullptr;
  f32x4 acc[4][2] = {};
  s16x8 a0, a1, a2, a3;
  float4 e0, e1, e2, e3, q0, q1, q2, q3;

#define APPLY_LD(K0)                                                      \
  {                                                                       \
    const unsigned short* s = Vb + (size_t)(c0 + aRow) * N_ + (K0) + aK;  \
    a0 = *(const s16x8*)(s);      a1 = *(const s16x8*)(s + 8);            \
    a2 = *(const s16x8*)(s + 16); a3 = *(const s16x8*)(s + 24);           \
    const float* e = Er + (K0) + bK;                                      \
    e0 = *(const float4*)(e);     e1 = *(const float4*)(e + 4);           \
    e2 = *(const float4*)(e + 8); e3 = *(const float4*)(e + 12);          \
    if (Mr) {                                                             \
      const float* m = Mr + (K0) + bK;                                    \
      q0 = *(const float4*)(m);     q1 = *(const float4*)(m + 4);         \
      q2 = *(const float4*)(m + 8); q3 = *(const float4*)(m + 12);        \
    }                                                                     \
  }

  APPLY_LD(0);
  for (int k0 = 0; k0 < N_; k0 += 64) {
    *(s16x8*)&As[aRow][aK]      = a0; *(s16x8*)&As[aRow][aK + 8]  = a1;
    *(s16x8*)&As[aRow][aK + 16] = a2; *(s16x8*)&As[aRow][aK + 24] = a3;
    {
      float w[16];
      const float4 ee[4] = {e0, e1, e2, e3};
      const float4 qq[4] = {q0, q1, q2, q3};
#pragma unroll
      for (int g4 = 0; g4 < 4; ++g4) {
        const float4 e4 = ee[g4];
        w[g4 * 4 + 0] = __expf(e4.x - mx) * rs;
        w[g4 * 4 + 1] = __expf(e4.y - mx) * rs;
        w[g4 * 4 + 2] = __expf(e4.z - mx) * rs;
        w[g4 * 4 + 3] = __expf(e4.w - mx) * rs;
        if (Mr) {
          const float4 m4 = qq[g4];
          if (!(m4.x > 0.f)) w[g4 * 4 + 0] = 0.f;
          if (!(m4.y > 0.f)) w[g4 * 4 + 1] = 0.f;
          if (!(m4.z > 0.f)) w[g4 * 4 + 2] = 0.f;
          if (!(m4.w > 0.f)) w[g4 * 4 + 3] = 0.f;
        }
      }
      s16x8 p0, p1;
#pragma unroll
      for (int t = 0; t < 8; ++t) { p0[t] = (short)f2bf(w[t]); p1[t] = (short)f2bf(w[8 + t]); }
      *(s16x8*)&Bs[bRow][bK]     = p0;
      *(s16x8*)&Bs[bRow][bK + 8] = p1;
    }
    __syncthreads();
    if (k0 + 64 < N_) APPLY_LD(k0 + 64);
#pragma unroll
    for (int kc = 0; kc < 2; ++kc) {
      s16x8 av[4], bv[2];
#pragma unroll
      for (int mt = 0; mt < 4; ++mt)
        av[mt] = *(const s16x8*)&As[wm * 64 + mt * 16 + lrow][kc * 32 + lk8];
#pragma unroll
      for (int nt = 0; nt < 2; ++nt)
        bv[nt] = *(const s16x8*)&Bs[wn * 32 + nt * 16 + lrow][kc * 32 + lk8];
#pragma unroll
      for (int mt = 0; mt < 4; ++mt)
#pragma unroll
        for (int nt = 0; nt < 2; ++nt)
          acc[mt][nt] = __builtin_amdgcn_mfma_f32_16x16x32_bf16(av[mt], bv[nt], acc[mt][nt], 0, 0, 0);
    }
    __syncthreads();
  }
#undef APPLY_LD

  const float g = gammaPtr[0];
  float* Yb = Y + (size_t)b * C_ * N_;
  const float* Rb = Resid + (size_t)b * C_ * N_;
#pragma unroll
  for (int mt = 0; mt < 4; ++mt)
#pragma unroll
    for (int nt = 0; nt < 2; ++nt) {
      const int col = m0 + wn * 32 + nt * 16 + lrow;
      const int rbase = c0 + wm * 64 + mt * 16 + (lane >> 4) * 4;
#pragma unroll
      for (int i = 0; i < 4; ++i) {
        const int row = rbase + i;
        const size_t off = (size_t)row * N_ + col;
        Yb[off] = g * acc[mt][nt][i] + Rb[off];
      }
    }
}

// ================================================================ conv3x3 split-bf16 on-the-fly (tiers 1/2 fallback)
__global__ __launch_bounds__(256)
void mfma_conv_split(const float* __restrict__ X, const float* __restrict__ Wt,
                     const float* __restrict__ sc, const float* __restrict__ bi,
                     float* __restrict__ Y)
{
  __shared__ unsigned short Ah[64][72], Al[64][72];
  __shared__ unsigned short Bh[64][72], Bl[64][72];
  const int b  = blockIdx.z;
  const int m0 = blockIdx.y * 64, n0 = blockIdx.x * 64;
  const int tid  = threadIdx.x;
  const int lane = tid & 63, wave = tid >> 6;
  const int wm = wave >> 1, wn = wave & 1;
  const int lrow = lane & 15, lk8 = (lane >> 4) * 8;
  const int sRow = tid >> 2, sK = (tid & 3) * 16;
  const int tj = tid & 63, tkg = (tid >> 6) * 16;
  const int n = n0 + tj, yy = n / W_, xx = n - yy * W_;
  const float* Xb = X + (size_t)b * C_ * N_;
  f32x4 acc[2][2] = {};

  for (int k0 = 0; k0 < KW; k0 += 64) {
    {
      const float* src = Wt + (size_t)(m0 + sRow) * KW + k0 + sK;
      unsigned short h[16], l[16];
#pragma unroll
      for (int t = 0; t < 16; ++t) {
        const float v = src[t];
        const unsigned short hh = f2bf(v);
        h[t] = hh;
        l[t] = f2bf(v - bf2f(hh));
      }
      *(s16x8*)&Ah[sRow][sK]     = *(s16x8*)&h[0];
      *(s16x8*)&Ah[sRow][sK + 8] = *(s16x8*)&h[8];
      *(s16x8*)&Al[sRow][sK]     = *(s16x8*)&l[0];
      *(s16x8*)&Al[sRow][sK + 8] = *(s16x8*)&l[8];
    }
    {
#pragma unroll
      for (int ii = 0; ii < 16; ii += 2) {
        unsigned int ph = 0, pl = 0;
#pragma unroll
        for (int hft = 0; hft < 2; ++hft) {
          const int kg = k0 + tkg + ii + hft;
          const int c = kg / 9, tap = kg - c * 9;
          const int t3 = tap / 3;
          const int iy = yy + t3 - 1, ix = xx + (tap - t3 * 3) - 1;
          float v = 0.f;
          if (iy >= 0 && iy < H_ && ix >= 0 && ix < W_)
            v = Xb[(size_t)c * N_ + iy * W_ + ix];
          const unsigned short hh = f2bf(v);
          const unsigned short ll = f2bf(v - bf2f(hh));
          ph |= ((unsigned int)hh) << (16 * hft);
          pl |= ((unsigned int)ll) << (16 * hft);
        }
        *(unsigned int*)&Bh[tj][tkg + ii] = ph;
        *(unsigned int*)&Bl[tj][tkg + ii] = pl;
      }
    }
    __syncthreads();
#pragma unroll
    for (int kc = 0; kc < 2; ++kc) {
      const s16x8 ah0 = *(const s16x8*)&Ah[wm * 32 + lrow     ][kc * 32 + lk8];
      const s16x8 ah1 = *(const s16x8*)&Ah[wm * 32 + 16 + lrow][kc * 32 + lk8];
      const s16x8 al0 = *(const s16x8*)&Al[wm * 32 + lrow     ][kc * 32 + lk8];
      const s16x8 al1 = *(const s16x8*)&Al[wm * 32 + 16 + lrow][kc * 32 + lk8];
      const s16x8 bh0 = *(const s16x8*)&Bh[wn * 32 + lrow     ][kc * 32 + lk8];
      const s16x8 bh1 = *(const s16x8*)&Bh[wn * 32 + 16 + lrow][kc * 32 + lk8];
      const s16x8 bl0 = *(const s16x8*)&Bl[wn * 32 + lrow     ][kc * 32 + lk8];
      const s16x8 bl1 = *(const s16x8*)&Bl[wn * 32 + 16 + lrow][kc * 32 + lk8];
      acc[0][0] = __builtin_amdgcn_mfma_f32_16x16x32_bf16(ah0, bh0, acc[0][0], 0, 0, 0);
      acc[0][1] = __builtin_amdgcn_mfma_f32_16x16x32_bf16(ah0, bh1, acc[0][1], 0, 0, 0);
      acc[1][0] = __builtin_amdgcn_mfma_f32_16x16x32_bf16(ah1, bh0, acc[1][0], 0, 0, 0);
      acc[1][1] = __builtin_amdgcn_mfma_f32_16x16x32_bf16(ah1, bh1, acc[1][1], 0, 0, 0);
      acc[0][0] = __builtin_amdgcn_mfma_f32_16x16x32_bf16(ah0, bl0, acc[0][0], 0, 0, 0);
      acc[0][1] = __builtin_amdgcn_mfma_f32_16x16x32_bf16(ah0, bl1, acc[0][1], 0, 0, 0);
      acc[1][0] = __builtin_amdgcn_mfma_f32_16x16x32_bf16(ah1, bl0, acc[1][0], 0, 0, 0);
      acc[1][1] = __builtin_amdgcn_mfma_f32_16x16x32_bf16(ah1, bl1, acc[1][1], 0, 0, 0);
      acc[0][0] = __builtin_amdgcn_mfma_f32_16x16x32_bf16(al0, bh0, acc[0][0], 0, 0, 0);
      acc[0][1] = __builtin_amdgcn_mfma_f32_16x16x32_bf16(al0, bh1, acc[0][1], 0, 0, 0);
      acc[1][0] = __builtin_amdgcn_mfma_f32_16x16x32_bf16(al1, bh0, acc[1][0], 0, 0, 0);
      acc[1][1] = __builtin_amdgcn_mfma_f32_16x16x32_bf16(al1, bh1, acc[1][1], 0, 0, 0);
    }
    __syncthreads();
  }

  float* Yb = Y + (size_t)b * C_ * N_;
#pragma unroll
  for (int mt = 0; mt < 2; ++mt)
#pragma unroll
    for (int nt = 0; nt < 2; ++nt) {
      const int col = n0 + wn * 32 + nt * 16 + lrow;
      const int rbase = m0 + wm * 32 + mt * 16 + (lane >> 4) * 4;
#pragma unroll
      for (int i = 0; i < 4; ++i) {
        const int row = rbase + i;
        const float v = fmaxf(acc[mt][nt][i] * sc[row] + bi[row], 0.f);
        Yb[(size_t)row * N_ + col] = v;
      }
    }
}

// ---------------------------------------------------------------- softmax stats (reads E)
__global__ __launch_bounds__(256)
void softmax_stats(const float* __restrict__ E, const float* __restrict__ M1,
                   const float* __restrict__ M2, float* __restrict__ st)
{
  const int row = blockIdx.x, b = blockIdx.y, tid = threadIdx.x;
  const float* er = E + ((size_t)b * N_ + row) * N_;
  const float* r1 = M1 + (size_t)row * N_;
  const float* r2 = M2 + (size_t)row * N_;
  float mx0 = -3.4e38f, mx1 = -3.4e38f, mx2 = -3.4e38f;
  for (int n = tid; n < N_; n += 256) {
    const float v = er[n];
    mx0 = fmaxf(mx0, v);
    if (r1[n] > 0.f) mx1 = fmaxf(mx1, v);
    if (r2[n] > 0.f) mx2 = fmaxf(mx2, v);
  }
  __shared__ float red[256];
  mx0 = blockReduceMax(mx0, red);
  mx1 = blockReduceMax(mx1, red);
  mx2 = blockReduceMax(mx2, red);
  float s0 = 0.f, s1 = 0.f, s2 = 0.f;
  for (int n = tid; n < N_; n += 256) {
    const float v = er[n];
    s0 += __expf(v - mx0);
    if (r1[n] > 0.f) s1 += __expf(v - mx1);
    if (r2[n] > 0.f) s2 += __expf(v - mx2);
  }
  s0 = blockReduceSum(s0, red);
  s1 = blockReduceSum(s1, red);
  s2 = blockReduceSum(s2, red);
  if (tid == 0) {
    float* o = st + ((size_t)b * N_ + row) * 6;
    o[0] = mx0; o[1] = s0; o[2] = mx1; o[3] = s1; o[4] = mx2; o[5] = s2;
  }
}

// ---------------------------------------------------------------- softmax stats (LITE, tier 2)
__global__ __launch_bounds__(256)
void softmax_stats_rq(const float* __restrict__ q, const float* __restrict__ k,
                      const float* __restrict__ M1, const float* __restrict__ M2,
                      float* __restrict__ st)
{
  const int row = blockIdx.x, b = blockIdx.y, tid = threadIdx.x;
  __shared__ float qs[CR_];
  if (tid < CR_) qs[tid] = q[((size_t)b * CR_ + tid) * N_ + row];
  __syncthreads();
  const float* kb_ = k + (size_t)b * CR_ * N_;
  float ev[9], mk1[9], mk2[9];
  const float* r1 = M1 + (size_t)row * N_;
  const float* r2 = M2 + (size_t)row * N_;
#pragma unroll
  for (int i = 0; i < 9; ++i) {
    const int n = tid + i * 256;
    float e = 0.f;
#pragma unroll 8
    for (int c = 0; c < CR_; ++c) e = fmaf(qs[c], kb_[(size_t)c * N_ + n], e);
    ev[i] = e; mk1[i] = r1[n]; mk2[i] = r2[n];
  }
  float mx0 = -3.4e38f, mx1 = -3.4e38f, mx2 = -3.4e38f;
#pragma unroll
  for (int i = 0; i < 9; ++i) {
    const float v = ev[i];
    mx0 = fmaxf(mx0, v);
    if (mk1[i] > 0.f) mx1 = fmaxf(mx1, v);
    if (mk2[i] > 0.f) mx2 = fmaxf(mx2, v);
  }
  __shared__ float red[256];
  mx0 = blockReduceMax(mx0, red);
  mx1 = blockReduceMax(mx1, red);
  mx2 = blockReduceMax(mx2, red);
  float s0 = 0.f, s1 = 0.f, s2 = 0.f;
#pragma unroll
  for (int i = 0; i < 9; ++i) {
    const float v = ev[i];
    s0 += __expf(v - mx0);
    if (mk1[i] > 0.f) s1 += __expf(v - mx1);
    if (mk2[i] > 0.f) s2 += __expf(v - mx2);
  }
  s0 = blockReduceSum(s0, red);
  s1 = blockReduceSum(s1, red);
  s2 = blockReduceSum(s2, red);
  if (tid == 0) {
    float* o = st + ((size_t)b * N_ + row) * 6;
    o[0] = mx0; o[1] = s0; o[2] = mx1; o[3] = s1; o[4] = mx2; o[5] = s2;
  }
}

// ---------------------------------------------------------------- attention apply (fp32, tier 1)
__global__ __launch_bounds__(256)
void attn_apply(const float* __restrict__ V, const float* __restrict__ E,
                const float* __restrict__ st, int variant,
                const float* __restrict__ mask,
                const float* __restrict__ gammaPtr,
                const float* __restrict__ R, float* __restrict__ Y)
{
  __shared__ float As[TK][LDSP], Bs[TK][LDSP];
  const int b  = blockIdx.z;
  const int c0 = blockIdx.y * 64, m0 = blockIdx.x * 64;
  const int tid = threadIdx.x, tx = tid & 15, ty = tid >> 4;
  const int ia = tid >> 2, ka = (tid & 3) * 4;
  const int jb = tid >> 2, kb = (tid & 3) * 4;
  const int mrow = m0 + jb;
  const float* sp = st + ((size_t)b * N_ + mrow) * 6 + variant * 2;
  const float mx = sp[0];
  const float rs = 1.f / sp[1];
  const float* Vb = V + (size_t)b * C_ * N_;
  const float* Er = E + ((size_t)b * N_ + mrow) * N_;
  const float* Mr = mask ? mask + (size_t)mrow * N_ : nullptr;
  float acc[4][4] = {};
  for (int k0 = 0; k0 < N_; k0 += TK) {
    const float4 a4 = *(const float4*)(Vb + (size_t)(c0 + ia) * N_ + k0 + ka);
    As[ka + 0][ia] = a4.x; As[ka + 1][ia] = a4.y;
    As[ka + 2][ia] = a4.z; As[ka + 3][ia] = a4.w;
    const float4 e4 = *(const float4*)(Er + k0 + kb);
    float w0, w1, w2, w3;
    if (Mr) {
      const float4 m4 = *(const float4*)(Mr + k0 + kb);
      w0 = (m4.x > 0.f) ? __expf(e4.x - mx) * rs : 0.f;
      w1 = (m4.y > 0.f) ? __expf(e4.y - mx) * rs : 0.f;
      w2 = (m4.z > 0.f) ? __expf(e4.z - mx) * rs : 0.f;
      w3 = (m4.w > 0.f) ? __expf(e4.w - mx) * rs : 0.f;
    } else {
      w0 = __expf(e4.x - mx) * rs; w1 = __expf(e4.y - mx) * rs;
      w2 = __expf(e4.z - mx) * rs; w3 = __expf(e4.w - mx) * rs;
    }
    Bs[kb + 0][jb] = w0; Bs[kb + 1][jb] = w1;
    Bs[kb + 2][jb] = w2; Bs[kb + 3][jb] = w3;
    __syncthreads();
    mm16(As, Bs, acc, ty, tx);
    __syncthreads();
  }
  const float g = gammaPtr[0];
  float* Yb = Y + (size_t)b * C_ * N_;
  const float* Rb = R + (size_t)b * C_ * N_;
#pragma unroll
  for (int i = 0; i < 4; ++i) {
    const int row = c0 + ty * 4 + i;
    const size_t off = (size_t)row * N_ + m0 + tx * 4;
    const float4 r4 = *(const float4*)(Rb + off);
    float4 o;
    o.x = g * acc[i][0] + r4.x; o.y = g * acc[i][1] + r4.y;
    o.z = g * acc[i][2] + r4.z; o.w = g * acc[i][3] + r4.w;
    *(float4*)(Yb + off) = o;
  }
}

// ---------------------------------------------------------------- attention apply (fp32 LITE, tier 2)
__global__ __launch_bounds__(256)
void attn_apply_rq(const float* __restrict__ V, const float* __restrict__ q,
                   const float* __restrict__ k,
                   const float* __restrict__ st, int variant,
                   const float* __restrict__ mask,
                   const float* __restrict__ gammaPtr,
                   const float* __restrict__ R, float* __restrict__ Y)
{
  __shared__ float As[TK][LDSP], Bs[TK][LDSP];
  __shared__ float qs[CR_][65];
  __shared__ float kss[CR_][17];
  const int b  = blockIdx.z;
  const int c0 = blockIdx.y * 64, m0 = blockIdx.x * 64;
  const int tid = threadIdx.x, tx = tid & 15, ty = tid >> 4;
  const int ia = tid >> 2, ka = (tid & 3) * 4;
  const int jb = tid >> 2, kb = (tid & 3) * 4;
  const int mrow = m0 + jb;
  const float* qb_ = q + (size_t)b * CR_ * N_;
  const float* kb_ = k + (size_t)b * CR_ * N_;
#pragma unroll
  for (int i = 0; i < 16; ++i) {
    const int idx = tid + i * 256;
    const int c = idx >> 6, j = idx & 63;
    qs[c][j] = qb_[(size_t)c * N_ + m0 + j];
  }
  const float* sp = st + ((size_t)b * N_ + mrow) * 6 + variant * 2;
  const float mx = sp[0];
  const float rs = 1.f / sp[1];
  const float* Vb = V + (size_t)b * C_ * N_;
  const float* Mr = mask ? mask + (size_t)mrow * N_ : nullptr;
  float acc[4][4] = {};
  __syncthreads();
  for (int k0 = 0; k0 < N_; k0 += TK) {
    const float4 a4 = *(const float4*)(Vb + (size_t)(c0 + ia) * N_ + k0 + ka);
    As[ka + 0][ia] = a4.x; As[ka + 1][ia] = a4.y;
    As[ka + 2][ia] = a4.z; As[ka + 3][ia] = a4.w;
#pragma unroll
    for (int i = 0; i < 4; ++i) {
      const int idx = tid + i * 256;
      const int c = idx >> 4, nn = idx & 15;
      kss[c][nn] = kb_[(size_t)c * N_ + k0 + nn];
    }
    __syncthreads();
    float e0 = 0.f, e1 = 0.f, e2 = 0.f, e3 = 0.f;
#pragma unroll 16
    for (int c = 0; c < CR_; ++c) {
      const float qv = qs[c][jb];
      e0 = fmaf(qv, kss[c][kb + 0], e0);
      e1 = fmaf(qv, kss[c][kb + 1], e1);
      e2 = fmaf(qv, kss[c][kb + 2], e2);
      e3 = fmaf(qv, kss[c][kb + 3], e3);
    }
    float w0, w1, w2, w3;
    if (Mr) {
      const float4 m4 = *(const float4*)(Mr + k0 + kb);
      w0 = (m4.x > 0.f) ? __expf(e0 - mx) * rs : 0.f;
      w1 = (m4.y > 0.f) ? __expf(e1 - mx) * rs : 0.f;
      w2 = (m4.z > 0.f) ? __expf(e2 - mx) * rs : 0.f;
      w3 = (m4.w > 0.f) ? __expf(e3 - mx) * rs : 0.f;
    } else {
      w0 = __expf(e0 - mx) * rs; w1 = __expf(e1 - mx) * rs;
      w2 = __expf(e2 - mx) * rs; w3 = __expf(e3 - mx) * rs;
    }
    Bs[kb + 0][jb] = w0; Bs[kb + 1][jb] = w1;
    Bs[kb + 2][jb] = w2; Bs[kb + 3][jb] = w3;
    __syncthreads();
    mm16(As, Bs, acc, ty, tx);
    __syncthreads();
  }
  const float g = gammaPtr[0];
  float* Yb = Y + (size_t)b * C_ * N_;
  const float* Rb = R + (size_t)b * C_ * N_;
#pragma unroll
  for (int i = 0; i < 4; ++i) {
    const int row = c0 + ty * 4 + i;
    const size_t off = (size_t)row * N_ + m0 + tx * 4;
    const float4 r4 = *(const float4*)(Rb + off);
    float4 o;
    o.x = g * acc[i][0] + r4.x; o.y = g * acc[i][1] + r4.y;
    o.z = g * acc[i][2] + r4.z; o.w = g * acc[i][3] + r4.w;
    *(float4*)(Yb + off) = o;
  }
}

// ---------------------------------------------------------------- chl row softmax
__global__ __launch_bounds__(256)
void chl_softmax(float* __restrict__ buf)
{
  const int row = blockIdx.x, tid = threadIdx.x;
  float* r = buf + (size_t)row * C_;
  const float v0 = -r[tid], v1 = -r[tid + 256];
  __shared__ float red[256];
  const float mx = blockReduceMax(fmaxf(v0, v1), red);
  const float e0 = __expf(v0 - mx), e1 = __expf(v1 - mx);
  const float s = blockReduceSum(e0 + e1, red);
  const float rs = 1.f / s;
  r[tid] = e0 * rs;
  r[tid + 256] = e1 * rs;
}

// ================================================================ launch
extern "C" void kernel_launch(void* const* d_in, const int* in_sizes, int n_in,
                              void* d_out, int out_size, void* d_ws, size_t ws_size,
                              hipStream_t stream)
{
  (void)in_sizes; (void)n_in; (void)out_size;
  const float* x      = (const float*)d_in[0];
  const float* wq     = (const float*)d_in[1];
  const float* bq     = (const float*)d_in[2];
  const float* wk     = (const float*)d_in[3];
  const float* bk     = (const float*)d_in[4];
  const float* wv0    = (const float*)d_in[5];
  const float* bv0    = (const float*)d_in[6];
  const float* c1w    = (const float*)d_in[7];
  const float* c1s    = (const float*)d_in[8];
  const float* c1b    = (const float*)d_in[9];
  const float* c2w    = (const float*)d_in[10];
  const float* c2s    = (const float*)d_in[11];
  const float* c2b    = (const float*)d_in[12];
  const float* gamma  = (const float*)d_in[13];
  const float* gamma1 = (const float*)d_in[14];
  const float* gamma2 = (const float*)d_in[15];
  const float* c1qw   = (const float*)d_in[16];
  const float* c1qs   = (const float*)d_in[17];
  const float* c1qb   = (const float*)d_in[18];
  const float* c1ew   = (const float*)d_in[19];
  const float* c1eb   = (const float*)d_in[20];
  const float* c2qw   = (const float*)d_in[21];
  const float* c2qs   = (const float*)d_in[22];
  const float* c2qb   = (const float*)d_in[23];
  const float* c2ew   = (const float*)d_in[24];
  const float* c2eb   = (const float*)d_in[25];
  const float* mask1  = (const float*)d_in[26];
  const float* mask2  = (const float*)d_in[27];

  const size_t QK = 589824;            // B*CR*N
  const size_t CQ = 1179648;           // B*C4*N
  const size_t VV = 4718592;           // B*C*N
  const size_t EE = 21233664;          // B*N*N
  const size_t ST = 55296;             // B*N*6
  const size_t CE = 262144;            // B*C4*C
  const size_t CA = 1048576;           // B*C*C
  const size_t ELEMS_B = CQ + VV + EE + ST + VV + CE + CA;       // 33,216,512
  const size_t ELEMS_A = ELEMS_B + EE / 2;                       // + time-shared bf16 region
  const int tier = (ws_size >= ELEMS_A * 4) ? 0
                 : (ws_size >= ELEMS_B * 4) ? 1 : 2;

  float* ws = (float*)d_ws;
  float *qbuf, *kbuf, *cq, *vbuf, *ebuf, *stb, *o0, *ce1, *cat_;
  unsigned short *Xh = nullptr, *Xl = nullptr,
                 *W1h = nullptr, *W1l = nullptr, *W2h = nullptr, *W2l = nullptr,
                 *xTh = nullptr, *xTl = nullptr, *oTh = nullptr, *oTl = nullptr;
  float *qTf = nullptr, *kTf = nullptr;
  if (tier <= 1) {
    qbuf = ws; kbuf = ws + QK;         // (tier1 only; dead after energy)
    cq   = ws;                          // aliases q+k region
    vbuf = ws + CQ;
    ebuf = vbuf + VV;
    stb  = ebuf + EE;
    o0   = stb + ST;
    ce1  = o0 + VV;
    cat_ = ce1 + CE;
    if (tier == 0) {
      unsigned short* reg = (unsigned short*)(cat_ + CA);   // EE shorts, time-shared
      // pre-loop: x^T hi/lo (dead after v-proj) + q^T/k^T fp32 (dead after energy)
      xTh = reg;                       //  4,718,592
      xTl = reg + 4718592;             // -> 9,437,184
      qTf = (float*)(reg + 9437184);   //  589,824 f = 1,179,648 shorts
      kTf = qTf + 589824;              // -> 11,796,480 shorts
      // persistent (whole run): conv weights hi/lo for both passes
      W1h = reg + 11796480;            //  2,359,296
      W1l = reg + 14155776;
      W2h = reg + 16515072;
      W2l = reg + 18874368;            // -> 21,233,664 == EE exactly
      // per-pass (alias xT region): padded act / o^T
      Xh  = reg;                       //  5,120,000
      Xl  = reg + 5120000;             // -> 10,240,000 < 11,796,480 OK
      oTh = reg;                       //  4,718,592
      oTl = reg + 4718592;             // -> 9,437,184 OK
    }
  } else {
    qbuf = ws; kbuf = qbuf + QK;       // live all passes
    cq   = kbuf + QK;
    vbuf = cq + CQ;
    stb  = vbuf + VV;
    o0   = stb + ST;
    ce1  = o0 + VV;
    cat_ = ce1 + CE;
    ebuf = nullptr;
  }
  float* t0 = (float*)d_out;           // pre-conv scratch aliases d_out
  unsigned short* vb16 = (unsigned short*)vbuf;  // tier-0: bf16 V in vbuf region

  const dim3 TPB(256);
  const long long sxc = (long long)C_ * N_;
  const long long sqr = (long long)CR_ * N_;
  const long long sq4 = (long long)C4_ * N_;
  const long long sNN = (long long)N_ * N_;
  const long long sNC = (long long)N_ * C_;
  const long long sCC = (long long)C_ * C_;
  const long long sEC = (long long)C4_ * C_;
  const long long sNR = (long long)N_ * CR_;

  if (tier == 0) {
    tr_split<<<dim3(B_, 36), TPB, 0, stream>>>(x, xTh, xTl);
    mfma_sp<<<dim3(36, 1, 4), TPB, 0, stream>>>(wq, 0, C_, xTh, xTl, sNC, C_, 1,
        qTf, sNR, CR_, 1, C_, 1, nullptr, bq, 0);
    mfma_sp<<<dim3(36, 1, 4), TPB, 0, stream>>>(wk, 0, C_, xTh, xTl, sNC, C_, 1,
        kTf, sNR, CR_, 1, C_, 1, nullptr, bk, 0);
    mfma_gemm<<<dim3(36, 8, 4), TPB, 0, stream>>>(wv0, 0, 0, C_, xTh, sNC, C_, 2,
        vb16, 1, sxc, N_, C_, nullptr, bv0, 0, nullptr, nullptr, 0);
    mfma_sp<<<dim3(36, 36, 4), TPB, 0, stream>>>(qTf, sNR, CR_, kTf, nullptr, sNR, CR_, 0,
        ebuf, sNN, N_, 0, CR_, 1, nullptr, nullptr, 0);
    softmax_stats<<<dim3(N_, 4), TPB, 0, stream>>>(ebuf, mask1, mask2, stb);
    wsplit<<<dim3(512, 9), TPB, 0, stream>>>(c1w, W1h, W1l);
    wsplit<<<dim3(512, 9), TPB, 0, stream>>>(c2w, W2h, W2l);
  } else if (tier == 1) {
    gemm_nn<<<dim3(36, 1, 4), TPB, 0, stream>>>(wq, 0, C_, x, sxc, N_,
                                                qbuf, sqr, N_, C_, nullptr, bq, 0);
    gemm_nn<<<dim3(36, 1, 4), TPB, 0, stream>>>(wk, 0, C_, x, sxc, N_,
                                                kbuf, sqr, N_, C_, nullptr, bk, 0);
    mfma_gemm<<<dim3(36, 8, 4), TPB, 0, stream>>>(wv0, 0, 0, C_, x, sxc, N_, 1,
        vbuf, 0, sxc, N_, C_, nullptr, bv0, 0, nullptr, nullptr, 0);
    gemm_tn<<<dim3(36, 36, 4), TPB, 0, stream>>>(qbuf, sqr, N_, kbuf, sqr, N_,
                                                 ebuf, sNN, N_, CR_);
    softmax_stats<<<dim3(N_, 4), TPB, 0, stream>>>(ebuf, mask1, mask2, stb);
  } else {
    gemm_nn<<<dim3(36, 1, 4), TPB, 0, stream>>>(wq, 0, C_, x, sxc, N_,
                                                qbuf, sqr, N_, C_, nullptr, bq, 0);
    gemm_nn<<<dim3(36, 1, 4), TPB, 0, stream>>>(wk, 0, C_, x, sxc, N_,
                                                kbuf, sqr, N_, C_, nullptr, bk, 0);
    mfma_gemm<<<dim3(36, 8, 4), TPB, 0, stream>>>(wv0, 0, 0, C_, x, sxc, N_, 1,
        vbuf, 0, sxc, N_, C_, nullptr, bv0, 0, nullptr, nullptr, 0);
    softmax_stats_rq<<<dim3(N_, 4), TPB, 0, stream>>>(qbuf, kbuf, mask1, mask2, stb);
  }

  for (int pass = 0; pass < 3; ++pass) {
    const float* msk = (pass == 0) ? nullptr : (pass == 1 ? mask1 : mask2);
    const float* gm  = (pass == 0) ? gamma : (pass == 1 ? gamma1 : gamma2);
    const float* res = (pass == 0) ? x : o0;
    float* dst = (pass == 2) ? (float*)d_out : t0;

    // ---- attention apply: dst = gm * V . P^T + res
    if (tier == 0) {
      mfma_apply<<<dim3(36, 4, 4), TPB, 0, stream>>>(vb16, ebuf, stb, pass, msk,
                                                     gm, res, dst);
    } else if (tier == 1) {
      attn_apply<<<dim3(36, 8, 4), TPB, 0, stream>>>(vbuf, ebuf, stb, pass, msk,
                                                     gm, res, dst);
    } else {
      attn_apply_rq<<<dim3(36, 8, 4), TPB, 0, stream>>>(vbuf, qbuf, kbuf, stb, pass, msk,
                                                        gm, res, dst);
    }
    if (pass == 2) break;

    // ---- conv3x3 + BN + ReLU  (dst -> o0)
    const float* cs = (pass == 0) ? c1s : c2s;
    const float* cb = (pass == 0) ? c1b : c2b;
    if (tier == 0) {
      pad_split2<<<dim3(B_, 37), TPB, 0, stream>>>(dst, Xh, Xl);
      mfma_conv3<<<dim3(36, 4, 4), TPB, 0, stream>>>(Xh, Xl,
          (pass == 0) ? W1h : W2h, (pass == 0) ? W1l : W2l, cs, cb, o0);
    } else {
      const float* cw = (pass == 0) ? c1w : c2w;
      mfma_conv_split<<<dim3(36, 8, 4), TPB, 0, stream>>>(dst, cw, cs, cb, o0);
    }

    // ---- chl block on o0 -> vbuf
    const float* qw = (pass == 0) ? c1qw : c2qw;
    const float* qs = (pass == 0) ? c1qs : c2qs;
    const float* qb = (pass == 0) ? c1qb : c2qb;
    const float* ew = (pass == 0) ? c1ew : c2ew;
    const float* eb = (pass == 0) ? c1eb : c2eb;
    if (tier == 0) {
      tr_split<<<dim3(B_, 36), TPB, 0, stream>>>(o0, oTh, oTl);
      mfma_sp<<<dim3(36, 2, 4), TPB, 0, stream>>>(qw, 0, C_, oTh, oTl, sNC, C_, 1,
          cq, sq4, N_, 0, C_, 1, qs, qb, 1);
      zero_buf<<<dim3(256), TPB, 0, stream>>>((float4*)ce1, (int)(CE / 4));
      mfma_sp<<<dim3(8, 2, 16), TPB, 0, stream>>>(cq, sq4, N_, o0, nullptr, sxc, N_, 0,
          ce1, sEC, C4_, 2, N_, 4, nullptr, nullptr, 0);
      mfma_sp<<<dim3(8, 8, 4), TPB, 0, stream>>>(ew, 0, C4_, ce1, nullptr, sEC, C4_, 0,
          cat_, sCC, C_, 0, C4_, 1, nullptr, eb, 0);
      chl_softmax<<<dim3(C_ * 4), TPB, 0, stream>>>(cat_);
      mfma_gemm<<<dim3(36, 8, 4), TPB, 0, stream>>>(cat_, 0, sCC, C_, oTh, sNC, C_, 2,
          vb16, 1, sxc, N_, C_, nullptr, nullptr, 0, nullptr, nullptr, 0);
    } else {
      gemm_nn<<<dim3(36, 2, 4), TPB, 0, stream>>>(qw, 0, C_, o0, sxc, N_,
                                                  cq, sq4, N_, C_, qs, qb, 1);
      zero_buf<<<dim3(256), TPB, 0, stream>>>((float4*)ce1, (int)(CE / 4));
      gemm_nt_splitk<<<dim3(8, 2, 16), TPB, 0, stream>>>(cq, sq4, N_, o0, sxc, N_,
                                                         ce1, sEC, C_, N_);
      gemm_nn<<<dim3(8, 8, 4), TPB, 0, stream>>>(ew, 0, C4_, ce1, sEC, C_,
                                                 cat_, sCC, C_, C4_, nullptr, eb, 0);
      chl_softmax<<<dim3(C_ * 4), TPB, 0, stream>>>(cat_);
      mfma_gemm<<<dim3(36, 8, 4), TPB, 0, stream>>>(cat_, 0, sCC, C_, o0, sxc, N_, 1,
          vbuf, 0, sxc, N_, C_, nullptr, nullptr, 0, nullptr, nullptr, 0);
    }
  }
}

// Round 8
// 1221.546 us; speedup vs baseline: 2.7960x; 1.0505x over previous
//
#include <hip/hip_runtime.h>

#define B_  4
#define C_  512
#define H_  48
#define W_  48
#define N_  2304      // H_*W_
#define CR_ 64        // C_/R
#define C4_ 128       // C_/4
#define TK  16
#define LDSP 68       // fp32 helper tiles: 64 + 4 pad
#define PW  50        // padded width/height
#define PN  2500      // PW*PW
#define KW  4608      // C_*9
#define NW  36        // N_/64 mask words per row

typedef short  s16x8 __attribute__((ext_vector_type(8)));   // 8 bf16 (4 VGPR)
typedef float  f32x4 __attribute__((ext_vector_type(4)));

// fp32 -> bf16 bits, round-to-nearest-even
__device__ __forceinline__ unsigned short f2bf(float f) {
  union { float f; unsigned int u; } v; v.f = f;
  const unsigned int u = v.u;
  return (unsigned short)((u + 0x7FFFu + ((u >> 16) & 1u)) >> 16);
}
__device__ __forceinline__ float bf2f(unsigned short h) {
  union { unsigned int u; float f; } v; v.u = ((unsigned int)h) << 16;
  return v.f;
}

// ---------------------------------------------------------------- reductions
__device__ __forceinline__ float blockReduceMax(float v, float* red) {
  const int tid = threadIdx.x;
  red[tid] = v; __syncthreads();
  for (int s = 128; s > 0; s >>= 1) {
    if (tid < s) red[tid] = fmaxf(red[tid], red[tid + s]);
    __syncthreads();
  }
  float r = red[0]; __syncthreads();
  return r;
}
__device__ __forceinline__ float blockReduceSum(float v, float* red) {
  const int tid = threadIdx.x;
  red[tid] = v; __syncthreads();
  for (int s = 128; s > 0; s >>= 1) {
    if (tid < s) red[tid] += red[tid + s];
    __syncthreads();
  }
  float r = red[0]; __syncthreads();
  return r;
}

// ---------------------------------------------------------------- fp32 micro-kernel (fallback tiers)
__device__ __forceinline__ void mm16(const float (*As)[LDSP], const float (*Bs)[LDSP],
                                     float acc[4][4], int ty, int tx)
{
#pragma unroll
  for (int kk = 0; kk < TK; ++kk) {
    const float4 a4 = *(const float4*)(&As[kk][ty * 4]);
    const float4 b4 = *(const float4*)(&Bs[kk][tx * 4]);
    const float av[4] = {a4.x, a4.y, a4.z, a4.w};
    const float bv[4] = {b4.x, b4.y, b4.z, b4.w};
#pragma unroll
    for (int i = 0; i < 4; ++i)
#pragma unroll
      for (int j = 0; j < 4; ++j)
        acc[i][j] = fmaf(av[i], bv[j], acc[i][j]);
  }
}

// ---------------------------------------------------------------- fp32 GEMM NN (fallback)
__global__ __launch_bounds__(256)
void gemm_nn(const float* __restrict__ A, long long aStrideB, int lda,
             const float* __restrict__ B, long long bStrideB, int ldb,
             float* __restrict__ Y, long long yStrideB, int ldy,
             int K,
             const float* __restrict__ scale, const float* __restrict__ bias, int relu)
{
  __shared__ float As[TK][LDSP], Bs[TK][LDSP];
  const int b  = blockIdx.z;
  const int m0 = blockIdx.y * 64, n0 = blockIdx.x * 64;
  const int tid = threadIdx.x, tx = tid & 15, ty = tid >> 4;
  const int ia = tid >> 2, ka = (tid & 3) * 4;
  const int jb = tid & 63, kb = (tid >> 6) * 4;
  const float* Ab = A + (size_t)b * aStrideB;
  const float* Bb = B + (size_t)b * bStrideB;
  float acc[4][4] = {};
  for (int k0 = 0; k0 < K; k0 += TK) {
    const float4 a4 = *(const float4*)(Ab + (size_t)(m0 + ia) * lda + k0 + ka);
    As[ka + 0][ia] = a4.x; As[ka + 1][ia] = a4.y;
    As[ka + 2][ia] = a4.z; As[ka + 3][ia] = a4.w;
#pragma unroll
    for (int t = 0; t < 4; ++t)
      Bs[kb + t][jb] = Bb[(size_t)(k0 + kb + t) * ldb + n0 + jb];
    __syncthreads();
    mm16(As, Bs, acc, ty, tx);
    __syncthreads();
  }
  float* Yb = Y + (size_t)b * yStrideB;
#pragma unroll
  for (int i = 0; i < 4; ++i) {
    const int row = m0 + ty * 4 + i;
    const float s = scale ? scale[row] : 1.f;
    const float bb = bias ? bias[row] : 0.f;
    float4 o;
    o.x = acc[i][0] * s + bb; o.y = acc[i][1] * s + bb;
    o.z = acc[i][2] * s + bb; o.w = acc[i][3] * s + bb;
    if (relu) {
      o.x = fmaxf(o.x, 0.f); o.y = fmaxf(o.y, 0.f);
      o.z = fmaxf(o.z, 0.f); o.w = fmaxf(o.w, 0.f);
    }
    *(float4*)(Yb + (size_t)row * ldy + n0 + tx * 4) = o;
  }
}

// ---------------------------------------------------------------- fp32 GEMM NT split-K x4 (fallback)
__global__ __launch_bounds__(256)
void gemm_nt_splitk(const float* __restrict__ A, long long aStrideB, int lda,
                    const float* __restrict__ B, long long bStrideB, int ldb,
                    float* __restrict__ Y, long long yStrideB, int ldy, int K)
{
  __shared__ float As[TK][LDSP], Bs[TK][LDSP];
  const int z = blockIdx.z, b = z >> 2, ks = z & 3;
  const int kBeg = ks * (K / 4), kEnd = kBeg + K / 4;
  const int m0 = blockIdx.y * 64, n0 = blockIdx.x * 64;
  const int tid = threadIdx.x, tx = tid & 15, ty = tid >> 4;
  const int ia = tid >> 2, ka = (tid & 3) * 4;
  const float* Ab = A + (size_t)b * aStrideB;
  const float* Bb = B + (size_t)b * bStrideB;
  float acc[4][4] = {};
  for (int k0 = kBeg; k0 < kEnd; k0 += TK) {
    const float4 a4 = *(const float4*)(Ab + (size_t)(m0 + ia) * lda + k0 + ka);
    As[ka + 0][ia] = a4.x; As[ka + 1][ia] = a4.y;
    As[ka + 2][ia] = a4.z; As[ka + 3][ia] = a4.w;
    const float4 b4 = *(const float4*)(Bb + (size_t)(n0 + ia) * ldb + k0 + ka);
    Bs[ka + 0][ia] = b4.x; Bs[ka + 1][ia] = b4.y;
    Bs[ka + 2][ia] = b4.z; Bs[ka + 3][ia] = b4.w;
    __syncthreads();
    mm16(As, Bs, acc, ty, tx);
    __syncthreads();
  }
  float* Yb = Y + (size_t)b * yStrideB;
#pragma unroll
  for (int i = 0; i < 4; ++i) {
    const int row = m0 + ty * 4 + i;
#pragma unroll
    for (int j = 0; j < 4; ++j)
      atomicAdd(Yb + (size_t)row * ldy + n0 + tx * 4 + j, acc[i][j]);
  }
}

// ---------------------------------------------------------------- zero buffer
__global__ __launch_bounds__(256)
void zero_buf(float4* __restrict__ p, int n4)
{
  const int i = blockIdx.x * 256 + threadIdx.x;
  if (i < n4) p[i] = float4{0.f, 0.f, 0.f, 0.f};
}

// ---------------------------------------------------------------- fp32 GEMM TN (fallback energy)
__global__ __launch_bounds__(256)
void gemm_tn(const float* __restrict__ A, long long aStrideB, int lda,
             const float* __restrict__ B, long long bStrideB, int ldb,
             float* __restrict__ Y, long long yStrideB, int ldy, int K)
{
  __shared__ float As[TK][LDSP], Bs[TK][LDSP];
  const int b  = blockIdx.z;
  const int m0 = blockIdx.y * 64, n0 = blockIdx.x * 64;
  const int tid = threadIdx.x, tx = tid & 15, ty = tid >> 4;
  const int i2 = tid & 63, k2 = (tid >> 6) * 4;
  const float* Ab = A + (size_t)b * aStrideB;
  const float* Bb = B + (size_t)b * bStrideB;
  float acc[4][4] = {};
  for (int k0 = 0; k0 < K; k0 += TK) {
#pragma unroll
    for (int t = 0; t < 4; ++t) {
      As[k2 + t][i2] = Ab[(size_t)(k0 + k2 + t) * lda + m0 + i2];
      Bs[k2 + t][i2] = Bb[(size_t)(k0 + k2 + t) * ldb + n0 + i2];
    }
    __syncthreads();
    mm16(As, Bs, acc, ty, tx);
    __syncthreads();
  }
  float* Yb = Y + (size_t)b * yStrideB;
#pragma unroll
  for (int i = 0; i < 4; ++i) {
    const int row = m0 + ty * 4 + i;
    float4 o = {acc[i][0], acc[i][1], acc[i][2], acc[i][3]};
    *(float4*)(Yb + (size_t)row * ldy + n0 + tx * 4) = o;
  }
}

// ================================================================ MFMA GEMM (single bf16, non-logit paths)
__global__ __launch_bounds__(256)
void mfma_gemm(const void* __restrict__ Av, int aBf16, long long aSB, int lda,
               const void* __restrict__ Bv, long long bSB, int ldb, int bMode,
               void* __restrict__ Yv, int outBf16, long long ySB, int ldy, int K,
               const float* __restrict__ scale, const float* __restrict__ bias,
               int relu,
               const float* __restrict__ gammaPtr, const float* __restrict__ Resid,
               long long rSB)
{
  __shared__ unsigned short As[64][72];
  __shared__ unsigned short Bs[64][72];
  const int b  = blockIdx.z;
  const int m0 = blockIdx.y * 64, n0 = blockIdx.x * 64;
  const int tid  = threadIdx.x;
  const int lane = tid & 63, wave = tid >> 6;
  const int wm = wave >> 1, wn = wave & 1;
  const int lrow = lane & 15, lk8 = (lane >> 4) * 8;
  const int sRow = tid >> 2, sK = (tid & 3) * 16;
  const int tj = tid & 63, tkg = (tid >> 6) * 16;
  f32x4 acc[2][2] = {};

  for (int k0 = 0; k0 < K; k0 += 64) {
    if (aBf16) {
      const unsigned short* Ab = (const unsigned short*)Av + (size_t)b * aSB;
      const unsigned short* src = Ab + (size_t)(m0 + sRow) * lda + k0 + sK;
      *(s16x8*)&As[sRow][sK]     = *(const s16x8*)(src);
      *(s16x8*)&As[sRow][sK + 8] = *(const s16x8*)(src + 8);
    } else {
      const float* Ab = (const float*)Av + (size_t)b * aSB;
      const float* src = Ab + (size_t)(m0 + sRow) * lda + k0 + sK;
      const float4 x0 = *(const float4*)(src);
      const float4 x1 = *(const float4*)(src + 4);
      const float4 x2 = *(const float4*)(src + 8);
      const float4 x3 = *(const float4*)(src + 12);
      s16x8 p0 = { (short)f2bf(x0.x), (short)f2bf(x0.y), (short)f2bf(x0.z), (short)f2bf(x0.w),
                   (short)f2bf(x1.x), (short)f2bf(x1.y), (short)f2bf(x1.z), (short)f2bf(x1.w) };
      s16x8 p1 = { (short)f2bf(x2.x), (short)f2bf(x2.y), (short)f2bf(x2.z), (short)f2bf(x2.w),
                   (short)f2bf(x3.x), (short)f2bf(x3.y), (short)f2bf(x3.z), (short)f2bf(x3.w) };
      *(s16x8*)&As[sRow][sK]     = p0;
      *(s16x8*)&As[sRow][sK + 8] = p1;
    }
    if (bMode == 1) {
      const float* Bb = (const float*)Bv + (size_t)b * bSB;
#pragma unroll
      for (int ii = 0; ii < 16; ii += 2) {
        const float v0 = Bb[(size_t)(k0 + tkg + ii)     * ldb + n0 + tj];
        const float v1 = Bb[(size_t)(k0 + tkg + ii + 1) * ldb + n0 + tj];
        *(unsigned int*)&Bs[tj][tkg + ii] =
            (unsigned int)f2bf(v0) | ((unsigned int)f2bf(v1) << 16);
      }
    } else if (bMode == 2) {
      const unsigned short* Bb = (const unsigned short*)Bv + (size_t)b * bSB;
      const unsigned short* src = Bb + (size_t)(n0 + sRow) * ldb + k0 + sK;
      *(s16x8*)&Bs[sRow][sK]     = *(const s16x8*)(src);
      *(s16x8*)&Bs[sRow][sK + 8] = *(const s16x8*)(src + 8);
    } else {
      const float* Bb = (const float*)Bv + (size_t)b * bSB;
      const float* src = Bb + (size_t)(n0 + sRow) * ldb + k0 + sK;
      const float4 x0 = *(const float4*)(src);
      const float4 x1 = *(const float4*)(src + 4);
      const float4 x2 = *(const float4*)(src + 8);
      const float4 x3 = *(const float4*)(src + 12);
      s16x8 p0 = { (short)f2bf(x0.x), (short)f2bf(x0.y), (short)f2bf(x0.z), (short)f2bf(x0.w),
                   (short)f2bf(x1.x), (short)f2bf(x1.y), (short)f2bf(x1.z), (short)f2bf(x1.w) };
      s16x8 p1 = { (short)f2bf(x2.x), (short)f2bf(x2.y), (short)f2bf(x2.z), (short)f2bf(x2.w),
                   (short)f2bf(x3.x), (short)f2bf(x3.y), (short)f2bf(x3.z), (short)f2bf(x3.w) };
      *(s16x8*)&Bs[sRow][sK]     = p0;
      *(s16x8*)&Bs[sRow][sK + 8] = p1;
    }
    __syncthreads();
#pragma unroll
    for (int kc = 0; kc < 2; ++kc) {
      const s16x8 a0 = *(const s16x8*)&As[wm * 32 + lrow     ][kc * 32 + lk8];
      const s16x8 a1 = *(const s16x8*)&As[wm * 32 + 16 + lrow][kc * 32 + lk8];
      const s16x8 b0 = *(const s16x8*)&Bs[wn * 32 + lrow     ][kc * 32 + lk8];
      const s16x8 b1 = *(const s16x8*)&Bs[wn * 32 + 16 + lrow][kc * 32 + lk8];
      acc[0][0] = __builtin_amdgcn_mfma_f32_16x16x32_bf16(a0, b0, acc[0][0], 0, 0, 0);
      acc[0][1] = __builtin_amdgcn_mfma_f32_16x16x32_bf16(a0, b1, acc[0][1], 0, 0, 0);
      acc[1][0] = __builtin_amdgcn_mfma_f32_16x16x32_bf16(a1, b0, acc[1][0], 0, 0, 0);
      acc[1][1] = __builtin_amdgcn_mfma_f32_16x16x32_bf16(a1, b1, acc[1][1], 0, 0, 0);
    }
    __syncthreads();
  }

  const float g = gammaPtr ? gammaPtr[0] : 0.f;
  const float* Rb = Resid ? Resid + (size_t)b * rSB : nullptr;
#pragma unroll
  for (int mt = 0; mt < 2; ++mt)
#pragma unroll
    for (int nt = 0; nt < 2; ++nt) {
      const int col = n0 + wn * 32 + nt * 16 + lrow;
      const int rbase = m0 + wm * 32 + mt * 16 + (lane >> 4) * 4;
#pragma unroll
      for (int i = 0; i < 4; ++i) {
        const int row = rbase + i;
        float v = acc[mt][nt][i];
        if (Rb) {
          v = g * v + Rb[(size_t)row * ldy + col];
        } else {
          const float s  = scale ? scale[row] : 1.f;
          const float bb = bias ? bias[row] : 0.f;
          v = v * s + bb;
          if (relu) v = fmaxf(v, 0.f);
        }
        if (outBf16)
          ((unsigned short*)Yv)[(size_t)b * ySB + (size_t)row * ldy + col] = f2bf(v);
        else
          ((float*)Yv)[(size_t)b * ySB + (size_t)row * ldy + col] = v;
      }
    }
}

// ================================================================ split-bf16 MFMA GEMM (fp32-grade, logit chain)
__global__ __launch_bounds__(256)
void mfma_sp(const float* __restrict__ A, long long aSB, int lda,
             const void* __restrict__ B0v, const void* __restrict__ B1v,
             long long bSB, int ldb, int bPre,
             float* __restrict__ Y, long long ySB, int ldy, int outMode,
             int K, int nSplit,
             const float* __restrict__ scale, const float* __restrict__ bias, int relu)
{
  __shared__ unsigned short Ah[64][72], Al[64][72];
  __shared__ unsigned short Bh[64][72], Bl[64][72];
  const int z = blockIdx.z;
  const int b = z / nSplit, ks = z % nSplit;
  const int kLen = K / nSplit, kBeg = ks * kLen, kEnd = kBeg + kLen;
  const int m0 = blockIdx.y * 64, n0 = blockIdx.x * 64;
  const int tid  = threadIdx.x;
  const int lane = tid & 63, wave = tid >> 6;
  const int wm = wave >> 1, wn = wave & 1;
  const int lrow = lane & 15, lk8 = (lane >> 4) * 8;
  const int sRow = tid >> 2, sK = (tid & 3) * 16;
  const float* Ab = A + (size_t)b * aSB;
  f32x4 acc[2][2] = {};

  for (int k0 = kBeg; k0 < kEnd; k0 += 64) {
    {
      const float* src = Ab + (size_t)(m0 + sRow) * lda + k0 + sK;
      s16x8 h0, l0, h1, l1;
#pragma unroll
      for (int t = 0; t < 8; ++t) {
        const float v = src[t];
        const unsigned short hh = f2bf(v);
        h0[t] = (short)hh; l0[t] = (short)f2bf(v - bf2f(hh));
      }
#pragma unroll
      for (int t = 0; t < 8; ++t) {
        const float v = src[8 + t];
        const unsigned short hh = f2bf(v);
        h1[t] = (short)hh; l1[t] = (short)f2bf(v - bf2f(hh));
      }
      *(s16x8*)&Ah[sRow][sK] = h0; *(s16x8*)&Ah[sRow][sK + 8] = h1;
      *(s16x8*)&Al[sRow][sK] = l0; *(s16x8*)&Al[sRow][sK + 8] = l1;
    }
    if (bPre) {
      const unsigned short* Bh_ = (const unsigned short*)B0v + (size_t)b * bSB;
      const unsigned short* Bl_ = (const unsigned short*)B1v + (size_t)b * bSB;
      const size_t off = (size_t)(n0 + sRow) * ldb + k0 + sK;
      *(s16x8*)&Bh[sRow][sK]     = *(const s16x8*)(Bh_ + off);
      *(s16x8*)&Bh[sRow][sK + 8] = *(const s16x8*)(Bh_ + off + 8);
      *(s16x8*)&Bl[sRow][sK]     = *(const s16x8*)(Bl_ + off);
      *(s16x8*)&Bl[sRow][sK + 8] = *(const s16x8*)(Bl_ + off + 8);
    } else {
      const float* Bb = (const float*)B0v + (size_t)b * bSB;
      const float* src = Bb + (size_t)(n0 + sRow) * ldb + k0 + sK;
      s16x8 h0, l0, h1, l1;
#pragma unroll
      for (int t = 0; t < 8; ++t) {
        const float v = src[t];
        const unsigned short hh = f2bf(v);
        h0[t] = (short)hh; l0[t] = (short)f2bf(v - bf2f(hh));
      }
#pragma unroll
      for (int t = 0; t < 8; ++t) {
        const float v = src[8 + t];
        const unsigned short hh = f2bf(v);
        h1[t] = (short)hh; l1[t] = (short)f2bf(v - bf2f(hh));
      }
      *(s16x8*)&Bh[sRow][sK] = h0; *(s16x8*)&Bh[sRow][sK + 8] = h1;
      *(s16x8*)&Bl[sRow][sK] = l0; *(s16x8*)&Bl[sRow][sK + 8] = l1;
    }
    __syncthreads();
#pragma unroll
    for (int kc = 0; kc < 2; ++kc) {
      const s16x8 ah0 = *(const s16x8*)&Ah[wm * 32 + lrow     ][kc * 32 + lk8];
      const s16x8 ah1 = *(const s16x8*)&Ah[wm * 32 + 16 + lrow][kc * 32 + lk8];
      const s16x8 al0 = *(const s16x8*)&Al[wm * 32 + lrow     ][kc * 32 + lk8];
      const s16x8 al1 = *(const s16x8*)&Al[wm * 32 + 16 + lrow][kc * 32 + lk8];
      const s16x8 bh0 = *(const s16x8*)&Bh[wn * 32 + lrow     ][kc * 32 + lk8];
      const s16x8 bh1 = *(const s16x8*)&Bh[wn * 32 + 16 + lrow][kc * 32 + lk8];
      const s16x8 bl0 = *(const s16x8*)&Bl[wn * 32 + lrow     ][kc * 32 + lk8];
      const s16x8 bl1 = *(const s16x8*)&Bl[wn * 32 + 16 + lrow][kc * 32 + lk8];
      acc[0][0] = __builtin_amdgcn_mfma_f32_16x16x32_bf16(ah0, bh0, acc[0][0], 0, 0, 0);
      acc[0][1] = __builtin_amdgcn_mfma_f32_16x16x32_bf16(ah0, bh1, acc[0][1], 0, 0, 0);
      acc[1][0] = __builtin_amdgcn_mfma_f32_16x16x32_bf16(ah1, bh0, acc[1][0], 0, 0, 0);
      acc[1][1] = __builtin_amdgcn_mfma_f32_16x16x32_bf16(ah1, bh1, acc[1][1], 0, 0, 0);
      acc[0][0] = __builtin_amdgcn_mfma_f32_16x16x32_bf16(ah0, bl0, acc[0][0], 0, 0, 0);
      acc[0][1] = __builtin_amdgcn_mfma_f32_16x16x32_bf16(ah0, bl1, acc[0][1], 0, 0, 0);
      acc[1][0] = __builtin_amdgcn_mfma_f32_16x16x32_bf16(ah1, bl0, acc[1][0], 0, 0, 0);
      acc[1][1] = __builtin_amdgcn_mfma_f32_16x16x32_bf16(ah1, bl1, acc[1][1], 0, 0, 0);
      acc[0][0] = __builtin_amdgcn_mfma_f32_16x16x32_bf16(al0, bh0, acc[0][0], 0, 0, 0);
      acc[0][1] = __builtin_amdgcn_mfma_f32_16x16x32_bf16(al0, bh1, acc[0][1], 0, 0, 0);
      acc[1][0] = __builtin_amdgcn_mfma_f32_16x16x32_bf16(al1, bh0, acc[1][0], 0, 0, 0);
      acc[1][1] = __builtin_amdgcn_mfma_f32_16x16x32_bf16(al1, bh1, acc[1][1], 0, 0, 0);
    }
    __syncthreads();
  }

  float* Yb = Y + (size_t)b * ySB;
#pragma unroll
  for (int mt = 0; mt < 2; ++mt)
#pragma unroll
    for (int nt = 0; nt < 2; ++nt) {
      const int col = n0 + wn * 32 + nt * 16 + lrow;
      const int rbase = m0 + wm * 32 + mt * 16 + (lane >> 4) * 4;
#pragma unroll
      for (int i = 0; i < 4; ++i) {
        const int row = rbase + i;
        float v = acc[mt][nt][i];
        const float s  = scale ? scale[row] : 1.f;
        const float bb = bias ? bias[row] : 0.f;
        v = v * s + bb;
        if (relu) v = fmaxf(v, 0.f);
        if (outMode == 0)      Yb[(size_t)row * ldy + col] = v;
        else if (outMode == 1) Yb[(size_t)col * ldy + row] = v;
        else                   atomicAdd(Yb + (size_t)col * ldy + row, v);
      }
    }
}

// ================================================================ pre-pad + split + transpose + ring-zero (grid (B_, 37))
__global__ __launch_bounds__(256)
void pad_split2(const float* __restrict__ X, unsigned short* __restrict__ Xh,
                unsigned short* __restrict__ Xl)
{
  const int b = blockIdx.x;
  const int tid = threadIdx.x;
  unsigned short* Xhb = Xh + (size_t)b * PN * C_;
  unsigned short* Xlb = Xl + (size_t)b * PN * C_;
  if (blockIdx.y == 36) {       // ring-zero block
    for (int idx = tid; idx < 196 * 256; idx += 256) {
      const int r = idx >> 8, u = idx & 255;
      int pcol;
      if (r < 50)       pcol = r;
      else if (r < 100) pcol = 49 * PW + (r - 50);
      else if (r < 148) pcol = (r - 100 + 1) * PW;
      else              pcol = (r - 148 + 1) * PW + 49;
      ((unsigned int*)(Xhb + (size_t)pcol * C_))[u] = 0u;
      ((unsigned int*)(Xlb + (size_t)pcol * C_))[u] = 0u;
    }
    return;
  }
  __shared__ float t[64][65];
  const int n0 = blockIdx.y * 64;
  const float* Xb = X + (size_t)b * C_ * N_;
  for (int cs = 0; cs < 8; ++cs) {
    const int c0 = cs * 64;
    __syncthreads();
#pragma unroll
    for (int i = 0; i < 16; ++i) {
      const int cc = i * 4 + (tid >> 6);
      t[cc][tid & 63] = Xb[(size_t)(c0 + cc) * N_ + n0 + (tid & 63)];
    }
    __syncthreads();
    const int cc = tid & 63;
#pragma unroll
    for (int i = 0; i < 16; ++i) {
      const int nn = i * 4 + (tid >> 6);
      const int n = n0 + nn;
      const float v = t[cc][nn];
      const unsigned short hh = f2bf(v);
      const unsigned short ll = f2bf(v - bf2f(hh));
      const size_t p = (size_t)((n / 48 + 1) * PW + (n % 48) + 1) * C_ + c0 + cc;
      Xhb[p] = hh; Xlb[p] = ll;
    }
  }
}

// weights fp32 [O][c*9+tap] -> hi/lo bf16 [O][tap*512+c]
__global__ __launch_bounds__(256)
void wsplit(const float* __restrict__ W, unsigned short* __restrict__ Wh,
            unsigned short* __restrict__ Wl)
{
  const int o = blockIdx.x, tap = blockIdx.y;
#pragma unroll
  for (int i = 0; i < 2; ++i) {
    const int c = threadIdx.x + i * 256;
    const float v = W[(size_t)o * KW + c * 9 + tap];
    const unsigned short hh = f2bf(v);
    Wh[(size_t)o * KW + tap * C_ + c] = hh;
    Wl[(size_t)o * KW + tap * C_ + c] = f2bf(v - bf2f(hh));
  }
}

// fp32 [C][N] -> bf16 hi/lo [N][C]
__global__ __launch_bounds__(256)
void tr_split(const float* __restrict__ X, unsigned short* __restrict__ Th,
              unsigned short* __restrict__ Tl)
{
  __shared__ float t[64][65];
  const int b = blockIdx.x, n0 = blockIdx.y * 64;
  const int tid = threadIdx.x;
  const float* Xb = X + (size_t)b * C_ * N_;
  unsigned short* Thb = Th + (size_t)b * N_ * C_;
  unsigned short* Tlb = Tl + (size_t)b * N_ * C_;
  for (int cs = 0; cs < 8; ++cs) {
    const int c0 = cs * 64;
    __syncthreads();
#pragma unroll
    for (int i = 0; i < 16; ++i) {
      const int cc = i * 4 + (tid >> 6);
      t[cc][tid & 63] = Xb[(size_t)(c0 + cc) * N_ + n0 + (tid & 63)];
    }
    __syncthreads();
    const int cc = tid & 63;
#pragma unroll
    for (int i = 0; i < 16; ++i) {
      const int nn = i * 4 + (tid >> 6);
      const float v = t[cc][nn];
      const unsigned short hh = f2bf(v);
      Thb[(size_t)(n0 + nn) * C_ + c0 + cc] = hh;
      Tlb[(size_t)(n0 + nn) * C_ + c0 + cc] = f2bf(v - bf2f(hh));
    }
  }
}

// ================================================================ mask -> 64-bit word pack (grid N_)
__global__ __launch_bounds__(256)
void mask_pack(const float* __restrict__ M, unsigned long long* __restrict__ Mb)
{
  const int row = blockIdx.x;
  const int tid = threadIdx.x, lane = tid & 63, wv = tid >> 6;
  const float* r = M + (size_t)row * N_;
  unsigned long long* o = Mb + (size_t)row * NW;
  for (int i = wv; i < NW; i += 4) {
    const unsigned long long m = __ballot(r[i * 64 + lane] > 0.f);
    if (lane == 0) o[i] = m;
  }
}

// ================================================================ conv3x3 tap-outer split-bf16 MFMA with reg-prefetch (tier 0)
__global__ __launch_bounds__(256)
void mfma_conv2(const unsigned short* __restrict__ Xh, const unsigned short* __restrict__ Xl,
                const unsigned short* __restrict__ Wh, const unsigned short* __restrict__ Wl,
                const float* __restrict__ sc, const float* __restrict__ bi,
                float* __restrict__ Y)
{
  __shared__ unsigned short Ah[64][72], Al[64][72];
  __shared__ unsigned short Bh[64][72], Bl[64][72];
  const int b  = blockIdx.z;
  const int m0 = blockIdx.y * 64, n0 = blockIdx.x * 64;
  const int tid  = threadIdx.x;
  const int lane = tid & 63, wave = tid >> 6;
  const int wm = wave >> 1, wn = wave & 1;
  const int lrow = lane & 15, lk8 = (lane >> 4) * 8;
  const int sRow = tid >> 2, sK = (tid & 3) * 16;
  const int nj = n0 + sRow;
  const int pbase = (nj / 48 + 1) * PW + (nj % 48) + 1;
  const unsigned short* Xhb = Xh + (size_t)b * PN * C_;
  const unsigned short* Xlb = Xl + (size_t)b * PN * C_;
  f32x4 acc[2][2] = {};
  s16x8 r0, r1, r2, r3, r4, r5, r6, r7;

#define CONV_LD(IT)                                                        \
  {                                                                        \
    const int tap_ = (IT) >> 3, c0_ = ((IT) & 7) * 64;                     \
    const int t3_ = tap_ / 3;                                              \
    const int toff_ = (t3_ - 1) * PW + (tap_ - t3_ * 3 - 1);               \
    const size_t bofs_ = (size_t)(pbase + toff_) * C_ + c0_ + sK;          \
    const size_t wrow_ = (size_t)(m0 + sRow) * KW + (size_t)tap_ * C_ + c0_ + sK; \
    r0 = *(const s16x8*)(Wh + wrow_);     r1 = *(const s16x8*)(Wh + wrow_ + 8); \
    r2 = *(const s16x8*)(Wl + wrow_);     r3 = *(const s16x8*)(Wl + wrow_ + 8); \
    r4 = *(const s16x8*)(Xhb + bofs_);    r5 = *(const s16x8*)(Xhb + bofs_ + 8); \
    r6 = *(const s16x8*)(Xlb + bofs_);    r7 = *(const s16x8*)(Xlb + bofs_ + 8); \
  }

  CONV_LD(0);
  for (int it = 0; it < 72; ++it) {
    *(s16x8*)&Ah[sRow][sK] = r0; *(s16x8*)&Ah[sRow][sK + 8] = r1;
    *(s16x8*)&Al[sRow][sK] = r2; *(s16x8*)&Al[sRow][sK + 8] = r3;
    *(s16x8*)&Bh[sRow][sK] = r4; *(s16x8*)&Bh[sRow][sK + 8] = r5;
    *(s16x8*)&Bl[sRow][sK] = r6; *(s16x8*)&Bl[sRow][sK + 8] = r7;
    __syncthreads();
    if (it < 71) CONV_LD(it + 1);     // next-iter loads fly under the MFMAs
#pragma unroll
    for (int kc = 0; kc < 2; ++kc) {
      const s16x8 ah0 = *(const s16x8*)&Ah[wm * 32 + lrow     ][kc * 32 + lk8];
      const s16x8 ah1 = *(const s16x8*)&Ah[wm * 32 + 16 + lrow][kc * 32 + lk8];
      const s16x8 al0 = *(const s16x8*)&Al[wm * 32 + lrow     ][kc * 32 + lk8];
      const s16x8 al1 = *(const s16x8*)&Al[wm * 32 + 16 + lrow][kc * 32 + lk8];
      const s16x8 bh0 = *(const s16x8*)&Bh[wn * 32 + lrow     ][kc * 32 + lk8];
      const s16x8 bh1 = *(const s16x8*)&Bh[wn * 32 + 16 + lrow][kc * 32 + lk8];
      const s16x8 bl0 = *(const s16x8*)&Bl[wn * 32 + lrow     ][kc * 32 + lk8];
      const s16x8 bl1 = *(const s16x8*)&Bl[wn * 32 + 16 + lrow][kc * 32 + lk8];
      acc[0][0] = __builtin_amdgcn_mfma_f32_16x16x32_bf16(ah0, bh0, acc[0][0], 0, 0, 0);
      acc[0][1] = __builtin_amdgcn_mfma_f32_16x16x32_bf16(ah0, bh1, acc[0][1], 0, 0, 0);
      acc[1][0] = __builtin_amdgcn_mfma_f32_16x16x32_bf16(ah1, bh0, acc[1][0], 0, 0, 0);
      acc[1][1] = __builtin_amdgcn_mfma_f32_16x16x32_bf16(ah1, bh1, acc[1][1], 0, 0, 0);
      acc[0][0] = __builtin_amdgcn_mfma_f32_16x16x32_bf16(ah0, bl0, acc[0][0], 0, 0, 0);
      acc[0][1] = __builtin_amdgcn_mfma_f32_16x16x32_bf16(ah0, bl1, acc[0][1], 0, 0, 0);
      acc[1][0] = __builtin_amdgcn_mfma_f32_16x16x32_bf16(ah1, bl0, acc[1][0], 0, 0, 0);
      acc[1][1] = __builtin_amdgcn_mfma_f32_16x16x32_bf16(ah1, bl1, acc[1][1], 0, 0, 0);
      acc[0][0] = __builtin_amdgcn_mfma_f32_16x16x32_bf16(al0, bh0, acc[0][0], 0, 0, 0);
      acc[0][1] = __builtin_amdgcn_mfma_f32_16x16x32_bf16(al0, bh1, acc[0][1], 0, 0, 0);
      acc[1][0] = __builtin_amdgcn_mfma_f32_16x16x32_bf16(al1, bh0, acc[1][0], 0, 0, 0);
      acc[1][1] = __builtin_amdgcn_mfma_f32_16x16x32_bf16(al1, bh1, acc[1][1], 0, 0, 0);
    }
    __syncthreads();
  }
#undef CONV_LD

  float* Yb = Y + (size_t)b * C_ * N_;
#pragma unroll
  for (int mt = 0; mt < 2; ++mt)
#pragma unroll
    for (int nt = 0; nt < 2; ++nt) {
      const int col = n0 + wn * 32 + nt * 16 + lrow;
      const int rbase = m0 + wm * 32 + mt * 16 + (lane >> 4) * 4;
#pragma unroll
      for (int i = 0; i < 4; ++i) {
        const int row = rbase + i;
        const float v = fmaxf(acc[mt][nt][i] * sc[row] + bi[row], 0.f);
        Yb[(size_t)row * N_ + col] = v;
      }
    }
}

// ================================================================ fused-softmax attention apply (tier 0, bitmask)
// Y[c][m] = gamma * sum_n V[c][n] * P[m][n] + Resid[c][m]. Tile 128c x 64m.
__global__ __launch_bounds__(256)
void mfma_apply(const unsigned short* __restrict__ V, const float* __restrict__ E,
                const float* __restrict__ st, int variant,
                const unsigned long long* __restrict__ Mb,
                const float* __restrict__ gammaPtr,
                const float* __restrict__ Resid, float* __restrict__ Y)
{
  __shared__ unsigned short As[128][72];
  __shared__ unsigned short Bs[64][72];
  const int b  = blockIdx.z;
  const int c0 = blockIdx.y * 128, m0 = blockIdx.x * 64;
  const int tid  = threadIdx.x;
  const int lane = tid & 63, wave = tid >> 6;
  const int wm = wave >> 1, wn = wave & 1;
  const int lrow = lane & 15, lk8 = (lane >> 4) * 8;
  const int aRow = tid >> 1, aK = (tid & 1) * 32;
  const int bRow = tid >> 2, bK = (tid & 3) * 16;
  const int mrow = m0 + bRow;
  const float* sp = st + ((size_t)b * N_ + mrow) * 6 + variant * 2;
  const float mx = sp[0], rs = 1.f / sp[1];
  const unsigned short* Vb = V + (size_t)b * C_ * N_;
  const float* Er = E + ((size_t)b * N_ + mrow) * N_;
  const unsigned long long* Mw = Mb ? Mb + (size_t)mrow * NW : nullptr;
  f32x4 acc[4][2] = {};
  s16x8 a0, a1, a2, a3;
  float4 e0, e1, e2, e3;
  unsigned long long mw = ~0ULL;

#define APPLY_LD(K0)                                                      \
  {                                                                       \
    const unsigned short* s = Vb + (size_t)(c0 + aRow) * N_ + (K0) + aK;  \
    a0 = *(const s16x8*)(s);      a1 = *(const s16x8*)(s + 8);            \
    a2 = *(const s16x8*)(s + 16); a3 = *(const s16x8*)(s + 24);           \
    const float* e = Er + (K0) + bK;                                      \
    e0 = *(const float4*)(e);     e1 = *(const float4*)(e + 4);           \
    e2 = *(const float4*)(e + 8); e3 = *(const float4*)(e + 12);          \
    if (Mw) mw = Mw[(K0) >> 6];                                           \
  }

  APPLY_LD(0);
  for (int k0 = 0; k0 < N_; k0 += 64) {
    *(s16x8*)&As[aRow][aK]      = a0; *(s16x8*)&As[aRow][aK + 8]  = a1;
    *(s16x8*)&As[aRow][aK + 16] = a2; *(s16x8*)&As[aRow][aK + 24] = a3;
    {
      float w[16];
      const float4 ee[4] = {e0, e1, e2, e3};
#pragma unroll
      for (int g4 = 0; g4 < 4; ++g4) {
        const float4 e4 = ee[g4];
        w[g4 * 4 + 0] = __expf(e4.x - mx) * rs;
        w[g4 * 4 + 1] = __expf(e4.y - mx) * rs;
        w[g4 * 4 + 2] = __expf(e4.z - mx) * rs;
        w[g4 * 4 + 3] = __expf(e4.w - mx) * rs;
      }
      if (Mw) {
        const unsigned long long mm = mw;
#pragma unroll
        for (int t = 0; t < 16; ++t)
          if (!((mm >> (bK + t)) & 1ULL)) w[t] = 0.f;
      }
      s16x8 p0, p1;
#pragma unroll
      for (int t = 0; t < 8; ++t) { p0[t] = (short)f2bf(w[t]); p1[t] = (short)f2bf(w[8 + t]); }
      *(s16x8*)&Bs[bRow][bK]     = p0;
      *(s16x8*)&Bs[bRow][bK + 8] = p1;
    }
    __syncthreads();
    if (k0 + 64 < N_) APPLY_LD(k0 + 64);
#pragma unroll
    for (int kc = 0; kc < 2; ++kc) {
      s16x8 av[4], bv[2];
#pragma unroll
      for (int mt = 0; mt < 4; ++mt)
        av[mt] = *(const s16x8*)&As[wm * 64 + mt * 16 + lrow][kc * 32 + lk8];
#pragma unroll
      for (int nt = 0; nt < 2; ++nt)
        bv[nt] = *(const s16x8*)&Bs[wn * 32 + nt * 16 + lrow][kc * 32 + lk8];
#pragma unroll
      for (int mt = 0; mt < 4; ++mt)
#pragma unroll
        for (int nt = 0; nt < 2; ++nt)
          acc[mt][nt] = __builtin_amdgcn_mfma_f32_16x16x32_bf16(av[mt], bv[nt], acc[mt][nt], 0, 0, 0);
    }
    __syncthreads();
  }
#undef APPLY_LD

  const float g = gammaPtr[0];
  float* Yb = Y + (size_t)b * C_ * N_;
  const float* Rb = Resid + (size_t)b * C_ * N_;
#pragma unroll
  for (int mt = 0; mt < 4; ++mt)
#pragma unroll
    for (int nt = 0; nt < 2; ++nt) {
      const int col = m0 + wn * 32 + nt * 16 + lrow;
      const int rbase = c0 + wm * 64 + mt * 16 + (lane >> 4) * 4;
#pragma unroll
      for (int i = 0; i < 4; ++i) {
        const int row = rbase + i;
        const size_t off = (size_t)row * N_ + col;
        Yb[off] = g * acc[mt][nt][i] + Rb[off];
      }
    }
}

// ================================================================ conv3x3 split-bf16 on-the-fly (tiers 1/2 fallback)
__global__ __launch_bounds__(256)
void mfma_conv_split(const float* __restrict__ X, const float* __restrict__ Wt,
                     const float* __restrict__ sc, const float* __restrict__ bi,
                     float* __restrict__ Y)
{
  __shared__ unsigned short Ah[64][72], Al[64][72];
  __shared__ unsigned short Bh[64][72], Bl[64][72];
  const int b  = blockIdx.z;
  const int m0 = blockIdx.y * 64, n0 = blockIdx.x * 64;
  const int tid  = threadIdx.x;
  const int lane = tid & 63, wave = tid >> 6;
  const int wm = wave >> 1, wn = wave & 1;
  const int lrow = lane & 15, lk8 = (lane >> 4) * 8;
  const int sRow = tid >> 2, sK = (tid & 3) * 16;
  const int tj = tid & 63, tkg = (tid >> 6) * 16;
  const int n = n0 + tj, yy = n / W_, xx = n - yy * W_;
  const float* Xb = X + (size_t)b * C_ * N_;
  f32x4 acc[2][2] = {};

  for (int k0 = 0; k0 < KW; k0 += 64) {
    {
      const float* src = Wt + (size_t)(m0 + sRow) * KW + k0 + sK;
      unsigned short h[16], l[16];
#pragma unroll
      for (int t = 0; t < 16; ++t) {
        const float v = src[t];
        const unsigned short hh = f2bf(v);
        h[t] = hh;
        l[t] = f2bf(v - bf2f(hh));
      }
      *(s16x8*)&Ah[sRow][sK]     = *(s16x8*)&h[0];
      *(s16x8*)&Ah[sRow][sK + 8] = *(s16x8*)&h[8];
      *(s16x8*)&Al[sRow][sK]     = *(s16x8*)&l[0];
      *(s16x8*)&Al[sRow][sK + 8] = *(s16x8*)&l[8];
    }
    {
#pragma unroll
      for (int ii = 0; ii < 16; ii += 2) {
        unsigned int ph = 0, pl = 0;
#pragma unroll
        for (int hft = 0; hft < 2; ++hft) {
          const int kg = k0 + tkg + ii + hft;
          const int c = kg / 9, tap = kg - c * 9;
          const int t3 = tap / 3;
          const int iy = yy + t3 - 1, ix = xx + (tap - t3 * 3) - 1;
          float v = 0.f;
          if (iy >= 0 && iy < H_ && ix >= 0 && ix < W_)
            v = Xb[(size_t)c * N_ + iy * W_ + ix];
          const unsigned short hh = f2bf(v);
          const unsigned short ll = f2bf(v - bf2f(hh));
          ph |= ((unsigned int)hh) << (16 * hft);
          pl |= ((unsigned int)ll) << (16 * hft);
        }
        *(unsigned int*)&Bh[tj][tkg + ii] = ph;
        *(unsigned int*)&Bl[tj][tkg + ii] = pl;
      }
    }
    __syncthreads();
#pragma unroll
    for (int kc = 0; kc < 2; ++kc) {
      const s16x8 ah0 = *(const s16x8*)&Ah[wm * 32 + lrow     ][kc * 32 + lk8];
      const s16x8 ah1 = *(const s16x8*)&Ah[wm * 32 + 16 + lrow][kc * 32 + lk8];
      const s16x8 al0 = *(const s16x8*)&Al[wm * 32 + lrow     ][kc * 32 + lk8];
      const s16x8 al1 = *(const s16x8*)&Al[wm * 32 + 16 + lrow][kc * 32 + lk8];
      const s16x8 bh0 = *(const s16x8*)&Bh[wn * 32 + lrow     ][kc * 32 + lk8];
      const s16x8 bh1 = *(const s16x8*)&Bh[wn * 32 + 16 + lrow][kc * 32 + lk8];
      const s16x8 bl0 = *(const s16x8*)&Bl[wn * 32 + lrow     ][kc * 32 + lk8];
      const s16x8 bl1 = *(const s16x8*)&Bl[wn * 32 + 16 + lrow][kc * 32 + lk8];
      acc[0][0] = __builtin_amdgcn_mfma_f32_16x16x32_bf16(ah0, bh0, acc[0][0], 0, 0, 0);
      acc[0][1] = __builtin_amdgcn_mfma_f32_16x16x32_bf16(ah0, bh1, acc[0][1], 0, 0, 0);
      acc[1][0] = __builtin_amdgcn_mfma_f32_16x16x32_bf16(ah1, bh0, acc[1][0], 0, 0, 0);
      acc[1][1] = __builtin_amdgcn_mfma_f32_16x16x32_bf16(ah1, bh1, acc[1][1], 0, 0, 0);
      acc[0][0] = __builtin_amdgcn_mfma_f32_16x16x32_bf16(ah0, bl0, acc[0][0], 0, 0, 0);
      acc[0][1] = __builtin_amdgcn_mfma_f32_16x16x32_bf16(ah0, bl1, acc[0][1], 0, 0, 0);
      acc[1][0] = __builtin_amdgcn_mfma_f32_16x16x32_bf16(ah1, bl0, acc[1][0], 0, 0, 0);
      acc[1][1] = __builtin_amdgcn_mfma_f32_16x16x32_bf16(ah1, bl1, acc[1][1], 0, 0, 0);
      acc[0][0] = __builtin_amdgcn_mfma_f32_16x16x32_bf16(al0, bh0, acc[0][0], 0, 0, 0);
      acc[0][1] = __builtin_amdgcn_mfma_f32_16x16x32_bf16(al0, bh1, acc[0][1], 0, 0, 0);
      acc[1][0] = __builtin_amdgcn_mfma_f32_16x16x32_bf16(al1, bh0, acc[1][0], 0, 0, 0);
      acc[1][1] = __builtin_amdgcn_mfma_f32_16x16x32_bf16(al1, bh1, acc[1][1], 0, 0, 0);
    }
    __syncthreads();
  }

  float* Yb = Y + (size_t)b * C_ * N_;
#pragma unroll
  for (int mt = 0; mt < 2; ++mt)
#pragma unroll
    for (int nt = 0; nt < 2; ++nt) {
      const int col = n0 + wn * 32 + nt * 16 + lrow;
      const int rbase = m0 + wm * 32 + mt * 16 + (lane >> 4) * 4;
#pragma unroll
      for (int i = 0; i < 4; ++i) {
        const int row = rbase + i;
        const float v = fmaxf(acc[mt][nt][i] * sc[row] + bi[row], 0.f);
        Yb[(size_t)row * N_ + col] = v;
      }
    }
}

// ---------------------------------------------------------------- softmax stats, bitmask masks (tier 0)
__global__ __launch_bounds__(256)
void softmax_stats_bm(const float* __restrict__ E,
                      const unsigned long long* __restrict__ M1b,
                      const unsigned long long* __restrict__ M2b,
                      float* __restrict__ st)
{
  const int row = blockIdx.x, b = blockIdx.y, tid = threadIdx.x;
  const float* er = E + ((size_t)b * N_ + row) * N_;
  const unsigned long long* r1 = M1b + (size_t)row * NW;
  const unsigned long long* r2 = M2b + (size_t)row * NW;
  const int bitp = tid & 63;
  float ev[9];
  bool f1[9], f2[9];
  float mx0 = -3.4e38f, mx1 = -3.4e38f, mx2 = -3.4e38f;
#pragma unroll
  for (int i = 0; i < 9; ++i) {
    const int n = tid + i * 256;
    ev[i] = er[n];
    f1[i] = (r1[n >> 6] >> bitp) & 1ULL;
    f2[i] = (r2[n >> 6] >> bitp) & 1ULL;
    mx0 = fmaxf(mx0, ev[i]);
    if (f1[i]) mx1 = fmaxf(mx1, ev[i]);
    if (f2[i]) mx2 = fmaxf(mx2, ev[i]);
  }
  __shared__ float red[256];
  mx0 = blockReduceMax(mx0, red);
  mx1 = blockReduceMax(mx1, red);
  mx2 = blockReduceMax(mx2, red);
  float s0 = 0.f, s1 = 0.f, s2 = 0.f;
#pragma unroll
  for (int i = 0; i < 9; ++i) {
    s0 += __expf(ev[i] - mx0);
    if (f1[i]) s1 += __expf(ev[i] - mx1);
    if (f2[i]) s2 += __expf(ev[i] - mx2);
  }
  s0 = blockReduceSum(s0, red);
  s1 = blockReduceSum(s1, red);
  s2 = blockReduceSum(s2, red);
  if (tid == 0) {
    float* o = st + ((size_t)b * N_ + row) * 6;
    o[0] = mx0; o[1] = s0; o[2] = mx1; o[3] = s1; o[4] = mx2; o[5] = s2;
  }
}

// ---------------------------------------------------------------- softmax stats (fp32 masks; tier 1)
__global__ __launch_bounds__(256)
void softmax_stats(const float* __restrict__ E, const float* __restrict__ M1,
                   const float* __restrict__ M2, float* __restrict__ st)
{
  const int row = blockIdx.x, b = blockIdx.y, tid = threadIdx.x;
  const float* er = E + ((size_t)b * N_ + row) * N_;
  const float* r1 = M1 + (size_t)row * N_;
  const float* r2 = M2 + (size_t)row * N_;
  float mx0 = -3.4e38f, mx1 = -3.4e38f, mx2 = -3.4e38f;
  for (int n = tid; n < N_; n += 256) {
    const float v = er[n];
    mx0 = fmaxf(mx0, v);
    if (r1[n] > 0.f) mx1 = fmaxf(mx1, v);
    if (r2[n] > 0.f) mx2 = fmaxf(mx2, v);
  }
  __shared__ float red[256];
  mx0 = blockReduceMax(mx0, red);
  mx1 = blockReduceMax(mx1, red);
  mx2 = blockReduceMax(mx2, red);
  float s0 = 0.f, s1 = 0.f, s2 = 0.f;
  for (int n = tid; n < N_; n += 256) {
    const float v = er[n];
    s0 += __expf(v - mx0);
    if (r1[n] > 0.f) s1 += __expf(v - mx1);
    if (r2[n] > 0.f) s2 += __expf(v - mx2);
  }
  s0 = blockReduceSum(s0, red);
  s1 = blockReduceSum(s1, red);
  s2 = blockReduceSum(s2, red);
  if (tid == 0) {
    float* o = st + ((size_t)b * N_ + row) * 6;
    o[0] = mx0; o[1] = s0; o[2] = mx1; o[3] = s1; o[4] = mx2; o[5] = s2;
  }
}

// ---------------------------------------------------------------- softmax stats (LITE, tier 2)
__global__ __launch_bounds__(256)
void softmax_stats_rq(const float* __restrict__ q, const float* __restrict__ k,
                      const float* __restrict__ M1, const float* __restrict__ M2,
                      float* __restrict__ st)
{
  const int row = blockIdx.x, b = blockIdx.y, tid = threadIdx.x;
  __shared__ float qs[CR_];
  if (tid < CR_) qs[tid] = q[((size_t)b * CR_ + tid) * N_ + row];
  __syncthreads();
  const float* kb_ = k + (size_t)b * CR_ * N_;
  float ev[9], mk1[9], mk2[9];
  const float* r1 = M1 + (size_t)row * N_;
  const float* r2 = M2 + (size_t)row * N_;
#pragma unroll
  for (int i = 0; i < 9; ++i) {
    const int n = tid + i * 256;
    float e = 0.f;
#pragma unroll 8
    for (int c = 0; c < CR_; ++c) e = fmaf(qs[c], kb_[(size_t)c * N_ + n], e);
    ev[i] = e; mk1[i] = r1[n]; mk2[i] = r2[n];
  }
  float mx0 = -3.4e38f, mx1 = -3.4e38f, mx2 = -3.4e38f;
#pragma unroll
  for (int i = 0; i < 9; ++i) {
    const float v = ev[i];
    mx0 = fmaxf(mx0, v);
    if (mk1[i] > 0.f) mx1 = fmaxf(mx1, v);
    if (mk2[i] > 0.f) mx2 = fmaxf(mx2, v);
  }
  __shared__ float red[256];
  mx0 = blockReduceMax(mx0, red);
  mx1 = blockReduceMax(mx1, red);
  mx2 = blockReduceMax(mx2, red);
  float s0 = 0.f, s1 = 0.f, s2 = 0.f;
#pragma unroll
  for (int i = 0; i < 9; ++i) {
    const float v = ev[i];
    s0 += __expf(v - mx0);
    if (mk1[i] > 0.f) s1 += __expf(v - mx1);
    if (mk2[i] > 0.f) s2 += __expf(v - mx2);
  }
  s0 = blockReduceSum(s0, red);
  s1 = blockReduceSum(s1, red);
  s2 = blockReduceSum(s2, red);
  if (tid == 0) {
    float* o = st + ((size_t)b * N_ + row) * 6;
    o[0] = mx0; o[1] = s0; o[2] = mx1; o[3] = s1; o[4] = mx2; o[5] = s2;
  }
}

// ---------------------------------------------------------------- attention apply (fp32, tier 1)
__global__ __launch_bounds__(256)
void attn_apply(const float* __restrict__ V, const float* __restrict__ E,
                const float* __restrict__ st, int variant,
                const float* __restrict__ mask,
                const float* __restrict__ gammaPtr,
                const float* __restrict__ R, float* __restrict__ Y)
{
  __shared__ float As[TK][LDSP], Bs[TK][LDSP];
  const int b  = blockIdx.z;
  const int c0 = blockIdx.y * 64, m0 = blockIdx.x * 64;
  const int tid = threadIdx.x, tx = tid & 15, ty = tid >> 4;
  const int ia = tid >> 2, ka = (tid & 3) * 4;
  const int jb = tid >> 2, kb = (tid & 3) * 4;
  const int mrow = m0 + jb;
  const float* sp = st + ((size_t)b * N_ + mrow) * 6 + variant * 2;
  const float mx = sp[0];
  const float rs = 1.f / sp[1];
  const float* Vb = V + (size_t)b * C_ * N_;
  const float* Er = E + ((size_t)b * N_ + mrow) * N_;
  const float* Mr = mask ? mask + (size_t)mrow * N_ : nullptr;
  float acc[4][4] = {};
  for (int k0 = 0; k0 < N_; k0 += TK) {
    const float4 a4 = *(const float4*)(Vb + (size_t)(c0 + ia) * N_ + k0 + ka);
    As[ka + 0][ia] = a4.x; As[ka + 1][ia] = a4.y;
    As[ka + 2][ia] = a4.z; As[ka + 3][ia] = a4.w;
    const float4 e4 = *(const float4*)(Er + k0 + kb);
    float w0, w1, w2, w3;
    if (Mr) {
      const float4 m4 = *(const float4*)(Mr + k0 + kb);
      w0 = (m4.x > 0.f) ? __expf(e4.x - mx) * rs : 0.f;
      w1 = (m4.y > 0.f) ? __expf(e4.y - mx) * rs : 0.f;
      w2 = (m4.z > 0.f) ? __expf(e4.z - mx) * rs : 0.f;
      w3 = (m4.w > 0.f) ? __expf(e4.w - mx) * rs : 0.f;
    } else {
      w0 = __expf(e4.x - mx) * rs; w1 = __expf(e4.y - mx) * rs;
      w2 = __expf(e4.z - mx) * rs; w3 = __expf(e4.w - mx) * rs;
    }
    Bs[kb + 0][jb] = w0; Bs[kb + 1][jb] = w1;
    Bs[kb + 2][jb] = w2; Bs[kb + 3][jb] = w3;
    __syncthreads();
    mm16(As, Bs, acc, ty, tx);
    __syncthreads();
  }
  const float g = gammaPtr[0];
  float* Yb = Y + (size_t)b * C_ * N_;
  const float* Rb = R + (size_t)b * C_ * N_;
#pragma unroll
  for (int i = 0; i < 4; ++i) {
    const int row = c0 + ty * 4 + i;
    const size_t off = (size_t)row * N_ + m0 + tx * 4;
    const float4 r4 = *(const float4*)(Rb + off);
    float4 o;
    o.x = g * acc[i][0] + r4.x; o.y = g * acc[i][1] + r4.y;
    o.z = g * acc[i][2] + r4.z; o.w = g * acc[i][3] + r4.w;
    *(float4*)(Yb + off) = o;
  }
}

// ---------------------------------------------------------------- attention apply (fp32 LITE, tier 2)
__global__ __launch_bounds__(256)
void attn_apply_rq(const float* __restrict__ V, const float* __restrict__ q,
                   const float* __restrict__ k,
                   const float* __restrict__ st, int variant,
                   const float* __restrict__ mask,
                   const float* __restrict__ gammaPtr,
                   const float* __restrict__ R, float* __restrict__ Y)
{
  __shared__ float As[TK][LDSP], Bs[TK][LDSP];
  __shared__ float qs[CR_][65];
  __shared__ float kss[CR_][17];
  const int b  = blockIdx.z;
  const int c0 = blockIdx.y * 64, m0 = blockIdx.x * 64;
  const int tid = threadIdx.x, tx = tid & 15, ty = tid >> 4;
  const int ia = tid >> 2, ka = (tid & 3) * 4;
  const int jb = tid >> 2, kb = (tid & 3) * 4;
  const int mrow = m0 + jb;
  const float* qb_ = q + (size_t)b * CR_ * N_;
  const float* kb_ = k + (size_t)b * CR_ * N_;
#pragma unroll
  for (int i = 0; i < 16; ++i) {
    const int idx = tid + i * 256;
    const int c = idx >> 6, j = idx & 63;
    qs[c][j] = qb_[(size_t)c * N_ + m0 + j];
  }
  const float* sp = st + ((size_t)b * N_ + mrow) * 6 + variant * 2;
  const float mx = sp[0];
  const float rs = 1.f / sp[1];
  const float* Vb = V + (size_t)b * C_ * N_;
  const float* Mr = mask ? mask + (size_t)mrow * N_ : nullptr;
  float acc[4][4] = {};
  __syncthreads();
  for (int k0 = 0; k0 < N_; k0 += TK) {
    const float4 a4 = *(const float4*)(Vb + (size_t)(c0 + ia) * N_ + k0 + ka);
    As[ka + 0][ia] = a4.x; As[ka + 1][ia] = a4.y;
    As[ka + 2][ia] = a4.z; As[ka + 3][ia] = a4.w;
#pragma unroll
    for (int i = 0; i < 4; ++i) {
      const int idx = tid + i * 256;
      const int c = idx >> 4, nn = idx & 15;
      kss[c][nn] = kb_[(size_t)c * N_ + k0 + nn];
    }
    __syncthreads();
    float e0 = 0.f, e1 = 0.f, e2 = 0.f, e3 = 0.f;
#pragma unroll 16
    for (int c = 0; c < CR_; ++c) {
      const float qv = qs[c][jb];
      e0 = fmaf(qv, kss[c][kb + 0], e0);
      e1 = fmaf(qv, kss[c][kb + 1], e1);
      e2 = fmaf(qv, kss[c][kb + 2], e2);
      e3 = fmaf(qv, kss[c][kb + 3], e3);
    }
    float w0, w1, w2, w3;
    if (Mr) {
      const float4 m4 = *(const float4*)(Mr + k0 + kb);
      w0 = (m4.x > 0.f) ? __expf(e0 - mx) * rs : 0.f;
      w1 = (m4.y > 0.f) ? __expf(e1 - mx) * rs : 0.f;
      w2 = (m4.z > 0.f) ? __expf(e2 - mx) * rs : 0.f;
      w3 = (m4.w > 0.f) ? __expf(e3 - mx) * rs : 0.f;
    } else {
      w0 = __expf(e0 - mx) * rs; w1 = __expf(e1 - mx) * rs;
      w2 = __expf(e2 - mx) * rs; w3 = __expf(e3 - mx) * rs;
    }
    Bs[kb + 0][jb] = w0; Bs[kb + 1][jb] = w1;
    Bs[kb + 2][jb] = w2; Bs[kb + 3][jb] = w3;
    __syncthreads();
    mm16(As, Bs, acc, ty, tx);
    __syncthreads();
  }
  const float g = gammaPtr[0];
  float* Yb = Y + (size_t)b * C_ * N_;
  const float* Rb = R + (size_t)b * C_ * N_;
#pragma unroll
  for (int i = 0; i < 4; ++i) {
    const int row = c0 + ty * 4 + i;
    const size_t off = (size_t)row * N_ + m0 + tx * 4;
    const float4 r4 = *(const float4*)(Rb + off);
    float4 o;
    o.x = g * acc[i][0] + r4.x; o.y = g * acc[i][1] + r4.y;
    o.z = g * acc[i][2] + r4.z; o.w = g * acc[i][3] + r4.w;
    *(float4*)(Yb + off) = o;
  }
}

// ---------------------------------------------------------------- chl row softmax
__global__ __launch_bounds__(256)
void chl_softmax(float* __restrict__ buf)
{
  const int row = blockIdx.x, tid = threadIdx.x;
  float* r = buf + (size_t)row * C_;
  const float v0 = -r[tid], v1 = -r[tid + 256];
  __shared__ float red[256];
  const float mx = blockReduceMax(fmaxf(v0, v1), red);
  const float e0 = __expf(v0 - mx), e1 = __expf(v1 - mx);
  const float s = blockReduceSum(e0 + e1, red);
  const float rs = 1.f / s;
  r[tid] = e0 * rs;
  r[tid + 256] = e1 * rs;
}

// ================================================================ launch
extern "C" void kernel_launch(void* const* d_in, const int* in_sizes, int n_in,
                              void* d_out, int out_size, void* d_ws, size_t ws_size,
                              hipStream_t stream)
{
  (void)in_sizes; (void)n_in; (void)out_size;
  const float* x      = (const float*)d_in[0];
  const float* wq     = (const float*)d_in[1];
  const float* bq     = (const float*)d_in[2];
  const float* wk     = (const float*)d_in[3];
  const float* bk     = (const float*)d_in[4];
  const float* wv0    = (const float*)d_in[5];
  const float* bv0    = (const float*)d_in[6];
  const float* c1w    = (const float*)d_in[7];
  const float* c1s    = (const float*)d_in[8];
  const float* c1b    = (const float*)d_in[9];
  const float* c2w    = (const float*)d_in[10];
  const float* c2s    = (const float*)d_in[11];
  const float* c2b    = (const float*)d_in[12];
  const float* gamma  = (const float*)d_in[13];
  const float* gamma1 = (const float*)d_in[14];
  const float* gamma2 = (const float*)d_in[15];
  const float* c1qw   = (const float*)d_in[16];
  const float* c1qs   = (const float*)d_in[17];
  const float* c1qb   = (const float*)d_in[18];
  const float* c1ew   = (const float*)d_in[19];
  const float* c1eb   = (const float*)d_in[20];
  const float* c2qw   = (const float*)d_in[21];
  const float* c2qs   = (const float*)d_in[22];
  const float* c2qb   = (const float*)d_in[23];
  const float* c2ew   = (const float*)d_in[24];
  const float* c2eb   = (const float*)d_in[25];
  const float* mask1  = (const float*)d_in[26];
  const float* mask2  = (const float*)d_in[27];

  const size_t QK = 589824;            // B*CR*N
  const size_t CQ = 1179648;           // B*C4*N
  const size_t VV = 4718592;           // B*C*N
  const size_t EE = 21233664;          // B*N*N
  const size_t ST = 55296;             // B*N*6
  const size_t CE = 262144;            // B*C4*C
  const size_t CA = 1048576;           // B*C*C
  const size_t ELEMS_B = CQ + VV + EE + ST + VV + CE + CA;       // 33,216,512
  const size_t ELEMS_A = ELEMS_B + EE / 2;                       // + time-shared bf16 region
  const int tier = (ws_size >= ELEMS_A * 4) ? 0
                 : (ws_size >= ELEMS_B * 4) ? 1 : 2;

  float* ws = (float*)d_ws;
  float *qbuf, *kbuf, *cq, *vbuf, *ebuf, *stb, *o0, *ce1, *cat_;
  unsigned short *Xh = nullptr, *Xl = nullptr,
                 *W1h = nullptr, *W1l = nullptr, *W2h = nullptr, *W2l = nullptr,
                 *xTh = nullptr, *xTl = nullptr, *oTh = nullptr, *oTl = nullptr;
  float *qTf = nullptr, *kTf = nullptr;
  unsigned long long *Mb1 = nullptr, *Mb2 = nullptr;
  if (tier <= 1) {
    qbuf = ws; kbuf = ws + QK;         // (tier1 only; dead after energy)
    cq   = ws;                          // aliases q+k region
    vbuf = ws + CQ;
    ebuf = vbuf + VV;
    stb  = ebuf + EE;
    o0   = stb + ST;
    ce1  = o0 + VV;
    cat_ = ce1 + CE;
    if (tier == 0) {
      unsigned short* reg = (unsigned short*)(cat_ + CA);   // EE shorts, time-shared
      // pre-loop: x^T hi/lo (dead after v-proj) + q^T/k^T fp32 (dead after energy)
      xTh = reg;                       //  4,718,592
      xTl = reg + 4718592;             // -> 9,437,184
      qTf = (float*)(reg + 9437184);   //  589,824 f = 1,179,648 shorts
      kTf = qTf + 589824;              // -> 11,796,480 shorts (dead after energy)
      // persistent: conv weights hi/lo for both passes
      W1h = reg + 11796480;            //  2,359,296
      W1l = reg + 14155776;
      W2h = reg + 16515072;
      W2l = reg + 18874368;            // -> 21,233,664 == EE exactly
      // per-pass (alias xT/qT region): padded act / o^T
      Xh  = reg;                       //  5,120,000
      Xl  = reg + 5120000;             // -> 10,240,000
      oTh = reg;                       //  4,718,592
      oTl = reg + 4718592;             // -> 9,437,184
      // persistent bitmasks live in [10,240,000 .. 11,796,480) — packed AFTER
      // energy (qT/kT dead), never touched by Xh/oTh (both end <= 10,240,000)
      Mb1 = (unsigned long long*)(reg + 10240000);   // 82,944 u64
      Mb2 = Mb1 + (size_t)N_ * NW;                   // + 82,944 u64 = 663,552 shorts total
    }
  } else {
    qbuf = ws; kbuf = qbuf + QK;       // live all passes
    cq   = kbuf + QK;
    vbuf = cq + CQ;
    stb  = vbuf + VV;
    o0   = stb + ST;
    ce1  = o0 + VV;
    cat_ = ce1 + CE;
    ebuf = nullptr;
  }
  float* t0 = (float*)d_out;           // pre-conv scratch aliases d_out
  unsigned short* vb16 = (unsigned short*)vbuf;  // tier-0: bf16 V in vbuf region

  const dim3 TPB(256);
  const long long sxc = (long long)C_ * N_;
  const long long sqr = (long long)CR_ * N_;
  const long long sq4 = (long long)C4_ * N_;
  const long long sNN = (long long)N_ * N_;
  const long long sNC = (long long)N_ * C_;
  const long long sCC = (long long)C_ * C_;
  const long long sEC = (long long)C4_ * C_;
  const long long sNR = (long long)N_ * CR_;

  if (tier == 0) {
    tr_split<<<dim3(B_, 36), TPB, 0, stream>>>(x, xTh, xTl);
    mfma_sp<<<dim3(36, 1, 4), TPB, 0, stream>>>(wq, 0, C_, xTh, xTl, sNC, C_, 1,
        qTf, sNR, CR_, 1, C_, 1, nullptr, bq, 0);
    mfma_sp<<<dim3(36, 1, 4), TPB, 0, stream>>>(wk, 0, C_, xTh, xTl, sNC, C_, 1,
        kTf, sNR, CR_, 1, C_, 1, nullptr, bk, 0);
    mfma_gemm<<<dim3(36, 8, 4), TPB, 0, stream>>>(wv0, 0, 0, C_, xTh, sNC, C_, 2,
        vb16, 1, sxc, N_, C_, nullptr, bv0, 0, nullptr, nullptr, 0);
    mfma_sp<<<dim3(36, 36, 4), TPB, 0, stream>>>(qTf, sNR, CR_, kTf, nullptr, sNR, CR_, 0,
        ebuf, sNN, N_, 0, CR_, 1, nullptr, nullptr, 0);
    mask_pack<<<dim3(N_), TPB, 0, stream>>>(mask1, Mb1);
    mask_pack<<<dim3(N_), TPB, 0, stream>>>(mask2, Mb2);
    softmax_stats_bm<<<dim3(N_, 4), TPB, 0, stream>>>(ebuf, Mb1, Mb2, stb);
    wsplit<<<dim3(512, 9), TPB, 0, stream>>>(c1w, W1h, W1l);
    wsplit<<<dim3(512, 9), TPB, 0, stream>>>(c2w, W2h, W2l);
  } else if (tier == 1) {
    gemm_nn<<<dim3(36, 1, 4), TPB, 0, stream>>>(wq, 0, C_, x, sxc, N_,
                                                qbuf, sqr, N_, C_, nullptr, bq, 0);
    gemm_nn<<<dim3(36, 1, 4), TPB, 0, stream>>>(wk, 0, C_, x, sxc, N_,
                                                kbuf, sqr, N_, C_, nullptr, bk, 0);
    mfma_gemm<<<dim3(36, 8, 4), TPB, 0, stream>>>(wv0, 0, 0, C_, x, sxc, N_, 1,
        vbuf, 0, sxc, N_, C_, nullptr, bv0, 0, nullptr, nullptr, 0);
    gemm_tn<<<dim3(36, 36, 4), TPB, 0, stream>>>(qbuf, sqr, N_, kbuf, sqr, N_,
                                                 ebuf, sNN, N_, CR_);
    softmax_stats<<<dim3(N_, 4), TPB, 0, stream>>>(ebuf, mask1, mask2, stb);
  } else {
    gemm_nn<<<dim3(36, 1, 4), TPB, 0, stream>>>(wq, 0, C_, x, sxc, N_,
                                                qbuf, sqr, N_, C_, nullptr, bq, 0);
    gemm_nn<<<dim3(36, 1, 4), TPB, 0, stream>>>(wk, 0, C_, x, sxc, N_,
                                                kbuf, sqr, N_, C_, nullptr, bk, 0);
    mfma_gemm<<<dim3(36, 8, 4), TPB, 0, stream>>>(wv0, 0, 0, C_, x, sxc, N_, 1,
        vbuf, 0, sxc, N_, C_, nullptr, bv0, 0, nullptr, nullptr, 0);
    softmax_stats_rq<<<dim3(N_, 4), TPB, 0, stream>>>(qbuf, kbuf, mask1, mask2, stb);
  }

  for (int pass = 0; pass < 3; ++pass) {
    const float* msk = (pass == 0) ? nullptr : (pass == 1 ? mask1 : mask2);
    const unsigned long long* mbk = (pass == 0) ? nullptr : (pass == 1 ? Mb1 : Mb2);
    const float* gm  = (pass == 0) ? gamma : (pass == 1 ? gamma1 : gamma2);
    const float* res = (pass == 0) ? x : o0;
    float* dst = (pass == 2) ? (float*)d_out : t0;

    // ---- attention apply: dst = gm * V . P^T + res
    if (tier == 0) {
      mfma_apply<<<dim3(36, 4, 4), TPB, 0, stream>>>(vb16, ebuf, stb, pass, mbk,
                                                     gm, res, dst);
    } else if (tier == 1) {
      attn_apply<<<dim3(36, 8, 4), TPB, 0, stream>>>(vbuf, ebuf, stb, pass, msk,
                                                     gm, res, dst);
    } else {
      attn_apply_rq<<<dim3(36, 8, 4), TPB, 0, stream>>>(vbuf, qbuf, kbuf, stb, pass, msk,
                                                        gm, res, dst);
    }
    if (pass == 2) break;

    // ---- conv3x3 + BN + ReLU  (dst -> o0)
    const float* cs = (pass == 0) ? c1s : c2s;
    const float* cb = (pass == 0) ? c1b : c2b;
    if (tier == 0) {
      pad_split2<<<dim3(B_, 37), TPB, 0, stream>>>(dst, Xh, Xl);
      mfma_conv2<<<dim3(36, 8, 4), TPB, 0, stream>>>(Xh, Xl,
          (pass == 0) ? W1h : W2h, (pass == 0) ? W1l : W2l, cs, cb, o0);
    } else {
      const float* cw = (pass == 0) ? c1w : c2w;
      mfma_conv_split<<<dim3(36, 8, 4), TPB, 0, stream>>>(dst, cw, cs, cb, o0);
    }

    // ---- chl block on o0 -> vbuf
    const float* qw = (pass == 0) ? c1qw : c2qw;
    const float* qs = (pass == 0) ? c1qs : c2qs;
    const float* qb = (pass == 0) ? c1qb : c2qb;
    const float* ew = (pass == 0) ? c1ew : c2ew;
    const float* eb = (pass == 0) ? c1eb : c2eb;
    if (tier == 0) {
      tr_split<<<dim3(B_, 36), TPB, 0, stream>>>(o0, oTh, oTl);
      mfma_sp<<<dim3(36, 2, 4), TPB, 0, stream>>>(qw, 0, C_, oTh, oTl, sNC, C_, 1,
          cq, sq4, N_, 0, C_, 1, qs, qb, 1);
      zero_buf<<<dim3(256), TPB, 0, stream>>>((float4*)ce1, (int)(CE / 4));
      mfma_sp<<<dim3(8, 2, 16), TPB, 0, stream>>>(cq, sq4, N_, o0, nullptr, sxc, N_, 0,
          ce1, sEC, C4_, 2, N_, 4, nullptr, nullptr, 0);
      mfma_sp<<<dim3(8, 8, 4), TPB, 0, stream>>>(ew, 0, C4_, ce1, nullptr, sEC, C4_, 0,
          cat_, sCC, C_, 0, C4_, 1, nullptr, eb, 0);
      chl_softmax<<<dim3(C_ * 4), TPB, 0, stream>>>(cat_);
      mfma_gemm<<<dim3(36, 8, 4), TPB, 0, stream>>>(cat_, 0, sCC, C_, oTh, sNC, C_, 2,
          vb16, 1, sxc, N_, C_, nullptr, nullptr, 0, nullptr, nullptr, 0);
    } else {
      gemm_nn<<<dim3(36, 2, 4), TPB, 0, stream>>>(qw, 0, C_, o0, sxc, N_,
                                                  cq, sq4, N_, C_, qs, qb, 1);
      zero_buf<<<dim3(256), TPB, 0, stream>>>((float4*)ce1, (int)(CE / 4));
      gemm_nt_splitk<<<dim3(8, 2, 16), TPB, 0, stream>>>(cq, sq4, N_, o0, sxc, N_,
                                                         ce1, sEC, C_, N_);
      gemm_nn<<<dim3(8, 8, 4), TPB, 0, stream>>>(ew, 0, C4_, ce1, sEC, C_,
                                                 cat_, sCC, C_, C4_, nullptr, eb, 0);
      chl_softmax<<<dim3(C_ * 4), TPB, 0, stream>>>(cat_);
      mfma_gemm<<<dim3(36, 8, 4), TPB, 0, stream>>>(cat_, 0, sCC, C_, o0, sxc, N_, 1,
          vbuf, 0, sxc, N_, C_, nullptr, nullptr, 0, nullptr, nullptr, 0);
    }
  }
}